// Round 6
// baseline (207.923 us; speedup 1.0000x reference)
//
#include <hip/hip_runtime.h>
#include <math.h>

#define BB 8
#define CH 128
#define HH 152
#define WWID 272
#define HWSZ (HH*WWID)
#define NDET 128
#define NHEAD 8
#define HDIM 16
#define DFF 512
#define NDB (BB*NDET)      // 1024 dets
#define NPOOL (2*NDB)      // 2048 pooling blocks: (det, channel-half)
#define NCOPY1 1024        // copy blocks in kernel 1 (first half of x)
#define NCOPY2 1024        // copy blocks in kernel 2 (second half of x)
#define KSTRIDE 1152       // 9*CH floats of pooled k per det

typedef float f4v __attribute__((ext_vector_type(4)));

__device__ __forceinline__ float dot4(float4 w, float4 u, float s) {
    s = fmaf(w.x, u.x, s);
    s = fmaf(w.y, u.y, s);
    s = fmaf(w.z, u.z, s);
    s = fmaf(w.w, u.w, s);
    return s;
}

// LayerNorm over 128 values held one-per-thread (t<128); ALL 256 threads must call.
__device__ __forceinline__ float block_layernorm(float v, int t,
        const float* __restrict__ gamma, const float* __restrict__ beta,
        float* redA, float* redB) {
    float s1 = v, s2 = v * v;
    #pragma unroll
    for (int off = 32; off >= 1; off >>= 1) {
        s1 += __shfl_xor(s1, off);
        s2 += __shfl_xor(s2, off);
    }
    if ((t & 63) == 0) { redA[t >> 6] = s1; redB[t >> 6] = s2; }
    __syncthreads();
    float sum = redA[0] + redA[1] + redA[2] + redA[3];
    float sq  = redB[0] + redB[1] + redB[2] + redB[3];
    __syncthreads();
    float m   = sum * (1.0f / 128.0f);
    float var = sq  * (1.0f / 128.0f) - m * m;
    float r = 0.f;
    if (t < CH) r = (v - m) * rsqrtf(var + 1e-5f) * gamma[t] + beta[t];
    return r;
}

// ============================================================================
// Kernel 1: adaptive 3x3 pooling (wide: det x channel-half) + first copy half
// ============================================================================
__global__ __launch_bounds__(256) void pool_copy(
    const float* __restrict__ x, const int* __restrict__ dets,
    float* __restrict__ kout, float* __restrict__ out)
{
    const int bid = blockIdx.x;
    const int t   = threadIdx.x;

    if (bid >= NPOOL) {
        // ---- streaming copy, first half (NT stores: don't evict x from L3) ----
        const size_t n4   = (size_t)BB * CH * HWSZ / 4;
        const size_t half = n4 / 2;
        const f4v* s4 = (const f4v*)x;
        f4v* o4 = (f4v*)out;
        size_t i = (size_t)(bid - NPOOL) * 256 + t;
        const size_t stride = (size_t)(gridDim.x - NPOOL) * 256;
        for (; i < half; i += stride) {
            f4v v = s4[i];
            __builtin_nontemporal_store(v, &o4[i]);
        }
        return;
    }

    __shared__ float msk[48][4];   // per-row y-cell masks {m0,m1,m2,0}

    const int det   = bid >> 1;
    const int chalf = bid & 1;     // which 64 channels
    const int b = det >> 7;
    const int n = det & (NDET - 1);

    const int4 dv = *((const int4*)(dets + (size_t)(b * NDET + n) * 4));
    const int sx = dv.x, sy = dv.y, ex = dv.z, ey = dv.w;
    const int Lx = ex - sx, Ly = ey - sy;
    // cell edges (cells OVERLAP due to floor/ceil in reference)
    const int xs1 = sx + Lx / 3,        xs2 = sx + 2 * Lx / 3;
    const int xe0 = sx + (Lx + 2) / 3,  xe1 = sx + (2 * Lx + 2) / 3;
    const int ys1 = sy + Ly / 3,        ys2 = sy + 2 * Ly / 3;
    const int ye0 = sy + (Ly + 2) / 3,  ye1 = sy + (2 * Ly + 2) / 3;

    if (t < 48) {
        int y = sy + t;
        bool inb = (y < ey);
        msk[t][0] = (inb && y < ye0)              ? 1.f : 0.f;
        msk[t][1] = (inb && y >= ys1 && y < ye1)  ? 1.f : 0.f;
        msk[t][2] = (inb && y >= ys2)             ? 1.f : 0.f;
        msk[t][3] = 0.f;
    }
    __syncthreads();

    const int g   = t >> 4;
    const int lx  = t & 15;
    const int sx4 = sx & ~3;                 // 16B-aligned start
    const int xb  = sx4 + lx * 4;            // mask-domain base x
    const int lxmax = ((ex - 1) - sx4) >> 2; // last active lane
    const int xba = sx4 + ((lx < lxmax) ? lx : lxmax) * 4;  // in-box address

    float4 mx0, mx1, mx2;
    {
        float m0[4], m1[4], m2[4];
        #pragma unroll
        for (int e = 0; e < 4; ++e) {
            int xx = xb + e;
            m0[e] = (xx >= sx  && xx < xe0) ? 1.f : 0.f;
            m1[e] = (xx >= xs1 && xx < xe1) ? 1.f : 0.f;
            m2[e] = (xx >= xs2 && xx < ex ) ? 1.f : 0.f;
        }
        mx0 = make_float4(m0[0], m0[1], m0[2], m0[3]);
        mx1 = make_float4(m1[0], m1[1], m1[2], m1[3]);
        mx2 = make_float4(m2[0], m2[1], m2[2], m2[3]);
    }

    const int rows_n = ey - sy;             // 3..40
    const int nch    = (rows_n + 7) >> 3;   // 1..5 chunks of 8 rows

    const float w0 = (float)(xe0 - sx), w1 = (float)(xe1 - xs1), w2 = (float)(ex - xs2);
    const float h0 = (float)(ye0 - sy), h1r = (float)(ye1 - ys1), h2 = (float)(ey - ys2);

    for (int c = 0; c < 4; ++c) {
        const int dd = chalf * 64 + g + c * 16;    // channel 0..127
        const float* base = x + ((size_t)b * CH + dd) * HWSZ + xba;
        // y-cell vector accumulators: 12 FMA per row (vs 21 in fused version)
        float4 ac0 = make_float4(0.f,0.f,0.f,0.f);
        float4 ac1 = make_float4(0.f,0.f,0.f,0.f);
        float4 ac2 = make_float4(0.f,0.f,0.f,0.f);
        for (int ck = 0; ck < nch; ++ck) {
            const int y0 = sy + (ck << 3);
            float4 v[8];
            #pragma unroll
            for (int k = 0; k < 8; ++k) {
                int y = y0 + k;
                y = (y < ey) ? y : (ey - 1);        // in-box clamp; mask is 0
                v[k] = *(const float4*)(base + (size_t)y * WWID);
            }
            #pragma unroll
            for (int k = 0; k < 8; ++k) {
                const float4 m = *(const float4*)&msk[(y0 - sy) + k][0];
                ac0.x = fmaf(m.x, v[k].x, ac0.x); ac0.y = fmaf(m.x, v[k].y, ac0.y);
                ac0.z = fmaf(m.x, v[k].z, ac0.z); ac0.w = fmaf(m.x, v[k].w, ac0.w);
                ac1.x = fmaf(m.y, v[k].x, ac1.x); ac1.y = fmaf(m.y, v[k].y, ac1.y);
                ac1.z = fmaf(m.y, v[k].z, ac1.z); ac1.w = fmaf(m.y, v[k].w, ac1.w);
                ac2.x = fmaf(m.z, v[k].x, ac2.x); ac2.y = fmaf(m.z, v[k].y, ac2.y);
                ac2.z = fmaf(m.z, v[k].z, ac2.z); ac2.w = fmaf(m.z, v[k].w, ac2.w);
            }
        }
        // x-cell dots once per channel
        float a[9];
        a[0] = dot4(mx0, ac0, 0.f); a[1] = dot4(mx1, ac0, 0.f); a[2] = dot4(mx2, ac0, 0.f);
        a[3] = dot4(mx0, ac1, 0.f); a[4] = dot4(mx1, ac1, 0.f); a[5] = dot4(mx2, ac1, 0.f);
        a[6] = dot4(mx0, ac2, 0.f); a[7] = dot4(mx1, ac2, 0.f); a[8] = dot4(mx2, ac2, 0.f);
        #pragma unroll
        for (int jj = 0; jj < 9; ++jj) {
            a[jj] += __shfl_xor(a[jj], 8);
            a[jj] += __shfl_xor(a[jj], 4);
            a[jj] += __shfl_xor(a[jj], 2);
            a[jj] += __shfl_xor(a[jj], 1);
        }
        if (lx == 0) {
            float* kd = kout + (size_t)det * KSTRIDE + dd;
            kd[0*CH] = a[0] / (h0  * w0);
            kd[1*CH] = a[1] / (h0  * w1);
            kd[2*CH] = a[2] / (h0  * w2);
            kd[3*CH] = a[3] / (h1r * w0);
            kd[4*CH] = a[4] / (h1r * w1);
            kd[5*CH] = a[5] / (h1r * w2);
            kd[6*CH] = a[6] / (h2  * w0);
            kd[7*CH] = a[7] / (h2  * w1);
            kd[8*CH] = a[8] / (h2  * w2);
        }
    }
}

// ============================================================================
// Kernel 2: transformer per det (reads pooled k from ws) + second copy half
// ============================================================================
__global__ __launch_bounds__(256) void er_det(
    const float* __restrict__ x, const float* __restrict__ vis,
    const int* __restrict__ inds, const float* __restrict__ kin,
    const float* __restrict__ Wqkv, const float* __restrict__ bqkv,
    const float* __restrict__ Wo,   const float* __restrict__ bo,
    const float* __restrict__ W1,   const float* __restrict__ b1,
    const float* __restrict__ W2,   const float* __restrict__ b2,
    const float* __restrict__ g2,   const float* __restrict__ be2,
    const float* __restrict__ g3,   const float* __restrict__ be3,
    float* __restrict__ out, float* __restrict__ rows)
{
    const int bid = blockIdx.x;
    const int t   = threadIdx.x;

    if (bid >= NDB) {
        // ---- streaming copy, second half ----
        const size_t n4   = (size_t)BB * CH * HWSZ / 4;
        const size_t half = n4 / 2;
        const f4v* s4 = (const f4v*)x;
        f4v* o4 = (f4v*)out;
        size_t i = half + (size_t)(bid - NDB) * 256 + t;
        const size_t stride = (size_t)(gridDim.x - NDB) * 256;
        for (; i < n4; i += stride) {
            f4v v = s4[i];
            __builtin_nontemporal_store(v, &o4[i]);
        }
        return;
    }

    __shared__ float kbuf[9][CH];
    __shared__ float qv[CH];
    __shared__ float qp[CH];
    __shared__ float kp[9][CH];
    __shared__ float vp[9][CH];
    __shared__ float att[NHEAD][9];
    __shared__ float aov[CH];
    __shared__ float tv[CH];
    __shared__ float h1[DFF];
    __shared__ float part[256];
    __shared__ float redA[4], redB[4];

    const int det_idx = bid;
    const int b = det_idx >> 7;
    const int n = det_idx & (NDET - 1);
    const int p = inds[b * NDET + n];

    // ---- load pooled k (coalesced) ----
    {
        const float* ks = kin + (size_t)det_idx * KSTRIDE;
        float* kd = (float*)kbuf;
        for (int i = t; i < KSTRIDE; i += 256) kd[i] = ks[i];
    }

    // ---- q gather + vis positional embedding (threads 0..127) ----
    if (t < CH) {
        float qval = x[((size_t)b * CH + t) * HWSZ + p];
        float vv   = vis[(size_t)b * HWSZ + p];
        int vidx   = (int)(vv * 10.0f);
        float fr   = powf(10000.0f, -(float)(t & 126) * (1.0f / 128.0f));
        float ang  = 0.1f * (float)vidx * fr;
        float pe   = (t & 1) ? cosf(ang) : sinf(ang);
        qv[t] = qval + pe;
    }
    __syncthreads();

    // ---- qp = Wq @ q + bq ----
    if (t < CH) {
        const float4* wr = (const float4*)(Wqkv + (size_t)t * CH);
        const float4* qq = (const float4*)qv;
        float s = 0.f;
        #pragma unroll 8
        for (int i = 0; i < CH / 4; ++i) s = dot4(wr[i], qq[i], s);
        qp[t] = s + bqkv[t];
    }

    // ---- kp/vp = {Wk,Wv} @ k + {bk,bv} : 256 threads = 128 outs x {k,v} ----
    {
        const int o = t & (CH - 1);
        const int which = t >> 7;  // 0 -> k, 1 -> v
        const float4* wr = (const float4*)(Wqkv + (size_t)(CH + which * CH + o) * CH);
        float acc[9] = {0.f,0.f,0.f,0.f,0.f,0.f,0.f,0.f,0.f};
        #pragma unroll 4
        for (int i = 0; i < CH / 4; ++i) {
            float4 w = wr[i];
            #pragma unroll
            for (int s = 0; s < 9; ++s) {
                float4 kk = ((const float4*)(&kbuf[s][0]))[i];
                acc[s] = dot4(w, kk, acc[s]);
            }
        }
        float bias = bqkv[CH + which * CH + o];
        if (which == 0) {
            #pragma unroll
            for (int s = 0; s < 9; ++s) kp[s][o] = acc[s] + bias;
        } else {
            #pragma unroll
            for (int s = 0; s < 9; ++s) vp[s][o] = acc[s] + bias;
        }
    }
    __syncthreads();

    // ---- attention scores (72 dots of len 16) ----
    if (t < NHEAD * 9) {
        int h = t / 9, s = t - h * 9;
        const float* qh = qp + h * HDIM;
        const float* kh = &kp[s][h * HDIM];
        float a = 0.f;
        #pragma unroll
        for (int e = 0; e < HDIM; ++e) a = fmaf(qh[e], kh[e], a);
        att[h][s] = a * 0.25f;   // / sqrt(16)
    }
    __syncthreads();

    // ---- softmax over s=9, per head ----
    if (t < NHEAD) {
        float m = att[t][0];
        #pragma unroll
        for (int s = 1; s < 9; ++s) m = fmaxf(m, att[t][s]);
        float e[9]; float sum = 0.f;
        #pragma unroll
        for (int s = 0; s < 9; ++s) { e[s] = expf(att[t][s] - m); sum += e[s]; }
        float inv = 1.0f / sum;
        #pragma unroll
        for (int s = 0; s < 9; ++s) att[t][s] = e[s] * inv;
    }
    __syncthreads();

    // ---- ao = att @ vp ----
    if (t < CH) {
        int h = t >> 4;
        float a = 0.f;
        #pragma unroll
        for (int s = 0; s < 9; ++s) a = fmaf(att[h][s], vp[s][t], a);
        aov[t] = a;
    }
    __syncthreads();

    // ---- ao2 = Wo @ ao + bo; resid; LN1 ----
    float v1 = 0.f;
    if (t < CH) {
        const float4* wr = (const float4*)(Wo + (size_t)t * CH);
        const float4* u4 = (const float4*)aov;
        float s = 0.f;
        #pragma unroll 8
        for (int i = 0; i < CH / 4; ++i) s = dot4(wr[i], u4[i], s);
        v1 = qv[t] + s + bo[t];
    }
    float t1 = block_layernorm(v1, t, g2, be2, redA, redB);
    if (t < CH) tv[t] = t1;
    __syncthreads();

    // ---- FFN: h1 = relu(W1 @ t + b1), 512 outs over 256 threads x2 ----
    #pragma unroll
    for (int rep = 0; rep < 2; ++rep) {
        int o = t + rep * 256;
        const float4* wr = (const float4*)(W1 + (size_t)o * CH);
        const float4* u4 = (const float4*)tv;
        float s = 0.f;
        #pragma unroll 8
        for (int i = 0; i < CH / 4; ++i) s = dot4(wr[i], u4[i], s);
        h1[o] = fmaxf(s + b1[o], 0.f);
    }
    __syncthreads();

    // ---- t2 = W2 @ h1 + b2 : 128 outs, split dot over 2 halves ----
    {
        int o = t & (CH - 1), hf = t >> 7;
        const float4* wr = (const float4*)(W2 + (size_t)o * DFF + hf * (DFF / 2));
        const float4* u4 = (const float4*)(h1 + hf * (DFF / 2));
        float s = 0.f;
        #pragma unroll 8
        for (int i = 0; i < DFF / 8; ++i) s = dot4(wr[i], u4[i], s);
        part[t] = s;
    }
    __syncthreads();

    float v2 = 0.f;
    if (t < CH) {
        float t2 = part[t] + part[t + 128] + b2[t];
        v2 = tv[t] + t2;
    }
    float outv = block_layernorm(v2, t, g3, be3, redA, redB);
    if (t < CH) rows[(size_t)det_idx * CH + t] = outv;
}

// ============================================================================
// Fallback path (ws too small): copy, then fully-fused det kernel (round-5)
// ============================================================================
__global__ __launch_bounds__(256) void copy_x(const f4v* __restrict__ src,
                                              f4v* __restrict__ dst, size_t n4) {
    size_t i = (size_t)blockIdx.x * 256 + threadIdx.x;
    const size_t stride = (size_t)gridDim.x * 256;
    for (; i < n4; i += stride) {
        f4v v = src[i];
        __builtin_nontemporal_store(v, &dst[i]);
    }
}

__global__ __launch_bounds__(256) void er_fused_fb(
    const float* __restrict__ x, const float* __restrict__ vis,
    const int* __restrict__ dets, const int* __restrict__ inds,
    const float* __restrict__ Wqkv, const float* __restrict__ bqkv,
    const float* __restrict__ Wo,   const float* __restrict__ bo,
    const float* __restrict__ W1,   const float* __restrict__ b1,
    const float* __restrict__ W2,   const float* __restrict__ b2,
    const float* __restrict__ g2,   const float* __restrict__ be2,
    const float* __restrict__ g3,   const float* __restrict__ be3,
    float* __restrict__ out)
{
    const int bid = blockIdx.x;
    const int t   = threadIdx.x;

    __shared__ float kbuf[9][CH];
    __shared__ float qv[CH];
    __shared__ float qp[CH];
    __shared__ float kp[9][CH];
    __shared__ float vp[9][CH];
    __shared__ float att[NHEAD][9];
    __shared__ float aov[CH];
    __shared__ float tv[CH];
    __shared__ float h1[DFF];
    __shared__ float part[256];
    __shared__ float redA[4], redB[4];
    __shared__ float msk[48][4];

    const int b = bid >> 7;
    const int n = bid & (NDET - 1);

    const int4 dv = *((const int4*)(dets + (size_t)(b * NDET + n) * 4));
    const int sx = dv.x, sy = dv.y, ex = dv.z, ey = dv.w;
    const int Lx = ex - sx, Ly = ey - sy;
    const int xs1 = sx + Lx / 3,        xs2 = sx + 2 * Lx / 3;
    const int xe0 = sx + (Lx + 2) / 3,  xe1 = sx + (2 * Lx + 2) / 3;
    const int ys1 = sy + Ly / 3,        ys2 = sy + 2 * Ly / 3;
    const int ye0 = sy + (Ly + 2) / 3,  ye1 = sy + (2 * Ly + 2) / 3;

    const int p = inds[b * NDET + n];

    if (t < 48) {
        int y = sy + t;
        bool inb = (y < ey);
        msk[t][0] = (inb && y < ye0)              ? 1.f : 0.f;
        msk[t][1] = (inb && y >= ys1 && y < ye1)  ? 1.f : 0.f;
        msk[t][2] = (inb && y >= ys2)             ? 1.f : 0.f;
        msk[t][3] = 0.f;
    }
    if (t < CH) {
        float qval = x[((size_t)b * CH + t) * HWSZ + p];
        float vv   = vis[(size_t)b * HWSZ + p];
        int vidx   = (int)(vv * 10.0f);
        float fr   = powf(10000.0f, -(float)(t & 126) * (1.0f / 128.0f));
        float ang  = 0.1f * (float)vidx * fr;
        float pe   = (t & 1) ? cosf(ang) : sinf(ang);
        qv[t] = qval + pe;
    }
    __syncthreads();

    {
        const int g   = t >> 4;
        const int lx  = t & 15;
        const int sx4 = sx & ~3;
        const int xb  = sx4 + lx * 4;
        const int lxmax = ((ex - 1) - sx4) >> 2;
        const int xba = sx4 + ((lx < lxmax) ? lx : lxmax) * 4;

        float4 mx0, mx1, mx2;
        {
            float m0[4], m1[4], m2[4];
            #pragma unroll
            for (int e = 0; e < 4; ++e) {
                int xx = xb + e;
                m0[e] = (xx >= sx  && xx < xe0) ? 1.f : 0.f;
                m1[e] = (xx >= xs1 && xx < xe1) ? 1.f : 0.f;
                m2[e] = (xx >= xs2 && xx < ex ) ? 1.f : 0.f;
            }
            mx0 = make_float4(m0[0], m0[1], m0[2], m0[3]);
            mx1 = make_float4(m1[0], m1[1], m1[2], m1[3]);
            mx2 = make_float4(m2[0], m2[1], m2[2], m2[3]);
        }

        const int rows_n = ey - sy;
        const int nch    = (rows_n + 7) >> 3;

        for (int c = 0; c < 8; ++c) {
            const int dd = g + c * 16;
            const float* base = x + ((size_t)b * CH + dd) * HWSZ + xba;
            float4 ac0 = make_float4(0.f,0.f,0.f,0.f);
            float4 ac1 = make_float4(0.f,0.f,0.f,0.f);
            float4 ac2 = make_float4(0.f,0.f,0.f,0.f);
            for (int ck = 0; ck < nch; ++ck) {
                const int y0 = sy + (ck << 3);
                float4 v[8];
                #pragma unroll
                for (int k = 0; k < 8; ++k) {
                    int y = y0 + k;
                    y = (y < ey) ? y : (ey - 1);
                    v[k] = *(const float4*)(base + (size_t)y * WWID);
                }
                #pragma unroll
                for (int k = 0; k < 8; ++k) {
                    const float4 m = *(const float4*)&msk[(y0 - sy) + k][0];
                    ac0.x = fmaf(m.x, v[k].x, ac0.x); ac0.y = fmaf(m.x, v[k].y, ac0.y);
                    ac0.z = fmaf(m.x, v[k].z, ac0.z); ac0.w = fmaf(m.x, v[k].w, ac0.w);
                    ac1.x = fmaf(m.y, v[k].x, ac1.x); ac1.y = fmaf(m.y, v[k].y, ac1.y);
                    ac1.z = fmaf(m.y, v[k].z, ac1.z); ac1.w = fmaf(m.y, v[k].w, ac1.w);
                    ac2.x = fmaf(m.z, v[k].x, ac2.x); ac2.y = fmaf(m.z, v[k].y, ac2.y);
                    ac2.z = fmaf(m.z, v[k].z, ac2.z); ac2.w = fmaf(m.z, v[k].w, ac2.w);
                }
            }
            float a[9];
            a[0] = dot4(mx0, ac0, 0.f); a[1] = dot4(mx1, ac0, 0.f); a[2] = dot4(mx2, ac0, 0.f);
            a[3] = dot4(mx0, ac1, 0.f); a[4] = dot4(mx1, ac1, 0.f); a[5] = dot4(mx2, ac1, 0.f);
            a[6] = dot4(mx0, ac2, 0.f); a[7] = dot4(mx1, ac2, 0.f); a[8] = dot4(mx2, ac2, 0.f);
            #pragma unroll
            for (int jj = 0; jj < 9; ++jj) {
                a[jj] += __shfl_xor(a[jj], 8);
                a[jj] += __shfl_xor(a[jj], 4);
                a[jj] += __shfl_xor(a[jj], 2);
                a[jj] += __shfl_xor(a[jj], 1);
            }
            if (lx == 0) {
                int w0 = xe0 - sx, w1 = xe1 - xs1, w2 = ex - xs2;
                int h0 = ye0 - sy, h1r = ye1 - ys1, h2 = ey - ys2;
                kbuf[0][dd] = a[0] / (float)(h0 * w0);
                kbuf[1][dd] = a[1] / (float)(h0 * w1);
                kbuf[2][dd] = a[2] / (float)(h0 * w2);
                kbuf[3][dd] = a[3] / (float)(h1r * w0);
                kbuf[4][dd] = a[4] / (float)(h1r * w1);
                kbuf[5][dd] = a[5] / (float)(h1r * w2);
                kbuf[6][dd] = a[6] / (float)(h2 * w0);
                kbuf[7][dd] = a[7] / (float)(h2 * w1);
                kbuf[8][dd] = a[8] / (float)(h2 * w2);
            }
        }
    }
    __syncthreads();

    if (t < CH) {
        const float4* wr = (const float4*)(Wqkv + (size_t)t * CH);
        const float4* qq = (const float4*)qv;
        float s = 0.f;
        #pragma unroll 8
        for (int i = 0; i < CH / 4; ++i) s = dot4(wr[i], qq[i], s);
        qp[t] = s + bqkv[t];
    }
    {
        const int o = t & (CH - 1);
        const int which = t >> 7;
        const float4* wr = (const float4*)(Wqkv + (size_t)(CH + which * CH + o) * CH);
        float acc[9] = {0.f,0.f,0.f,0.f,0.f,0.f,0.f,0.f,0.f};
        #pragma unroll 4
        for (int i = 0; i < CH / 4; ++i) {
            float4 w = wr[i];
            #pragma unroll
            for (int s = 0; s < 9; ++s) {
                float4 kk = ((const float4*)(&kbuf[s][0]))[i];
                acc[s] = dot4(w, kk, acc[s]);
            }
        }
        float bias = bqkv[CH + which * CH + o];
        if (which == 0) {
            #pragma unroll
            for (int s = 0; s < 9; ++s) kp[s][o] = acc[s] + bias;
        } else {
            #pragma unroll
            for (int s = 0; s < 9; ++s) vp[s][o] = acc[s] + bias;
        }
    }
    __syncthreads();

    if (t < NHEAD * 9) {
        int h = t / 9, s = t - h * 9;
        const float* qh = qp + h * HDIM;
        const float* kh = &kp[s][h * HDIM];
        float a = 0.f;
        #pragma unroll
        for (int e = 0; e < HDIM; ++e) a = fmaf(qh[e], kh[e], a);
        att[h][s] = a * 0.25f;
    }
    __syncthreads();

    if (t < NHEAD) {
        float m = att[t][0];
        #pragma unroll
        for (int s = 1; s < 9; ++s) m = fmaxf(m, att[t][s]);
        float e[9]; float sum = 0.f;
        #pragma unroll
        for (int s = 0; s < 9; ++s) { e[s] = expf(att[t][s] - m); sum += e[s]; }
        float inv = 1.0f / sum;
        #pragma unroll
        for (int s = 0; s < 9; ++s) att[t][s] = e[s] * inv;
    }
    __syncthreads();

    if (t < CH) {
        int h = t >> 4;
        float a = 0.f;
        #pragma unroll
        for (int s = 0; s < 9; ++s) a = fmaf(att[h][s], vp[s][t], a);
        aov[t] = a;
    }
    __syncthreads();

    float v1 = 0.f;
    if (t < CH) {
        const float4* wr = (const float4*)(Wo + (size_t)t * CH);
        const float4* u4 = (const float4*)aov;
        float s = 0.f;
        #pragma unroll 8
        for (int i = 0; i < CH / 4; ++i) s = dot4(wr[i], u4[i], s);
        v1 = qv[t] + s + bo[t];
    }
    float t1 = block_layernorm(v1, t, g2, be2, redA, redB);
    if (t < CH) tv[t] = t1;
    __syncthreads();

    #pragma unroll
    for (int rep = 0; rep < 2; ++rep) {
        int o = t + rep * 256;
        const float4* wr = (const float4*)(W1 + (size_t)o * CH);
        const float4* u4 = (const float4*)tv;
        float s = 0.f;
        #pragma unroll 8
        for (int i = 0; i < CH / 4; ++i) s = dot4(wr[i], u4[i], s);
        h1[o] = fmaxf(s + b1[o], 0.f);
    }
    __syncthreads();

    {
        int o = t & (CH - 1), hf = t >> 7;
        const float4* wr = (const float4*)(W2 + (size_t)o * DFF + hf * (DFF / 2));
        const float4* u4 = (const float4*)(h1 + hf * (DFF / 2));
        float s = 0.f;
        #pragma unroll 8
        for (int i = 0; i < DFF / 8; ++i) s = dot4(wr[i], u4[i], s);
        part[t] = s;
    }
    __syncthreads();

    float v2 = 0.f;
    if (t < CH) {
        float t2 = part[t] + part[t + 128] + b2[t];
        v2 = tv[t] + t2;
    }
    float outv = block_layernorm(v2, t, g3, be3, redA, redB);
    if (t < CH) out[((size_t)b * CH + t) * HWSZ + p] = outv;
}

__global__ __launch_bounds__(256) void scatter_rows(const float* __restrict__ rows,
                                                    const int* __restrict__ inds,
                                                    float* __restrict__ out) {
    int i = blockIdx.x * 256 + threadIdx.x;   // over B*NDET*CH
    int dd = i & (CH - 1);
    int bn = i >> 7;
    int b  = bn >> 7;
    int p  = inds[bn];
    out[((size_t)b * CH + dd) * HWSZ + p] = rows[i];
}

extern "C" void kernel_launch(void* const* d_in, const int* in_sizes, int n_in,
                              void* d_out, int out_size, void* d_ws, size_t ws_size,
                              hipStream_t stream) {
    const float* x    = (const float*)d_in[0];
    const float* vis  = (const float*)d_in[1];
    const int*   dets = (const int*)d_in[2];
    const int*   inds = (const int*)d_in[3];
    const float* Wqkv = (const float*)d_in[4];
    const float* bqkv = (const float*)d_in[5];
    const float* Wo   = (const float*)d_in[6];
    const float* bo   = (const float*)d_in[7];
    const float* W1   = (const float*)d_in[8];
    const float* b1   = (const float*)d_in[9];
    const float* W2   = (const float*)d_in[10];
    const float* b2   = (const float*)d_in[11];
    const float* g2   = (const float*)d_in[12];
    const float* be2  = (const float*)d_in[13];
    const float* g3   = (const float*)d_in[14];
    const float* be3  = (const float*)d_in[15];
    float* out = (float*)d_out;

    const size_t need = ((size_t)NDB * KSTRIDE + (size_t)NDB * CH) * sizeof(float);
    if (ws_size >= need) {
        float* kout = (float*)d_ws;                       // 1024*1152 floats
        float* rows = kout + (size_t)NDB * KSTRIDE;       // 1024*128 floats
        pool_copy<<<dim3(NPOOL + NCOPY1), dim3(256), 0, stream>>>(x, dets, kout, out);
        er_det<<<dim3(NDB + NCOPY2), dim3(256), 0, stream>>>(
            x, vis, inds, kout, Wqkv, bqkv, Wo, bo, W1, b1, W2, b2,
            g2, be2, g3, be3, out, rows);
        scatter_rows<<<dim3((NDB * CH) / 256), dim3(256), 0, stream>>>(
            rows, inds, out);
    } else {
        // fallback: copy first, then fully-fused det blocks write direct
        copy_x<<<dim3(2048), dim3(256), 0, stream>>>(
            (const f4v*)x, (f4v*)out, (size_t)BB * CH * HWSZ / 4);
        er_fused_fb<<<dim3(NDB), dim3(256), 0, stream>>>(
            x, vis, dets, inds, Wqkv, bqkv, Wo, bo, W1, b1, W2, b2,
            g2, be2, g3, be3, out);
    }
}

// Round 7
// 198.654 us; speedup vs baseline: 1.0467x; 1.0467x over previous
//
#include <hip/hip_runtime.h>
#include <math.h>

#define BB 8
#define CH 128
#define HH 152
#define WWID 272
#define HWSZ (HH*WWID)
#define NDET 128
#define NHEAD 8
#define HDIM 16
#define DFF 512
#define NDB (BB*NDET)      // 1024 dets
#define NPOOL (2*NDB)      // 2048 pooling blocks: (det, channel-half)
#define KSTRIDE 1152       // 9*CH floats of pooled k per det

typedef float f4v __attribute__((ext_vector_type(4)));

__device__ __forceinline__ float dot4(float4 w, float4 u, float s) {
    s = fmaf(w.x, u.x, s);
    s = fmaf(w.y, u.y, s);
    s = fmaf(w.z, u.z, s);
    s = fmaf(w.w, u.w, s);
    return s;
}

// streaming copy of float4 range [beg,end) using ncb blocks of nthr threads
__device__ __forceinline__ void copy_range(const float* __restrict__ x,
                                           float* __restrict__ out,
                                           size_t beg, size_t end,
                                           int cb, int ncb, int t, int nthr) {
    const f4v* s4 = (const f4v*)x;
    f4v* o4 = (f4v*)out;
    size_t i = beg + (size_t)cb * nthr + t;
    const size_t stride = (size_t)ncb * nthr;
    for (; i < end; i += stride) {
        f4v v = s4[i];
        __builtin_nontemporal_store(v, &o4[i]);   // don't evict x from L3
    }
}

// ============================================================================
// K1: adaptive 3x3 pooling (det x channel-half) + copy share
// ============================================================================
__global__ __launch_bounds__(256) void pool_copy(
    const float* __restrict__ x, const int* __restrict__ dets,
    float* __restrict__ kout, float* __restrict__ out,
    size_t cbeg, size_t cend, int ncb)
{
    const int bid = blockIdx.x;
    const int t   = threadIdx.x;

    if (bid >= NPOOL) {
        copy_range(x, out, cbeg, cend, bid - NPOOL, ncb, t, 256);
        return;
    }

    __shared__ float msk[48][4];   // per-row y-cell masks {m0,m1,m2,0}

    const int det   = bid >> 1;
    const int chalf = bid & 1;
    const int b = det >> 7;
    const int n = det & (NDET - 1);

    const int4 dv = *((const int4*)(dets + (size_t)(b * NDET + n) * 4));
    const int sx = dv.x, sy = dv.y, ex = dv.z, ey = dv.w;
    const int Lx = ex - sx, Ly = ey - sy;
    // cell edges (cells OVERLAP due to floor/ceil in reference)
    const int xs1 = sx + Lx / 3,        xs2 = sx + 2 * Lx / 3;
    const int xe0 = sx + (Lx + 2) / 3,  xe1 = sx + (2 * Lx + 2) / 3;
    const int ys1 = sy + Ly / 3,        ys2 = sy + 2 * Ly / 3;
    const int ye0 = sy + (Ly + 2) / 3,  ye1 = sy + (2 * Ly + 2) / 3;

    if (t < 48) {
        int y = sy + t;
        bool inb = (y < ey);
        msk[t][0] = (inb && y < ye0)              ? 1.f : 0.f;
        msk[t][1] = (inb && y >= ys1 && y < ye1)  ? 1.f : 0.f;
        msk[t][2] = (inb && y >= ys2)             ? 1.f : 0.f;
        msk[t][3] = 0.f;
    }
    __syncthreads();

    const int g   = t >> 4;
    const int lx  = t & 15;
    const int sx4 = sx & ~3;
    const int xb  = sx4 + lx * 4;
    const int lxmax = ((ex - 1) - sx4) >> 2;
    const int xba = sx4 + ((lx < lxmax) ? lx : lxmax) * 4;   // in-box address

    float4 mx0, mx1, mx2;
    {
        float m0[4], m1[4], m2[4];
        #pragma unroll
        for (int e = 0; e < 4; ++e) {
            int xx = xb + e;
            m0[e] = (xx >= sx  && xx < xe0) ? 1.f : 0.f;
            m1[e] = (xx >= xs1 && xx < xe1) ? 1.f : 0.f;
            m2[e] = (xx >= xs2 && xx < ex ) ? 1.f : 0.f;
        }
        mx0 = make_float4(m0[0], m0[1], m0[2], m0[3]);
        mx1 = make_float4(m1[0], m1[1], m1[2], m1[3]);
        mx2 = make_float4(m2[0], m2[1], m2[2], m2[3]);
    }

    const int rows_n = ey - sy;
    const int nch    = (rows_n + 7) >> 3;

    const float w0 = (float)(xe0 - sx), w1 = (float)(xe1 - xs1), w2 = (float)(ex - xs2);
    const float h0 = (float)(ye0 - sy), h1r = (float)(ye1 - ys1), h2 = (float)(ey - ys2);

    for (int c = 0; c < 4; ++c) {
        const int dd = chalf * 64 + g + c * 16;
        const float* base = x + ((size_t)b * CH + dd) * HWSZ + xba;
        float4 ac0 = make_float4(0.f,0.f,0.f,0.f);
        float4 ac1 = make_float4(0.f,0.f,0.f,0.f);
        float4 ac2 = make_float4(0.f,0.f,0.f,0.f);
        for (int ck = 0; ck < nch; ++ck) {
            const int y0 = sy + (ck << 3);
            float4 v[8];
            #pragma unroll
            for (int k = 0; k < 8; ++k) {
                int y = y0 + k;
                y = (y < ey) ? y : (ey - 1);
                v[k] = *(const float4*)(base + (size_t)y * WWID);
            }
            #pragma unroll
            for (int k = 0; k < 8; ++k) {
                const float4 m = *(const float4*)&msk[(y0 - sy) + k][0];
                ac0.x = fmaf(m.x, v[k].x, ac0.x); ac0.y = fmaf(m.x, v[k].y, ac0.y);
                ac0.z = fmaf(m.x, v[k].z, ac0.z); ac0.w = fmaf(m.x, v[k].w, ac0.w);
                ac1.x = fmaf(m.y, v[k].x, ac1.x); ac1.y = fmaf(m.y, v[k].y, ac1.y);
                ac1.z = fmaf(m.y, v[k].z, ac1.z); ac1.w = fmaf(m.y, v[k].w, ac1.w);
                ac2.x = fmaf(m.z, v[k].x, ac2.x); ac2.y = fmaf(m.z, v[k].y, ac2.y);
                ac2.z = fmaf(m.z, v[k].z, ac2.z); ac2.w = fmaf(m.z, v[k].w, ac2.w);
            }
        }
        float a[9];
        a[0] = dot4(mx0, ac0, 0.f); a[1] = dot4(mx1, ac0, 0.f); a[2] = dot4(mx2, ac0, 0.f);
        a[3] = dot4(mx0, ac1, 0.f); a[4] = dot4(mx1, ac1, 0.f); a[5] = dot4(mx2, ac1, 0.f);
        a[6] = dot4(mx0, ac2, 0.f); a[7] = dot4(mx1, ac2, 0.f); a[8] = dot4(mx2, ac2, 0.f);
        #pragma unroll
        for (int jj = 0; jj < 9; ++jj) {
            a[jj] += __shfl_xor(a[jj], 8);
            a[jj] += __shfl_xor(a[jj], 4);
            a[jj] += __shfl_xor(a[jj], 2);
            a[jj] += __shfl_xor(a[jj], 1);
        }
        if (lx == 0) {
            float* kd = kout + (size_t)det * KSTRIDE + dd;
            kd[0*CH] = a[0] / (h0  * w0);
            kd[1*CH] = a[1] / (h0  * w1);
            kd[2*CH] = a[2] / (h0  * w2);
            kd[3*CH] = a[3] / (h1r * w0);
            kd[4*CH] = a[4] / (h1r * w1);
            kd[5*CH] = a[5] / (h1r * w2);
            kd[6*CH] = a[6] / (h2  * w0);
            kd[7*CH] = a[7] / (h2  * w1);
            kd[8*CH] = a[8] / (h2  * w2);
        }
    }
}

// ============================================================================
// K2: QKV projection GEMM. kv-role: 512 blocks x 2 dets (18 rows);
//     q-role: 64 blocks x 16 dets (gather + posemb + GEMV); + copy.
// ============================================================================
#define K2_KV 512
#define K2_Q  64
__global__ __launch_bounds__(256) void qkv_kernel(
    const float* __restrict__ x, const float* __restrict__ vis,
    const int* __restrict__ inds, const float* __restrict__ kout,
    const float* __restrict__ Wqkv, const float* __restrict__ bqkv,
    float* __restrict__ kvp, float* __restrict__ qpb, float* __restrict__ qvb,
    float* __restrict__ out, size_t cbeg, size_t cend, int ncb)
{
    const int bid = blockIdx.x;
    const int t   = threadIdx.x;

    if (bid >= K2_KV + K2_Q) {
        copy_range(x, out, cbeg, cend, bid - (K2_KV + K2_Q), ncb, t, 256);
        return;
    }

    __shared__ float As[2304];   // kv: 18x128 rows; q: 16x128 rows

    if (bid < K2_KV) {
        // ---- kp/vp for 2 dets = 18 rows, all 256 (o,which) weight rows ----
        const int d0 = bid * 2;
        const float4* src = (const float4*)(kout + (size_t)d0 * KSTRIDE);
        for (int i = t; i < 576; i += 256) ((float4*)As)[i] = src[i];
        __syncthreads();

        const int o = t & 127, which = t >> 7;
        const float4* wr = (const float4*)(Wqkv + (size_t)(CH + which * CH + o) * CH);
        float acc[18];
        #pragma unroll
        for (int r = 0; r < 18; ++r) acc[r] = 0.f;
        for (int i = 0; i < 32; ++i) {
            float4 w = wr[i];
            #pragma unroll
            for (int r = 0; r < 18; ++r) {
                float4 a = ((const float4*)(As + r * 128))[i];   // broadcast
                acc[r] = dot4(w, a, acc[r]);
            }
        }
        const float bias = bqkv[CH + which * CH + o];
        #pragma unroll
        for (int r = 0; r < 18; ++r) {
            int det = d0 + (r / 9), slot = r % 9;
            kvp[(((size_t)det * 2 + which) * 9 + slot) * CH + o] = acc[r] + bias;
        }
    } else {
        // ---- q: gather + posemb for 16 dets, then qp GEMV ----
        const int dg = (bid - K2_KV) * 16;
        const int o  = t & 127;
        const int rh = t >> 7;
        const float fr = powf(10000.0f, -(float)(o & 126) * (1.0f / 128.0f));
        for (int j = 0; j < 8; ++j) {
            int r = rh + 2 * j;
            int det = dg + r;
            int b = det >> 7, n = det & 127;
            int p = inds[b * NDET + n];
            float qval = x[((size_t)b * CH + o) * HWSZ + p];
            float vv   = vis[(size_t)b * HWSZ + p];
            int vidx   = (int)(vv * 10.0f);
            float ang  = 0.1f * (float)vidx * fr;
            float pe   = (o & 1) ? cosf(ang) : sinf(ang);
            float q = qval + pe;
            As[r * 128 + o] = q;
            qvb[(size_t)det * CH + o] = q;
        }
        __syncthreads();
        const float4* wr = (const float4*)(Wqkv + (size_t)o * CH);   // Wq row o
        float acc[8] = {0.f,0.f,0.f,0.f,0.f,0.f,0.f,0.f};
        for (int i = 0; i < 32; ++i) {
            float4 w = wr[i];
            #pragma unroll
            for (int j = 0; j < 8; ++j) {
                float4 a = ((const float4*)(As + (rh + 2 * j) * 128))[i];
                acc[j] = dot4(w, a, acc[j]);
            }
        }
        const float bias = bqkv[o];
        #pragma unroll
        for (int j = 0; j < 8; ++j)
            qpb[(size_t)(dg + rh + 2 * j) * CH + o] = acc[j] + bias;
    }
}

// ============================================================================
// K3: attention per det (64 threads, no weights) + copy
// ============================================================================
__global__ __launch_bounds__(64) void attn_kernel(
    const float* __restrict__ kvp, const float* __restrict__ qpb,
    const float* __restrict__ x, float* __restrict__ aovb,
    float* __restrict__ out, size_t cbeg, size_t cend, int ncb)
{
    const int bid = blockIdx.x;
    const int t   = threadIdx.x;

    if (bid >= NDB) {
        copy_range(x, out, cbeg, cend, bid - NDB, ncb, t, 64);
        return;
    }

    __shared__ float qpl[CH];
    __shared__ float kpl[9][CH];
    __shared__ float vpl[9][CH];
    __shared__ float attl[NHEAD][9];

    const int det = bid;
    const float4* kph = (const float4*)(kvp + (size_t)det * 2 * 9 * CH);
    for (int i = t; i < 288; i += 64) ((float4*)kpl)[i] = kph[i];
    for (int i = t; i < 288; i += 64) ((float4*)vpl)[i] = kph[288 + i];
    for (int i = t; i < 32;  i += 64) ((float4*)qpl)[i] = ((const float4*)(qpb + (size_t)det * CH))[i];
    __syncthreads();

    for (int pr = t; pr < NHEAD * 9; pr += 64) {
        int h = pr / 9, s = pr - h * 9;
        const float* qh = qpl + h * HDIM;
        const float* kh = &kpl[s][h * HDIM];
        float a = 0.f;
        #pragma unroll
        for (int e = 0; e < HDIM; ++e) a = fmaf(qh[e], kh[e], a);
        attl[h][s] = a * 0.25f;
    }
    __syncthreads();

    if (t < NHEAD) {
        float m = attl[t][0];
        #pragma unroll
        for (int s = 1; s < 9; ++s) m = fmaxf(m, attl[t][s]);
        float e[9]; float sum = 0.f;
        #pragma unroll
        for (int s = 0; s < 9; ++s) { e[s] = expf(attl[t][s] - m); sum += e[s]; }
        float inv = 1.0f / sum;
        #pragma unroll
        for (int s = 0; s < 9; ++s) attl[t][s] = e[s] * inv;
    }
    __syncthreads();

    for (int o = t; o < CH; o += 64) {
        int h = o >> 4;
        float a = 0.f;
        #pragma unroll
        for (int s = 0; s < 9; ++s) a = fmaf(attl[h][s], vpl[s][o], a);
        aovb[(size_t)det * CH + o] = a;
    }
}

// ============================================================================
// K4: ao@Wo^T + bo + qv resid + LN1 -> tv  (64 blocks x 16 dets) + copy
// ============================================================================
__global__ __launch_bounds__(256) void wo_ln1_kernel(
    const float* __restrict__ aovb, const float* __restrict__ qvb,
    const float* __restrict__ Wo, const float* __restrict__ bo,
    const float* __restrict__ g2, const float* __restrict__ be2,
    const float* __restrict__ x, float* __restrict__ tvb,
    float* __restrict__ out, size_t cbeg, size_t cend, int ncb)
{
    const int bid = blockIdx.x;
    const int t   = threadIdx.x;

    if (bid >= 64) {
        copy_range(x, out, cbeg, cend, bid - 64, ncb, t, 256);
        return;
    }

    __shared__ float A[16 * CH];
    __shared__ float Q[16 * CH];
    __shared__ float T[16][CH];
    __shared__ float stats[16][2];

    const int dg = bid * 16;
    {
        const float4* sa = (const float4*)(aovb + (size_t)dg * CH);
        const float4* sq = (const float4*)(qvb  + (size_t)dg * CH);
        for (int i = t; i < 512; i += 256) { ((float4*)A)[i] = sa[i]; ((float4*)Q)[i] = sq[i]; }
    }
    __syncthreads();

    const int o = t & 127, rh = t >> 7;
    {
        const float4* wr = (const float4*)(Wo + (size_t)o * CH);
        float acc[8] = {0.f,0.f,0.f,0.f,0.f,0.f,0.f,0.f};
        for (int i = 0; i < 32; ++i) {
            float4 w = wr[i];
            #pragma unroll
            for (int j = 0; j < 8; ++j) {
                float4 a = ((const float4*)(A + (rh + 2 * j) * CH))[i];
                acc[j] = dot4(w, a, acc[j]);
            }
        }
        const float bb = bo[o];
        #pragma unroll
        for (int j = 0; j < 8; ++j) {
            int r = rh + 2 * j;
            T[r][o] = Q[r * CH + o] + acc[j] + bb;
        }
    }
    __syncthreads();

    // LN stats: 16 rows x 16 lanes
    {
        const int row = t >> 4, l = t & 15;
        float s1 = 0.f, s2 = 0.f;
        #pragma unroll
        for (int m = 0; m < 8; ++m) {
            float v = T[row][l + 16 * m];
            s1 += v; s2 += v * v;
        }
        #pragma unroll
        for (int off = 8; off >= 1; off >>= 1) {
            s1 += __shfl_xor(s1, off);
            s2 += __shfl_xor(s2, off);
        }
        if (l == 0) { stats[row][0] = s1; stats[row][1] = s2; }
    }
    __syncthreads();

    const float gg = g2[o], bb2 = be2[o];
    #pragma unroll
    for (int j = 0; j < 8; ++j) {
        int r = rh + 2 * j;
        float m   = stats[r][0] * (1.0f / 128.0f);
        float var = stats[r][1] * (1.0f / 128.0f) - m * m;
        float tv  = (T[r][o] - m) * rsqrtf(var + 1e-5f) * gg + bb2;
        tvb[(size_t)(dg + r) * CH + o] = tv;
    }
}

// ============================================================================
// K5: FFN1 relu(tv@W1^T+b1) -> h1  (128 blocks: 16 dets x 256-col tile) + copy
// ============================================================================
__global__ __launch_bounds__(256) void ffn1_kernel(
    const float* __restrict__ tvb, const float* __restrict__ W1,
    const float* __restrict__ b1, const float* __restrict__ x,
    float* __restrict__ h1b, float* __restrict__ out,
    size_t cbeg, size_t cend, int ncb)
{
    const int bid = blockIdx.x;
    const int t   = threadIdx.x;

    if (bid >= 128) {
        copy_range(x, out, cbeg, cend, bid - 128, ncb, t, 256);
        return;
    }

    __shared__ float A[16 * CH];
    const int dg = (bid >> 1) * 16;
    const int o  = (bid & 1) * 256 + t;

    {
        const float4* sa = (const float4*)(tvb + (size_t)dg * CH);
        for (int i = t; i < 512; i += 256) ((float4*)A)[i] = sa[i];
    }
    __syncthreads();

    const float4* wr = (const float4*)(W1 + (size_t)o * CH);
    float acc[16];
    #pragma unroll
    for (int r = 0; r < 16; ++r) acc[r] = 0.f;
    for (int i = 0; i < 32; ++i) {
        float4 w = wr[i];
        #pragma unroll
        for (int r = 0; r < 16; ++r) {
            float4 a = ((const float4*)(A + r * CH))[i];
            acc[r] = dot4(w, a, acc[r]);
        }
    }
    const float bb = b1[o];
    #pragma unroll
    for (int r = 0; r < 16; ++r)
        h1b[(size_t)(dg + r) * DFF + o] = fmaxf(acc[r] + bb, 0.f);
}

// ============================================================================
// K6: FFN2 (h1@W2^T+b2) + tv resid + LN2 -> rows  (128 blocks x 8 dets) + copy
// ============================================================================
__global__ __launch_bounds__(256) void ffn2_ln2_kernel(
    const float* __restrict__ h1b, const float* __restrict__ tvb,
    const float* __restrict__ W2, const float* __restrict__ b2,
    const float* __restrict__ g3, const float* __restrict__ be3,
    const float* __restrict__ x, float* __restrict__ rowsb,
    float* __restrict__ out, size_t cbeg, size_t cend, int ncb)
{
    const int bid = blockIdx.x;
    const int t   = threadIdx.x;

    if (bid >= 128) {
        copy_range(x, out, cbeg, cend, bid - 128, ncb, t, 256);
        return;
    }

    __shared__ float A[8 * DFF];
    __shared__ float Tv[8 * CH];
    __shared__ float T[8][CH];
    __shared__ float stats[8][2];

    const int dg = bid * 8;
    {
        const float4* sa = (const float4*)(h1b + (size_t)dg * DFF);
        for (int i = t; i < 1024; i += 256) ((float4*)A)[i] = sa[i];
        const float4* st = (const float4*)(tvb + (size_t)dg * CH);
        for (int i = t; i < 256; i += 256) ((float4*)Tv)[i] = st[i];
    }
    __syncthreads();

    const int o = t & 127, rh = t >> 7;
    {
        const float4* wr = (const float4*)(W2 + (size_t)o * DFF);
        float acc[4] = {0.f,0.f,0.f,0.f};
        #pragma unroll 4
        for (int i = 0; i < 128; ++i) {
            float4 w = wr[i];
            #pragma unroll
            for (int j = 0; j < 4; ++j) {
                float4 a = ((const float4*)(A + (rh + 2 * j) * DFF))[i];
                acc[j] = dot4(w, a, acc[j]);
            }
        }
        const float bb = b2[o];
        #pragma unroll
        for (int j = 0; j < 4; ++j) {
            int r = rh + 2 * j;
            T[r][o] = Tv[r * CH + o] + acc[j] + bb;
        }
    }
    __syncthreads();

    // LN stats: 8 rows x 32 lanes
    {
        const int row = t >> 5, l = t & 31;
        float s1 = 0.f, s2 = 0.f;
        #pragma unroll
        for (int m = 0; m < 4; ++m) {
            float v = T[row][l + 32 * m];
            s1 += v; s2 += v * v;
        }
        #pragma unroll
        for (int off = 16; off >= 1; off >>= 1) {
            s1 += __shfl_xor(s1, off);
            s2 += __shfl_xor(s2, off);
        }
        if (l == 0) { stats[row][0] = s1; stats[row][1] = s2; }
    }
    __syncthreads();

    const float gg = g3[o], bb3 = be3[o];
    #pragma unroll
    for (int j = 0; j < 4; ++j) {
        int r = rh + 2 * j;
        float m   = stats[r][0] * (1.0f / 128.0f);
        float var = stats[r][1] * (1.0f / 128.0f) - m * m;
        float ov  = (T[r][o] - m) * rsqrtf(var + 1e-5f) * gg + bb3;
        rowsb[(size_t)(dg + r) * CH + o] = ov;
    }
}

// ============================================================================
// K7: scatter rows into out
// ============================================================================
__global__ __launch_bounds__(256) void scatter_rows(const float* __restrict__ rows,
                                                    const int* __restrict__ inds,
                                                    float* __restrict__ out) {
    int i = blockIdx.x * 256 + threadIdx.x;   // over B*NDET*CH
    int dd = i & (CH - 1);
    int bn = i >> 7;
    int b  = bn >> 7;
    int p  = inds[bn];
    out[((size_t)b * CH + dd) * HWSZ + p] = rows[i];
}

// ============================================================================
// Fallback path (ws too small): copy, then fully-fused det kernel (round-5)
// ============================================================================
__global__ __launch_bounds__(256) void copy_x(const f4v* __restrict__ src,
                                              f4v* __restrict__ dst, size_t n4) {
    size_t i = (size_t)blockIdx.x * 256 + threadIdx.x;
    const size_t stride = (size_t)gridDim.x * 256;
    for (; i < n4; i += stride) {
        f4v v = src[i];
        __builtin_nontemporal_store(v, &dst[i]);
    }
}

__device__ __forceinline__ float block_layernorm(float v, int t,
        const float* __restrict__ gamma, const float* __restrict__ beta,
        float* redA, float* redB) {
    float s1 = v, s2 = v * v;
    #pragma unroll
    for (int off = 32; off >= 1; off >>= 1) {
        s1 += __shfl_xor(s1, off);
        s2 += __shfl_xor(s2, off);
    }
    if ((t & 63) == 0) { redA[t >> 6] = s1; redB[t >> 6] = s2; }
    __syncthreads();
    float sum = redA[0] + redA[1] + redA[2] + redA[3];
    float sq  = redB[0] + redB[1] + redB[2] + redB[3];
    __syncthreads();
    float m   = sum * (1.0f / 128.0f);
    float var = sq  * (1.0f / 128.0f) - m * m;
    float r = 0.f;
    if (t < CH) r = (v - m) * rsqrtf(var + 1e-5f) * gamma[t] + beta[t];
    return r;
}

__global__ __launch_bounds__(256) void er_fused_fb(
    const float* __restrict__ x, const float* __restrict__ vis,
    const int* __restrict__ dets, const int* __restrict__ inds,
    const float* __restrict__ Wqkv, const float* __restrict__ bqkv,
    const float* __restrict__ Wo,   const float* __restrict__ bo,
    const float* __restrict__ W1,   const float* __restrict__ b1,
    const float* __restrict__ W2,   const float* __restrict__ b2,
    const float* __restrict__ g2,   const float* __restrict__ be2,
    const float* __restrict__ g3,   const float* __restrict__ be3,
    float* __restrict__ out)
{
    const int bid = blockIdx.x;
    const int t   = threadIdx.x;

    __shared__ float kbuf[9][CH];
    __shared__ float qv[CH];
    __shared__ float qp[CH];
    __shared__ float kp[9][CH];
    __shared__ float vp[9][CH];
    __shared__ float att[NHEAD][9];
    __shared__ float aov[CH];
    __shared__ float tv[CH];
    __shared__ float h1[DFF];
    __shared__ float part[256];
    __shared__ float redA[4], redB[4];
    __shared__ float msk[48][4];

    const int b = bid >> 7;
    const int n = bid & (NDET - 1);

    const int4 dv = *((const int4*)(dets + (size_t)(b * NDET + n) * 4));
    const int sx = dv.x, sy = dv.y, ex = dv.z, ey = dv.w;
    const int Lx = ex - sx, Ly = ey - sy;
    const int xs1 = sx + Lx / 3,        xs2 = sx + 2 * Lx / 3;
    const int xe0 = sx + (Lx + 2) / 3,  xe1 = sx + (2 * Lx + 2) / 3;
    const int ys1 = sy + Ly / 3,        ys2 = sy + 2 * Ly / 3;
    const int ye0 = sy + (Ly + 2) / 3,  ye1 = sy + (2 * Ly + 2) / 3;

    const int p = inds[b * NDET + n];

    if (t < 48) {
        int y = sy + t;
        bool inb = (y < ey);
        msk[t][0] = (inb && y < ye0)              ? 1.f : 0.f;
        msk[t][1] = (inb && y >= ys1 && y < ye1)  ? 1.f : 0.f;
        msk[t][2] = (inb && y >= ys2)             ? 1.f : 0.f;
        msk[t][3] = 0.f;
    }
    if (t < CH) {
        float qval = x[((size_t)b * CH + t) * HWSZ + p];
        float vv   = vis[(size_t)b * HWSZ + p];
        int vidx   = (int)(vv * 10.0f);
        float fr   = powf(10000.0f, -(float)(t & 126) * (1.0f / 128.0f));
        float ang  = 0.1f * (float)vidx * fr;
        float pe   = (t & 1) ? cosf(ang) : sinf(ang);
        qv[t] = qval + pe;
    }
    __syncthreads();

    {
        const int g   = t >> 4;
        const int lx  = t & 15;
        const int sx4 = sx & ~3;
        const int xb  = sx4 + lx * 4;
        const int lxmax = ((ex - 1) - sx4) >> 2;
        const int xba = sx4 + ((lx < lxmax) ? lx : lxmax) * 4;

        float4 mx0, mx1, mx2;
        {
            float m0[4], m1[4], m2[4];
            #pragma unroll
            for (int e = 0; e < 4; ++e) {
                int xx = xb + e;
                m0[e] = (xx >= sx  && xx < xe0) ? 1.f : 0.f;
                m1[e] = (xx >= xs1 && xx < xe1) ? 1.f : 0.f;
                m2[e] = (xx >= xs2 && xx < ex ) ? 1.f : 0.f;
            }
            mx0 = make_float4(m0[0], m0[1], m0[2], m0[3]);
            mx1 = make_float4(m1[0], m1[1], m1[2], m1[3]);
            mx2 = make_float4(m2[0], m2[1], m2[2], m2[3]);
        }

        const int rows_n = ey - sy;
        const int nch    = (rows_n + 7) >> 3;

        for (int c = 0; c < 8; ++c) {
            const int dd = g + c * 16;
            const float* base = x + ((size_t)b * CH + dd) * HWSZ + xba;
            float4 ac0 = make_float4(0.f,0.f,0.f,0.f);
            float4 ac1 = make_float4(0.f,0.f,0.f,0.f);
            float4 ac2 = make_float4(0.f,0.f,0.f,0.f);
            for (int ck = 0; ck < nch; ++ck) {
                const int y0 = sy + (ck << 3);
                float4 v[8];
                #pragma unroll
                for (int k = 0; k < 8; ++k) {
                    int y = y0 + k;
                    y = (y < ey) ? y : (ey - 1);
                    v[k] = *(const float4*)(base + (size_t)y * WWID);
                }
                #pragma unroll
                for (int k = 0; k < 8; ++k) {
                    const float4 m = *(const float4*)&msk[(y0 - sy) + k][0];
                    ac0.x = fmaf(m.x, v[k].x, ac0.x); ac0.y = fmaf(m.x, v[k].y, ac0.y);
                    ac0.z = fmaf(m.x, v[k].z, ac0.z); ac0.w = fmaf(m.x, v[k].w, ac0.w);
                    ac1.x = fmaf(m.y, v[k].x, ac1.x); ac1.y = fmaf(m.y, v[k].y, ac1.y);
                    ac1.z = fmaf(m.y, v[k].z, ac1.z); ac1.w = fmaf(m.y, v[k].w, ac1.w);
                    ac2.x = fmaf(m.z, v[k].x, ac2.x); ac2.y = fmaf(m.z, v[k].y, ac2.y);
                    ac2.z = fmaf(m.z, v[k].z, ac2.z); ac2.w = fmaf(m.z, v[k].w, ac2.w);
                }
            }
            float a[9];
            a[0] = dot4(mx0, ac0, 0.f); a[1] = dot4(mx1, ac0, 0.f); a[2] = dot4(mx2, ac0, 0.f);
            a[3] = dot4(mx0, ac1, 0.f); a[4] = dot4(mx1, ac1, 0.f); a[5] = dot4(mx2, ac1, 0.f);
            a[6] = dot4(mx0, ac2, 0.f); a[7] = dot4(mx1, ac2, 0.f); a[8] = dot4(mx2, ac2, 0.f);
            #pragma unroll
            for (int jj = 0; jj < 9; ++jj) {
                a[jj] += __shfl_xor(a[jj], 8);
                a[jj] += __shfl_xor(a[jj], 4);
                a[jj] += __shfl_xor(a[jj], 2);
                a[jj] += __shfl_xor(a[jj], 1);
            }
            if (lx == 0) {
                int w0 = xe0 - sx, w1 = xe1 - xs1, w2 = ex - xs2;
                int h0 = ye0 - sy, h1r = ye1 - ys1, h2 = ey - ys2;
                kbuf[0][dd] = a[0] / (float)(h0 * w0);
                kbuf[1][dd] = a[1] / (float)(h0 * w1);
                kbuf[2][dd] = a[2] / (float)(h0 * w2);
                kbuf[3][dd] = a[3] / (float)(h1r * w0);
                kbuf[4][dd] = a[4] / (float)(h1r * w1);
                kbuf[5][dd] = a[5] / (float)(h1r * w2);
                kbuf[6][dd] = a[6] / (float)(h2 * w0);
                kbuf[7][dd] = a[7] / (float)(h2 * w1);
                kbuf[8][dd] = a[8] / (float)(h2 * w2);
            }
        }
    }
    __syncthreads();

    if (t < CH) {
        const float4* wr = (const float4*)(Wqkv + (size_t)t * CH);
        const float4* qq = (const float4*)qv;
        float s = 0.f;
        #pragma unroll 8
        for (int i = 0; i < CH / 4; ++i) s = dot4(wr[i], qq[i], s);
        qp[t] = s + bqkv[t];
    }
    {
        const int o = t & (CH - 1);
        const int which = t >> 7;
        const float4* wr = (const float4*)(Wqkv + (size_t)(CH + which * CH + o) * CH);
        float acc[9] = {0.f,0.f,0.f,0.f,0.f,0.f,0.f,0.f,0.f};
        #pragma unroll 4
        for (int i = 0; i < CH / 4; ++i) {
            float4 w = wr[i];
            #pragma unroll
            for (int s = 0; s < 9; ++s) {
                float4 kk = ((const float4*)(&kbuf[s][0]))[i];
                acc[s] = dot4(w, kk, acc[s]);
            }
        }
        float bias = bqkv[CH + which * CH + o];
        if (which == 0) {
            #pragma unroll
            for (int s = 0; s < 9; ++s) kp[s][o] = acc[s] + bias;
        } else {
            #pragma unroll
            for (int s = 0; s < 9; ++s) vp[s][o] = acc[s] + bias;
        }
    }
    __syncthreads();

    if (t < NHEAD * 9) {
        int h = t / 9, s = t - h * 9;
        const float* qh = qp + h * HDIM;
        const float* kh = &kp[s][h * HDIM];
        float a = 0.f;
        #pragma unroll
        for (int e = 0; e < HDIM; ++e) a = fmaf(qh[e], kh[e], a);
        att[h][s] = a * 0.25f;
    }
    __syncthreads();

    if (t < NHEAD) {
        float m = att[t][0];
        #pragma unroll
        for (int s = 1; s < 9; ++s) m = fmaxf(m, att[t][s]);
        float e[9]; float sum = 0.f;
        #pragma unroll
        for (int s = 0; s < 9; ++s) { e[s] = expf(att[t][s] - m); sum += e[s]; }
        float inv = 1.0f / sum;
        #pragma unroll
        for (int s = 0; s < 9; ++s) att[t][s] = e[s] * inv;
    }
    __syncthreads();

    if (t < CH) {
        int h = t >> 4;
        float a = 0.f;
        #pragma unroll
        for (int s = 0; s < 9; ++s) a = fmaf(att[h][s], vp[s][t], a);
        aov[t] = a;
    }
    __syncthreads();

    float v1 = 0.f;
    if (t < CH) {
        const float4* wr = (const float4*)(Wo + (size_t)t * CH);
        const float4* u4 = (const float4*)aov;
        float s = 0.f;
        #pragma unroll 8
        for (int i = 0; i < CH / 4; ++i) s = dot4(wr[i], u4[i], s);
        v1 = qv[t] + s + bo[t];
    }
    float t1 = block_layernorm(v1, t, g2, be2, redA, redB);
    if (t < CH) tv[t] = t1;
    __syncthreads();

    #pragma unroll
    for (int rep = 0; rep < 2; ++rep) {
        int o = t + rep * 256;
        const float4* wr = (const float4*)(W1 + (size_t)o * CH);
        const float4* u4 = (const float4*)tv;
        float s = 0.f;
        #pragma unroll 8
        for (int i = 0; i < CH / 4; ++i) s = dot4(wr[i], u4[i], s);
        h1[o] = fmaxf(s + b1[o], 0.f);
    }
    __syncthreads();

    {
        int o = t & (CH - 1), hf = t >> 7;
        const float4* wr = (const float4*)(W2 + (size_t)o * DFF + hf * (DFF / 2));
        const float4* u4 = (const float4*)(h1 + hf * (DFF / 2));
        float s = 0.f;
        #pragma unroll 8
        for (int i = 0; i < DFF / 8; ++i) s = dot4(wr[i], u4[i], s);
        part[t] = s;
    }
    __syncthreads();

    float v2 = 0.f;
    if (t < CH) {
        float t2 = part[t] + part[t + 128] + b2[t];
        v2 = tv[t] + t2;
    }
    float outv = block_layernorm(v2, t, g3, be3, redA, redB);
    if (t < CH) out[((size_t)b * CH + t) * HWSZ + p] = outv;
}

extern "C" void kernel_launch(void* const* d_in, const int* in_sizes, int n_in,
                              void* d_out, int out_size, void* d_ws, size_t ws_size,
                              hipStream_t stream) {
    const float* x    = (const float*)d_in[0];
    const float* vis  = (const float*)d_in[1];
    const int*   dets = (const int*)d_in[2];
    const int*   inds = (const int*)d_in[3];
    const float* Wqkv = (const float*)d_in[4];
    const float* bqkv = (const float*)d_in[5];
    const float* Wo   = (const float*)d_in[6];
    const float* bo   = (const float*)d_in[7];
    const float* W1   = (const float*)d_in[8];
    const float* b1   = (const float*)d_in[9];
    const float* W2   = (const float*)d_in[10];
    const float* b2   = (const float*)d_in[11];
    const float* g2   = (const float*)d_in[12];
    const float* be2  = (const float*)d_in[13];
    const float* g3   = (const float*)d_in[14];
    const float* be3  = (const float*)d_in[15];
    float* out = (float*)d_out;

    // workspace layout (floats)
    const size_t SZ_KOUT = (size_t)NDB * KSTRIDE;       // pooled k
    const size_t SZ_128  = (size_t)NDB * CH;
    const size_t SZ_KVP  = (size_t)NDB * 2 * 9 * CH;    // kp+vp
    const size_t SZ_H1   = (size_t)NDB * DFF;
    const size_t need = (SZ_KOUT + 4 * SZ_128 + SZ_KVP + SZ_H1 + SZ_128) * sizeof(float);

    const size_t N4 = (size_t)BB * CH * HWSZ / 4;
    if (ws_size >= need) {
        float* kout = (float*)d_ws;
        float* qvb  = kout + SZ_KOUT;
        float* qpb  = qvb  + SZ_128;
        float* kvp  = qpb  + SZ_128;
        float* aovb = kvp  + SZ_KVP;
        float* tvb  = aovb + SZ_128;
        float* h1b  = tvb  + SZ_128;
        float* rows = h1b  + SZ_H1;

        // copy-range cuts (fractions of the big x->out copy)
        const size_t c1 = N4 * 65 / 100;
        const size_t c2 = N4 * 80 / 100;
        const size_t c3 = N4 * 84 / 100;
        const size_t c4 = N4 * 88 / 100;
        const size_t c5 = N4 * 95 / 100;

        pool_copy<<<dim3(NPOOL + 1024), dim3(256), 0, stream>>>(
            x, dets, kout, out, 0, c1, 1024);
        qkv_kernel<<<dim3(K2_KV + K2_Q + 512), dim3(256), 0, stream>>>(
            x, vis, inds, kout, Wqkv, bqkv, kvp, qpb, qvb, out, c1, c2, 512);
        attn_kernel<<<dim3(NDB + 256), dim3(64), 0, stream>>>(
            kvp, qpb, x, aovb, out, c2, c3, 256);
        wo_ln1_kernel<<<dim3(64 + 256), dim3(256), 0, stream>>>(
            aovb, qvb, Wo, bo, g2, be2, x, tvb, out, c3, c4, 256);
        ffn1_kernel<<<dim3(128 + 256), dim3(256), 0, stream>>>(
            tvb, W1, b1, x, h1b, out, c4, c5, 256);
        ffn2_ln2_kernel<<<dim3(128 + 256), dim3(256), 0, stream>>>(
            h1b, tvb, W2, b2, g3, be3, x, rows, out, c5, N4, 256);
        scatter_rows<<<dim3((NDB * CH) / 256), dim3(256), 0, stream>>>(
            rows, inds, out);
    } else {
        // fallback: copy first, then fully-fused det blocks write direct
        copy_x<<<dim3(2048), dim3(256), 0, stream>>>(
            (const f4v*)x, (f4v*)out, N4);
        er_fused_fb<<<dim3(NDB), dim3(256), 0, stream>>>(
            x, vis, dets, inds, Wqkv, bqkv, Wo, bo, W1, b1, W2, b2,
            g2, be2, g3, be3, out);
    }
}

// Round 8
// 163.345 us; speedup vs baseline: 1.2729x; 1.2162x over previous
//
#include <hip/hip_runtime.h>
#include <math.h>

#define BB 8
#define CH 128
#define HH 152
#define WWID 272
#define HWSZ (HH*WWID)
#define NDET 128
#define NHEAD 8
#define HDIM 16
#define DFF 512
#define NDB (BB*NDET)      // 1024 dets
#define NPLANE (BB*CH)     // 1024 (image, channel) planes
#define KSTRIDE 1152       // 9*CH floats of pooled k per det
#define CHUNK 38           // rows per LDS prefix-sum slab (152 = 4*38)
#define SROW 276           // S row stride in floats (273 used, %4==0)

typedef float f4v __attribute__((ext_vector_type(4)));

__device__ __forceinline__ float dot4(float4 w, float4 u, float s) {
    s = fmaf(w.x, u.x, s);
    s = fmaf(w.y, u.y, s);
    s = fmaf(w.z, u.z, s);
    s = fmaf(w.w, u.w, s);
    return s;
}

// ============================================================================
// K1: fused copy + adaptive 3x3 pooling. One block per (b, ch) plane.
// Each wave streams rows (coalesced float4 read -> NT store to out) and
// builds an exclusive prefix-sum per row in LDS; det-threads then reduce
// box cells from the prefix sums. x is read from HBM exactly once.
// ============================================================================
__global__ __launch_bounds__(256) void pool_stream(
    const float* __restrict__ x, const int* __restrict__ dets,
    float* __restrict__ kout, float* __restrict__ out)
{
    const int bid  = blockIdx.x;          // b*128 + ch
    const int t    = threadIdx.x;
    const int b    = bid >> 7, ch = bid & 127;
    const int lane = t & 63,  w  = t >> 6;

    __shared__ float S[CHUNK * SROW];     // exclusive prefix sums per row
    __shared__ float scratch[NDET * 9];   // partner-half accumulators

    const float* xp = x + ((size_t)b * CH + ch) * HWSZ;
    f4v* o4 = (f4v*)(out + ((size_t)b * CH + ch) * HWSZ);

    // ---- det-thread setup: thread d & d+128 both own det d ----
    const int d = t & 127, half = t >> 7;
    const int4 dv = *((const int4*)(dets + (size_t)(b * NDET + d) * 4));
    const int sx = dv.x, sy = dv.y, ex = dv.z, ey = dv.w;
    const int Lx = ex - sx, Ly = ey - sy;
    // cell edges (cells OVERLAP due to floor/ceil in reference)
    const int xs1 = sx + Lx / 3,        xs2 = sx + 2 * Lx / 3;
    const int xe0 = sx + (Lx + 2) / 3,  xe1 = sx + (2 * Lx + 2) / 3;
    const int ys1 = sy + Ly / 3,        ys2 = sy + 2 * Ly / 3;
    const int ye0 = sy + (Ly + 2) / 3,  ye1 = sy + (2 * Ly + 2) / 3;

    float acc[9] = {0.f,0.f,0.f,0.f,0.f,0.f,0.f,0.f,0.f};

    #pragma unroll 1
    for (int c = 0; c < HH / CHUNK; ++c) {
        const int cbeg = c * CHUNK;

        // ---- phase A: stream + scan rows (wave-parallel, prefetched) ----
        {
            int rl = w;                       // wave w does rows w, w+4, ...
            f4v vm = (f4v)(0.f), ve = (f4v)(0.f);
            bool have = (rl < CHUNK);
            if (have) {
                const f4v* rowp = (const f4v*)(xp + (size_t)(cbeg + rl) * WWID);
                vm = rowp[lane];
                if (lane < 4) ve = rowp[64 + lane];
            }
            while (have) {
                const int rc = rl;
                f4v v = vm, e = ve;
                rl += 4;
                have = (rl < CHUNK);
                if (have) {                   // prefetch next row
                    const f4v* rowp = (const f4v*)(xp + (size_t)(cbeg + rl) * WWID);
                    vm = rowp[lane];
                    if (lane < 4) ve = rowp[64 + lane];
                }
                // copy current row to out (NT: don't evict x from L3)
                __builtin_nontemporal_store(v, &o4[(size_t)(cbeg + rc) * 68 + lane]);
                if (lane < 4)
                    __builtin_nontemporal_store(e, &o4[(size_t)(cbeg + rc) * 68 + 64 + lane]);
                // exclusive prefix: S[c] = sum of cols [0, c)
                float T = v[0] + v[1] + v[2] + v[3];
                float s = T;
                #pragma unroll
                for (int o = 1; o < 64; o <<= 1) {
                    float u = __shfl_up(s, o);
                    if (lane >= o) s += u;
                }
                float off0 = s - T;
                float* Sr = S + rc * SROW;
                f4v sm;
                sm[0] = off0;
                sm[1] = off0 + v[0];
                sm[2] = off0 + v[0] + v[1];
                sm[3] = off0 + v[0] + v[1] + v[2];
                *(f4v*)&Sr[4 * lane] = sm;
                float R  = __shfl(s, 63);                       // total cols 0..255
                float Te = (lane < 4) ? (e[0]+e[1]+e[2]+e[3]) : 0.f;
                float T0 = __shfl(Te, 0), T1 = __shfl(Te, 1);
                float T2 = __shfl(Te, 2), T3 = __shfl(Te, 3);
                if (lane < 4) {
                    float offE = R + ((lane > 0) ? T0 : 0.f)
                                   + ((lane > 1) ? T1 : 0.f)
                                   + ((lane > 2) ? T2 : 0.f);
                    f4v se;
                    se[0] = offE;
                    se[1] = offE + e[0];
                    se[2] = offE + e[0] + e[1];
                    se[3] = offE + e[0] + e[1] + e[2];
                    *(f4v*)&Sr[256 + 4 * lane] = se;
                }
                if (lane == 0) Sr[272] = R + T0 + T1 + T2 + T3;
            }
        }
        __syncthreads();

        // ---- phase B: det accumulation from prefix sums ----
        {
            int lo = (sy > cbeg) ? sy : cbeg;
            int hi = (ey < cbeg + CHUNK) ? ey : (cbeg + CHUNK);
            if (lo < hi) {
                int mid = (lo + hi + 1) >> 1;
                int y0 = half ? mid : lo;
                int y1 = half ? hi  : mid;
                for (int y = y0; y < y1; ++y) {
                    const float* Sr = S + (y - cbeg) * SROW;
                    float c0 = Sr[xe0] - Sr[sx];
                    float c1 = Sr[xe1] - Sr[xs1];
                    float c2 = Sr[ex]  - Sr[xs2];
                    float m0 = (y < ye0) ? 1.f : 0.f;
                    float m1 = (y >= ys1 && y < ye1) ? 1.f : 0.f;
                    float m2 = (y >= ys2) ? 1.f : 0.f;
                    acc[0] = fmaf(m0, c0, acc[0]); acc[1] = fmaf(m0, c1, acc[1]); acc[2] = fmaf(m0, c2, acc[2]);
                    acc[3] = fmaf(m1, c0, acc[3]); acc[4] = fmaf(m1, c1, acc[4]); acc[5] = fmaf(m1, c2, acc[5]);
                    acc[6] = fmaf(m2, c0, acc[6]); acc[7] = fmaf(m2, c1, acc[7]); acc[8] = fmaf(m2, c2, acc[8]);
                }
            }
        }
        __syncthreads();
    }

    // ---- combine halves, divide by area, write kout ----
    if (half) {
        #pragma unroll
        for (int j = 0; j < 9; ++j) scratch[d * 9 + j] = acc[j];
    }
    __syncthreads();
    if (!half) {
        const float w0 = (float)(xe0 - sx), w1 = (float)(xe1 - xs1), w2 = (float)(ex - xs2);
        const float h0 = (float)(ye0 - sy), h1r = (float)(ye1 - ys1), h2 = (float)(ey - ys2);
        float aj[9];
        #pragma unroll
        for (int j = 0; j < 9; ++j) aj[j] = acc[j] + scratch[d * 9 + j];
        float* kd = kout + (size_t)(b * NDET + d) * KSTRIDE + ch;
        kd[0*CH] = aj[0] / (h0  * w0);
        kd[1*CH] = aj[1] / (h0  * w1);
        kd[2*CH] = aj[2] / (h0  * w2);
        kd[3*CH] = aj[3] / (h1r * w0);
        kd[4*CH] = aj[4] / (h1r * w1);
        kd[5*CH] = aj[5] / (h1r * w2);
        kd[6*CH] = aj[6] / (h2  * w0);
        kd[7*CH] = aj[7] / (h2  * w1);
        kd[8*CH] = aj[8] / (h2  * w2);
    }
}

// ============================================================================
// K2: QKV projection GEMM. kv-role: 512 blocks x 2 dets (18 rows);
//     q-role: 64 blocks x 16 dets (gather + posemb + GEMV).
// ============================================================================
#define K2_KV 512
#define K2_Q  64
__global__ __launch_bounds__(256) void qkv_kernel(
    const float* __restrict__ x, const float* __restrict__ vis,
    const int* __restrict__ inds, const float* __restrict__ kout,
    const float* __restrict__ Wqkv, const float* __restrict__ bqkv,
    float* __restrict__ kvp, float* __restrict__ qpb, float* __restrict__ qvb)
{
    const int bid = blockIdx.x;
    const int t   = threadIdx.x;

    __shared__ float As[2304];   // kv: 18x128 rows; q: 16x128 rows

    if (bid < K2_KV) {
        const int d0 = bid * 2;
        const float4* src = (const float4*)(kout + (size_t)d0 * KSTRIDE);
        for (int i = t; i < 576; i += 256) ((float4*)As)[i] = src[i];
        __syncthreads();

        const int o = t & 127, which = t >> 7;
        const float4* wr = (const float4*)(Wqkv + (size_t)(CH + which * CH + o) * CH);
        float acc[18];
        #pragma unroll
        for (int r = 0; r < 18; ++r) acc[r] = 0.f;
        for (int i = 0; i < 32; ++i) {
            float4 w = wr[i];
            #pragma unroll
            for (int r = 0; r < 18; ++r) {
                float4 a = ((const float4*)(As + r * 128))[i];   // broadcast
                acc[r] = dot4(w, a, acc[r]);
            }
        }
        const float bias = bqkv[CH + which * CH + o];
        #pragma unroll
        for (int r = 0; r < 18; ++r) {
            int det = d0 + (r / 9), slot = r % 9;
            kvp[(((size_t)det * 2 + which) * 9 + slot) * CH + o] = acc[r] + bias;
        }
    } else {
        const int dg = (bid - K2_KV) * 16;
        const int o  = t & 127;
        const int rh = t >> 7;
        const float fr = powf(10000.0f, -(float)(o & 126) * (1.0f / 128.0f));
        for (int j = 0; j < 8; ++j) {
            int r = rh + 2 * j;
            int det = dg + r;
            int b = det >> 7, n = det & 127;
            int p = inds[b * NDET + n];
            float qval = x[((size_t)b * CH + o) * HWSZ + p];
            float vv   = vis[(size_t)b * HWSZ + p];
            int vidx   = (int)(vv * 10.0f);
            float ang  = 0.1f * (float)vidx * fr;
            float pe   = (o & 1) ? cosf(ang) : sinf(ang);
            float q = qval + pe;
            As[r * 128 + o] = q;
            qvb[(size_t)det * CH + o] = q;
        }
        __syncthreads();
        const float4* wr = (const float4*)(Wqkv + (size_t)o * CH);   // Wq row o
        float acc[8] = {0.f,0.f,0.f,0.f,0.f,0.f,0.f,0.f};
        for (int i = 0; i < 32; ++i) {
            float4 w = wr[i];
            #pragma unroll
            for (int j = 0; j < 8; ++j) {
                float4 a = ((const float4*)(As + (rh + 2 * j) * 128))[i];
                acc[j] = dot4(w, a, acc[j]);
            }
        }
        const float bias = bqkv[o];
        #pragma unroll
        for (int j = 0; j < 8; ++j)
            qpb[(size_t)(dg + rh + 2 * j) * CH + o] = acc[j] + bias;
    }
}

// ============================================================================
// K3: attention per det (64 threads, no weights)
// ============================================================================
__global__ __launch_bounds__(64) void attn_kernel(
    const float* __restrict__ kvp, const float* __restrict__ qpb,
    float* __restrict__ aovb)
{
    const int bid = blockIdx.x;
    const int t   = threadIdx.x;

    __shared__ float qpl[CH];
    __shared__ float kpl[9][CH];
    __shared__ float vpl[9][CH];
    __shared__ float attl[NHEAD][9];

    const int det = bid;
    const float4* kph = (const float4*)(kvp + (size_t)det * 2 * 9 * CH);
    for (int i = t; i < 288; i += 64) ((float4*)kpl)[i] = kph[i];
    for (int i = t; i < 288; i += 64) ((float4*)vpl)[i] = kph[288 + i];
    for (int i = t; i < 32;  i += 64) ((float4*)qpl)[i] = ((const float4*)(qpb + (size_t)det * CH))[i];
    __syncthreads();

    for (int pr = t; pr < NHEAD * 9; pr += 64) {
        int h = pr / 9, s = pr - h * 9;
        const float* qh = qpl + h * HDIM;
        const float* kh = &kpl[s][h * HDIM];
        float a = 0.f;
        #pragma unroll
        for (int e = 0; e < HDIM; ++e) a = fmaf(qh[e], kh[e], a);
        attl[h][s] = a * 0.25f;
    }
    __syncthreads();

    if (t < NHEAD) {
        float m = attl[t][0];
        #pragma unroll
        for (int s = 1; s < 9; ++s) m = fmaxf(m, attl[t][s]);
        float e[9]; float sum = 0.f;
        #pragma unroll
        for (int s = 0; s < 9; ++s) { e[s] = expf(attl[t][s] - m); sum += e[s]; }
        float inv = 1.0f / sum;
        #pragma unroll
        for (int s = 0; s < 9; ++s) attl[t][s] = e[s] * inv;
    }
    __syncthreads();

    for (int o = t; o < CH; o += 64) {
        int h = o >> 4;
        float a = 0.f;
        #pragma unroll
        for (int s = 0; s < 9; ++s) a = fmaf(attl[h][s], vpl[s][o], a);
        aovb[(size_t)det * CH + o] = a;
    }
}

// ============================================================================
// K4: ao@Wo^T + bo + qv resid + LN1 -> tv  (64 blocks x 16 dets)
// ============================================================================
__global__ __launch_bounds__(256) void wo_ln1_kernel(
    const float* __restrict__ aovb, const float* __restrict__ qvb,
    const float* __restrict__ Wo, const float* __restrict__ bo,
    const float* __restrict__ g2, const float* __restrict__ be2,
    float* __restrict__ tvb)
{
    const int bid = blockIdx.x;
    const int t   = threadIdx.x;

    __shared__ float A[16 * CH];
    __shared__ float Q[16 * CH];
    __shared__ float T[16][CH];
    __shared__ float stats[16][2];

    const int dg = bid * 16;
    {
        const float4* sa = (const float4*)(aovb + (size_t)dg * CH);
        const float4* sq = (const float4*)(qvb  + (size_t)dg * CH);
        for (int i = t; i < 512; i += 256) { ((float4*)A)[i] = sa[i]; ((float4*)Q)[i] = sq[i]; }
    }
    __syncthreads();

    const int o = t & 127, rh = t >> 7;
    {
        const float4* wr = (const float4*)(Wo + (size_t)o * CH);
        float acc[8] = {0.f,0.f,0.f,0.f,0.f,0.f,0.f,0.f};
        for (int i = 0; i < 32; ++i) {
            float4 w = wr[i];
            #pragma unroll
            for (int j = 0; j < 8; ++j) {
                float4 a = ((const float4*)(A + (rh + 2 * j) * CH))[i];
                acc[j] = dot4(w, a, acc[j]);
            }
        }
        const float bb = bo[o];
        #pragma unroll
        for (int j = 0; j < 8; ++j) {
            int r = rh + 2 * j;
            T[r][o] = Q[r * CH + o] + acc[j] + bb;
        }
    }
    __syncthreads();

    {
        const int row = t >> 4, l = t & 15;
        float s1 = 0.f, s2 = 0.f;
        #pragma unroll
        for (int m = 0; m < 8; ++m) {
            float v = T[row][l + 16 * m];
            s1 += v; s2 += v * v;
        }
        #pragma unroll
        for (int off = 8; off >= 1; off >>= 1) {
            s1 += __shfl_xor(s1, off);
            s2 += __shfl_xor(s2, off);
        }
        if (l == 0) { stats[row][0] = s1; stats[row][1] = s2; }
    }
    __syncthreads();

    const float gg = g2[o], bb2 = be2[o];
    #pragma unroll
    for (int j = 0; j < 8; ++j) {
        int r = rh + 2 * j;
        float m   = stats[r][0] * (1.0f / 128.0f);
        float var = stats[r][1] * (1.0f / 128.0f) - m * m;
        float tv  = (T[r][o] - m) * rsqrtf(var + 1e-5f) * gg + bb2;
        tvb[(size_t)(dg + r) * CH + o] = tv;
    }
}

// ============================================================================
// K5: FFN1 relu(tv@W1^T+b1) -> h1  (128 blocks: 16 dets x 256-col tile)
// ============================================================================
__global__ __launch_bounds__(256) void ffn1_kernel(
    const float* __restrict__ tvb, const float* __restrict__ W1,
    const float* __restrict__ b1, float* __restrict__ h1b)
{
    const int bid = blockIdx.x;
    const int t   = threadIdx.x;

    __shared__ float A[16 * CH];
    const int dg = (bid >> 1) * 16;
    const int o  = (bid & 1) * 256 + t;

    {
        const float4* sa = (const float4*)(tvb + (size_t)dg * CH);
        for (int i = t; i < 512; i += 256) ((float4*)A)[i] = sa[i];
    }
    __syncthreads();

    const float4* wr = (const float4*)(W1 + (size_t)o * CH);
    float acc[16];
    #pragma unroll
    for (int r = 0; r < 16; ++r) acc[r] = 0.f;
    for (int i = 0; i < 32; ++i) {
        float4 w = wr[i];
        #pragma unroll
        for (int r = 0; r < 16; ++r) {
            float4 a = ((const float4*)(A + r * CH))[i];
            acc[r] = dot4(w, a, acc[r]);
        }
    }
    const float bb = b1[o];
    #pragma unroll
    for (int r = 0; r < 16; ++r)
        h1b[(size_t)(dg + r) * DFF + o] = fmaxf(acc[r] + bb, 0.f);
}

// ============================================================================
// K6: FFN2 (h1@W2^T+b2) + tv resid + LN2 -> rows  (128 blocks x 8 dets)
// ============================================================================
__global__ __launch_bounds__(256) void ffn2_ln2_kernel(
    const float* __restrict__ h1b, const float* __restrict__ tvb,
    const float* __restrict__ W2, const float* __restrict__ b2,
    const float* __restrict__ g3, const float* __restrict__ be3,
    float* __restrict__ rowsb)
{
    const int bid = blockIdx.x;
    const int t   = threadIdx.x;

    __shared__ float A[8 * DFF];
    __shared__ float Tv[8 * CH];
    __shared__ float T[8][CH];
    __shared__ float stats[8][2];

    const int dg = bid * 8;
    {
        const float4* sa = (const float4*)(h1b + (size_t)dg * DFF);
        for (int i = t; i < 1024; i += 256) ((float4*)A)[i] = sa[i];
        const float4* st = (const float4*)(tvb + (size_t)dg * CH);
        for (int i = t; i < 256; i += 256) ((float4*)Tv)[i] = st[i];
    }
    __syncthreads();

    const int o = t & 127, rh = t >> 7;
    {
        const float4* wr = (const float4*)(W2 + (size_t)o * DFF);
        float acc[4] = {0.f,0.f,0.f,0.f};
        #pragma unroll 4
        for (int i = 0; i < 128; ++i) {
            float4 w = wr[i];
            #pragma unroll
            for (int j = 0; j < 4; ++j) {
                float4 a = ((const float4*)(A + (rh + 2 * j) * DFF))[i];
                acc[j] = dot4(w, a, acc[j]);
            }
        }
        const float bb = b2[o];
        #pragma unroll
        for (int j = 0; j < 4; ++j) {
            int r = rh + 2 * j;
            T[r][o] = Tv[r * CH + o] + acc[j] + bb;
        }
    }
    __syncthreads();

    {
        const int row = t >> 5, l = t & 31;
        float s1 = 0.f, s2 = 0.f;
        #pragma unroll
        for (int m = 0; m < 4; ++m) {
            float v = T[row][l + 32 * m];
            s1 += v; s2 += v * v;
        }
        #pragma unroll
        for (int off = 16; off >= 1; off >>= 1) {
            s1 += __shfl_xor(s1, off);
            s2 += __shfl_xor(s2, off);
        }
        if (l == 0) { stats[row][0] = s1; stats[row][1] = s2; }
    }
    __syncthreads();

    const float gg = g3[o], bb3 = be3[o];
    #pragma unroll
    for (int j = 0; j < 4; ++j) {
        int r = rh + 2 * j;
        float m   = stats[r][0] * (1.0f / 128.0f);
        float var = stats[r][1] * (1.0f / 128.0f) - m * m;
        float ov  = (T[r][o] - m) * rsqrtf(var + 1e-5f) * gg + bb3;
        rowsb[(size_t)(dg + r) * CH + o] = ov;
    }
}

// ============================================================================
// K7: scatter rows into out
// ============================================================================
__global__ __launch_bounds__(256) void scatter_rows(const float* __restrict__ rows,
                                                    const int* __restrict__ inds,
                                                    float* __restrict__ out) {
    int i = blockIdx.x * 256 + threadIdx.x;   // over B*NDET*CH
    int dd = i & (CH - 1);
    int bn = i >> 7;
    int b  = bn >> 7;
    int p  = inds[bn];
    out[((size_t)b * CH + dd) * HWSZ + p] = rows[i];
}

// ============================================================================
// Fallback path (ws too small): copy, then fully-fused det kernel
// ============================================================================
__global__ __launch_bounds__(256) void copy_x(const f4v* __restrict__ src,
                                              f4v* __restrict__ dst, size_t n4) {
    size_t i = (size_t)blockIdx.x * 256 + threadIdx.x;
    const size_t stride = (size_t)gridDim.x * 256;
    for (; i < n4; i += stride) {
        f4v v = src[i];
        __builtin_nontemporal_store(v, &dst[i]);
    }
}

__device__ __forceinline__ float block_layernorm(float v, int t,
        const float* __restrict__ gamma, const float* __restrict__ beta,
        float* redA, float* redB) {
    float s1 = v, s2 = v * v;
    #pragma unroll
    for (int off = 32; off >= 1; off >>= 1) {
        s1 += __shfl_xor(s1, off);
        s2 += __shfl_xor(s2, off);
    }
    if ((t & 63) == 0) { redA[t >> 6] = s1; redB[t >> 6] = s2; }
    __syncthreads();
    float sum = redA[0] + redA[1] + redA[2] + redA[3];
    float sq  = redB[0] + redB[1] + redB[2] + redB[3];
    __syncthreads();
    float m   = sum * (1.0f / 128.0f);
    float var = sq  * (1.0f / 128.0f) - m * m;
    float r = 0.f;
    if (t < CH) r = (v - m) * rsqrtf(var + 1e-5f) * gamma[t] + beta[t];
    return r;
}

__global__ __launch_bounds__(256) void er_fused_fb(
    const float* __restrict__ x, const float* __restrict__ vis,
    const int* __restrict__ dets, const int* __restrict__ inds,
    const float* __restrict__ Wqkv, const float* __restrict__ bqkv,
    const float* __restrict__ Wo,   const float* __restrict__ bo,
    const float* __restrict__ W1,   const float* __restrict__ b1,
    const float* __restrict__ W2,   const float* __restrict__ b2,
    const float* __restrict__ g2,   const float* __restrict__ be2,
    const float* __restrict__ g3,   const float* __restrict__ be3,
    float* __restrict__ out)
{
    const int bid = blockIdx.x;
    const int t   = threadIdx.x;

    __shared__ float kbuf[9][CH];
    __shared__ float qv[CH];
    __shared__ float qp[CH];
    __shared__ float kp[9][CH];
    __shared__ float vp[9][CH];
    __shared__ float att[NHEAD][9];
    __shared__ float aov[CH];
    __shared__ float tv[CH];
    __shared__ float h1[DFF];
    __shared__ float part[256];
    __shared__ float redA[4], redB[4];
    __shared__ float msk[48][4];

    const int b = bid >> 7;
    const int n = bid & (NDET - 1);

    const int4 dv = *((const int4*)(dets + (size_t)(b * NDET + n) * 4));
    const int sx = dv.x, sy = dv.y, ex = dv.z, ey = dv.w;
    const int Lx = ex - sx, Ly = ey - sy;
    const int xs1 = sx + Lx / 3,        xs2 = sx + 2 * Lx / 3;
    const int xe0 = sx + (Lx + 2) / 3,  xe1 = sx + (2 * Lx + 2) / 3;
    const int ys1 = sy + Ly / 3,        ys2 = sy + 2 * Ly / 3;
    const int ye0 = sy + (Ly + 2) / 3,  ye1 = sy + (2 * Ly + 2) / 3;

    const int p = inds[b * NDET + n];

    if (t < 48) {
        int y = sy + t;
        bool inb = (y < ey);
        msk[t][0] = (inb && y < ye0)              ? 1.f : 0.f;
        msk[t][1] = (inb && y >= ys1 && y < ye1)  ? 1.f : 0.f;
        msk[t][2] = (inb && y >= ys2)             ? 1.f : 0.f;
        msk[t][3] = 0.f;
    }
    if (t < CH) {
        float qval = x[((size_t)b * CH + t) * HWSZ + p];
        float vv   = vis[(size_t)b * HWSZ + p];
        int vidx   = (int)(vv * 10.0f);
        float fr   = powf(10000.0f, -(float)(t & 126) * (1.0f / 128.0f));
        float ang  = 0.1f * (float)vidx * fr;
        float pe   = (t & 1) ? cosf(ang) : sinf(ang);
        qv[t] = qval + pe;
    }
    __syncthreads();

    {
        const int g   = t >> 4;
        const int lx  = t & 15;
        const int sx4 = sx & ~3;
        const int xb  = sx4 + lx * 4;
        const int lxmax = ((ex - 1) - sx4) >> 2;
        const int xba = sx4 + ((lx < lxmax) ? lx : lxmax) * 4;

        float4 mx0, mx1, mx2;
        {
            float m0[4], m1[4], m2[4];
            #pragma unroll
            for (int e = 0; e < 4; ++e) {
                int xx = xb + e;
                m0[e] = (xx >= sx  && xx < xe0) ? 1.f : 0.f;
                m1[e] = (xx >= xs1 && xx < xe1) ? 1.f : 0.f;
                m2[e] = (xx >= xs2 && xx < ex ) ? 1.f : 0.f;
            }
            mx0 = make_float4(m0[0], m0[1], m0[2], m0[3]);
            mx1 = make_float4(m1[0], m1[1], m1[2], m1[3]);
            mx2 = make_float4(m2[0], m2[1], m2[2], m2[3]);
        }

        const int rows_n = ey - sy;
        const int nch    = (rows_n + 7) >> 3;

        for (int c = 0; c < 8; ++c) {
            const int dd = g + c * 16;
            const float* base = x + ((size_t)b * CH + dd) * HWSZ + xba;
            float4 ac0 = make_float4(0.f,0.f,0.f,0.f);
            float4 ac1 = make_float4(0.f,0.f,0.f,0.f);
            float4 ac2 = make_float4(0.f,0.f,0.f,0.f);
            for (int ck = 0; ck < nch; ++ck) {
                const int y0 = sy + (ck << 3);
                float4 v[8];
                #pragma unroll
                for (int k = 0; k < 8; ++k) {
                    int y = y0 + k;
                    y = (y < ey) ? y : (ey - 1);
                    v[k] = *(const float4*)(base + (size_t)y * WWID);
                }
                #pragma unroll
                for (int k = 0; k < 8; ++k) {
                    const float4 m = *(const float4*)&msk[(y0 - sy) + k][0];
                    ac0.x = fmaf(m.x, v[k].x, ac0.x); ac0.y = fmaf(m.x, v[k].y, ac0.y);
                    ac0.z = fmaf(m.x, v[k].z, ac0.z); ac0.w = fmaf(m.x, v[k].w, ac0.w);
                    ac1.x = fmaf(m.y, v[k].x, ac1.x); ac1.y = fmaf(m.y, v[k].y, ac1.y);
                    ac1.z = fmaf(m.y, v[k].z, ac1.z); ac1.w = fmaf(m.y, v[k].w, ac1.w);
                    ac2.x = fmaf(m.z, v[k].x, ac2.x); ac2.y = fmaf(m.z, v[k].y, ac2.y);
                    ac2.z = fmaf(m.z, v[k].z, ac2.z); ac2.w = fmaf(m.z, v[k].w, ac2.w);
                }
            }
            float a[9];
            a[0] = dot4(mx0, ac0, 0.f); a[1] = dot4(mx1, ac0, 0.f); a[2] = dot4(mx2, ac0, 0.f);
            a[3] = dot4(mx0, ac1, 0.f); a[4] = dot4(mx1, ac1, 0.f); a[5] = dot4(mx2, ac1, 0.f);
            a[6] = dot4(mx0, ac2, 0.f); a[7] = dot4(mx1, ac2, 0.f); a[8] = dot4(mx2, ac2, 0.f);
            #pragma unroll
            for (int jj = 0; jj < 9; ++jj) {
                a[jj] += __shfl_xor(a[jj], 8);
                a[jj] += __shfl_xor(a[jj], 4);
                a[jj] += __shfl_xor(a[jj], 2);
                a[jj] += __shfl_xor(a[jj], 1);
            }
            if (lx == 0) {
                int w0 = xe0 - sx, w1 = xe1 - xs1, w2 = ex - xs2;
                int h0 = ye0 - sy, h1r = ye1 - ys1, h2 = ey - ys2;
                kbuf[0][dd] = a[0] / (float)(h0 * w0);
                kbuf[1][dd] = a[1] / (float)(h0 * w1);
                kbuf[2][dd] = a[2] / (float)(h0 * w2);
                kbuf[3][dd] = a[3] / (float)(h1r * w0);
                kbuf[4][dd] = a[4] / (float)(h1r * w1);
                kbuf[5][dd] = a[5] / (float)(h1r * w2);
                kbuf[6][dd] = a[6] / (float)(h2 * w0);
                kbuf[7][dd] = a[7] / (float)(h2 * w1);
                kbuf[8][dd] = a[8] / (float)(h2 * w2);
            }
        }
    }
    __syncthreads();

    if (t < CH) {
        const float4* wr = (const float4*)(Wqkv + (size_t)t * CH);
        const float4* qq = (const float4*)qv;
        float s = 0.f;
        #pragma unroll 8
        for (int i = 0; i < CH / 4; ++i) s = dot4(wr[i], qq[i], s);
        qp[t] = s + bqkv[t];
    }
    {
        const int o = t & (CH - 1);
        const int which = t >> 7;
        const float4* wr = (const float4*)(Wqkv + (size_t)(CH + which * CH + o) * CH);
        float acc[9] = {0.f,0.f,0.f,0.f,0.f,0.f,0.f,0.f,0.f};
        #pragma unroll 4
        for (int i = 0; i < CH / 4; ++i) {
            float4 w = wr[i];
            #pragma unroll
            for (int s = 0; s < 9; ++s) {
                float4 kk = ((const float4*)(&kbuf[s][0]))[i];
                acc[s] = dot4(w, kk, acc[s]);
            }
        }
        float bias = bqkv[CH + which * CH + o];
        if (which == 0) {
            #pragma unroll
            for (int s = 0; s < 9; ++s) kp[s][o] = acc[s] + bias;
        } else {
            #pragma unroll
            for (int s = 0; s < 9; ++s) vp[s][o] = acc[s] + bias;
        }
    }
    __syncthreads();

    if (t < NHEAD * 9) {
        int h = t / 9, s = t - h * 9;
        const float* qh = qp + h * HDIM;
        const float* kh = &kp[s][h * HDIM];
        float a = 0.f;
        #pragma unroll
        for (int e = 0; e < HDIM; ++e) a = fmaf(qh[e], kh[e], a);
        att[h][s] = a * 0.25f;
    }
    __syncthreads();

    if (t < NHEAD) {
        float m = att[t][0];
        #pragma unroll
        for (int s = 1; s < 9; ++s) m = fmaxf(m, att[t][s]);
        float e[9]; float sum = 0.f;
        #pragma unroll
        for (int s = 0; s < 9; ++s) { e[s] = expf(att[t][s] - m); sum += e[s]; }
        float inv = 1.0f / sum;
        #pragma unroll
        for (int s = 0; s < 9; ++s) att[t][s] = e[s] * inv;
    }
    __syncthreads();

    if (t < CH) {
        int h = t >> 4;
        float a = 0.f;
        #pragma unroll
        for (int s = 0; s < 9; ++s) a = fmaf(att[h][s], vp[s][t], a);
        aov[t] = a;
    }
    __syncthreads();

    float v1 = 0.f;
    if (t < CH) {
        const float4* wr = (const float4*)(Wo + (size_t)t * CH);
        const float4* u4 = (const float4*)aov;
        float s = 0.f;
        #pragma unroll 8
        for (int i = 0; i < CH / 4; ++i) s = dot4(wr[i], u4[i], s);
        v1 = qv[t] + s + bo[t];
    }
    float t1 = block_layernorm(v1, t, g2, be2, redA, redB);
    if (t < CH) tv[t] = t1;
    __syncthreads();

    #pragma unroll
    for (int rep = 0; rep < 2; ++rep) {
        int o = t + rep * 256;
        const float4* wr = (const float4*)(W1 + (size_t)o * CH);
        const float4* u4 = (const float4*)tv;
        float s = 0.f;
        #pragma unroll 8
        for (int i = 0; i < CH / 4; ++i) s = dot4(wr[i], u4[i], s);
        h1[o] = fmaxf(s + b1[o], 0.f);
    }
    __syncthreads();

    {
        int o = t & (CH - 1), hf = t >> 7;
        const float4* wr = (const float4*)(W2 + (size_t)o * DFF + hf * (DFF / 2));
        const float4* u4 = (const float4*)(h1 + hf * (DFF / 2));
        float s = 0.f;
        #pragma unroll 8
        for (int i = 0; i < DFF / 8; ++i) s = dot4(wr[i], u4[i], s);
        part[t] = s;
    }
    __syncthreads();

    float v2 = 0.f;
    if (t < CH) {
        float t2 = part[t] + part[t + 128] + b2[t];
        v2 = tv[t] + t2;
    }
    float outv = block_layernorm(v2, t, g3, be3, redA, redB);
    if (t < CH) out[((size_t)b * CH + t) * HWSZ + p] = outv;
}

extern "C" void kernel_launch(void* const* d_in, const int* in_sizes, int n_in,
                              void* d_out, int out_size, void* d_ws, size_t ws_size,
                              hipStream_t stream) {
    const float* x    = (const float*)d_in[0];
    const float* vis  = (const float*)d_in[1];
    const int*   dets = (const int*)d_in[2];
    const int*   inds = (const int*)d_in[3];
    const float* Wqkv = (const float*)d_in[4];
    const float* bqkv = (const float*)d_in[5];
    const float* Wo   = (const float*)d_in[6];
    const float* bo   = (const float*)d_in[7];
    const float* W1   = (const float*)d_in[8];
    const float* b1   = (const float*)d_in[9];
    const float* W2   = (const float*)d_in[10];
    const float* b2   = (const float*)d_in[11];
    const float* g2   = (const float*)d_in[12];
    const float* be2  = (const float*)d_in[13];
    const float* g3   = (const float*)d_in[14];
    const float* be3  = (const float*)d_in[15];
    float* out = (float*)d_out;

    // workspace layout (floats)
    const size_t SZ_KOUT = (size_t)NDB * KSTRIDE;
    const size_t SZ_128  = (size_t)NDB * CH;
    const size_t SZ_KVP  = (size_t)NDB * 2 * 9 * CH;
    const size_t SZ_H1   = (size_t)NDB * DFF;
    const size_t need = (SZ_KOUT + 4 * SZ_128 + SZ_KVP + SZ_H1 + SZ_128) * sizeof(float);

    const size_t N4 = (size_t)BB * CH * HWSZ / 4;
    if (ws_size >= need) {
        float* kout = (float*)d_ws;
        float* qvb  = kout + SZ_KOUT;
        float* qpb  = qvb  + SZ_128;
        float* kvp  = qpb  + SZ_128;
        float* aovb = kvp  + SZ_KVP;
        float* tvb  = aovb + SZ_128;
        float* h1b  = tvb  + SZ_128;
        float* rows = h1b  + SZ_H1;

        pool_stream<<<dim3(NPLANE), dim3(256), 0, stream>>>(x, dets, kout, out);
        qkv_kernel<<<dim3(K2_KV + K2_Q), dim3(256), 0, stream>>>(
            x, vis, inds, kout, Wqkv, bqkv, kvp, qpb, qvb);
        attn_kernel<<<dim3(NDB), dim3(64), 0, stream>>>(kvp, qpb, aovb);
        wo_ln1_kernel<<<dim3(64), dim3(256), 0, stream>>>(
            aovb, qvb, Wo, bo, g2, be2, tvb);
        ffn1_kernel<<<dim3(128), dim3(256), 0, stream>>>(tvb, W1, b1, h1b);
        ffn2_ln2_kernel<<<dim3(128), dim3(256), 0, stream>>>(
            h1b, tvb, W2, b2, g3, be3, rows);
        scatter_rows<<<dim3((NDB * CH) / 256), dim3(256), 0, stream>>>(
            rows, inds, out);
    } else {
        copy_x<<<dim3(2048), dim3(256), 0, stream>>>(
            (const f4v*)x, (f4v*)out, N4);
        er_fused_fb<<<dim3(NDB), dim3(256), 0, stream>>>(
            x, vis, dets, inds, Wqkv, bqkv, Wo, bo, W1, b1, W2, b2,
            g2, be2, g3, be3, out);
    }
}

// Round 9
// 154.771 us; speedup vs baseline: 1.3434x; 1.0554x over previous
//
#include <hip/hip_runtime.h>
#include <math.h>

#define BB 8
#define CH 128
#define HH 152
#define WWID 272
#define HWSZ (HH*WWID)
#define NDET 128
#define NHEAD 8
#define HDIM 16
#define DFF 512
#define NDB (BB*NDET)      // 1024 dets
#define NPLANE (BB*CH)     // 1024 (image, channel) planes
#define KSTRIDE 1152       // 9*CH floats of pooled k per det
#define CHUNK 19           // rows per LDS prefix-sum slab (152 = 8*19) -> 25.6KB LDS
#define SROW 276           // S row stride in floats (273 used, %4==0)

typedef float f4v __attribute__((ext_vector_type(4)));

__device__ __forceinline__ float dot4(float4 w, float4 u, float s) {
    s = fmaf(w.x, u.x, s);
    s = fmaf(w.y, u.y, s);
    s = fmaf(w.z, u.z, s);
    s = fmaf(w.w, u.w, s);
    return s;
}

// ============================================================================
// K1: fused copy + adaptive 3x3 pooling. One block per (b, ch) plane.
// Waves stream rows (coalesced read -> NT store = the copy) and build an
// exclusive prefix-sum per row in LDS; det-threads reduce box cells from the
// prefix sums. x is read from HBM exactly once. CHUNK=19 keeps LDS at 25.6KB
// so 6 blocks/CU fit -> all 1024 blocks co-resident, 16 waves/CU.
// ============================================================================
__global__ __launch_bounds__(256) void pool_stream(
    const float* __restrict__ x, const int* __restrict__ dets,
    float* __restrict__ kout, float* __restrict__ out)
{
    const int bid  = blockIdx.x;          // b*128 + ch
    const int t    = threadIdx.x;
    const int b    = bid >> 7, ch = bid & 127;
    const int lane = t & 63,  w  = t >> 6;

    __shared__ float S[CHUNK * SROW];     // exclusive prefix sums per row
    __shared__ float scratch[NDET * 9];   // partner-half accumulators

    const float* xp = x + ((size_t)b * CH + ch) * HWSZ;
    f4v* o4 = (f4v*)(out + ((size_t)b * CH + ch) * HWSZ);

    // ---- det-thread setup: thread d & d+128 both own det d ----
    const int d = t & 127, half = t >> 7;
    const int4 dv = *((const int4*)(dets + (size_t)(b * NDET + d) * 4));
    const int sx = dv.x, sy = dv.y, ex = dv.z, ey = dv.w;
    const int Lx = ex - sx, Ly = ey - sy;
    // cell edges (cells OVERLAP due to floor/ceil in reference)
    const int xs1 = sx + Lx / 3,        xs2 = sx + 2 * Lx / 3;
    const int xe0 = sx + (Lx + 2) / 3,  xe1 = sx + (2 * Lx + 2) / 3;
    const int ys1 = sy + Ly / 3,        ys2 = sy + 2 * Ly / 3;
    const int ye0 = sy + (Ly + 2) / 3,  ye1 = sy + (2 * Ly + 2) / 3;

    float acc[9] = {0.f,0.f,0.f,0.f,0.f,0.f,0.f,0.f,0.f};

    #pragma unroll 1
    for (int c = 0; c < HH / CHUNK; ++c) {
        const int cbeg = c * CHUNK;

        // ---- phase A: stream + scan rows (wave-parallel, prefetched) ----
        {
            int rl = w;                       // wave w does rows w, w+4, ...
            f4v vm = (f4v)(0.f), ve = (f4v)(0.f);
            bool have = (rl < CHUNK);
            if (have) {
                const f4v* rowp = (const f4v*)(xp + (size_t)(cbeg + rl) * WWID);
                vm = rowp[lane];
                if (lane < 4) ve = rowp[64 + lane];
            }
            while (have) {
                const int rc = rl;
                f4v v = vm, e = ve;
                rl += 4;
                have = (rl < CHUNK);
                if (have) {                   // prefetch next row
                    const f4v* rowp = (const f4v*)(xp + (size_t)(cbeg + rl) * WWID);
                    vm = rowp[lane];
                    if (lane < 4) ve = rowp[64 + lane];
                }
                // copy current row to out (NT: don't evict x from L3)
                __builtin_nontemporal_store(v, &o4[(size_t)(cbeg + rc) * 68 + lane]);
                if (lane < 4)
                    __builtin_nontemporal_store(e, &o4[(size_t)(cbeg + rc) * 68 + 64 + lane]);
                // exclusive prefix: S[c] = sum of cols [0, c)
                float T = v[0] + v[1] + v[2] + v[3];
                float s = T;
                #pragma unroll
                for (int o = 1; o < 64; o <<= 1) {
                    float u = __shfl_up(s, o);
                    if (lane >= o) s += u;
                }
                float off0 = s - T;
                float* Sr = S + rc * SROW;
                f4v sm;
                sm[0] = off0;
                sm[1] = off0 + v[0];
                sm[2] = off0 + v[0] + v[1];
                sm[3] = off0 + v[0] + v[1] + v[2];
                *(f4v*)&Sr[4 * lane] = sm;
                float R  = __shfl(s, 63);                       // total cols 0..255
                float Te = (lane < 4) ? (e[0]+e[1]+e[2]+e[3]) : 0.f;
                float T0 = __shfl(Te, 0), T1 = __shfl(Te, 1);
                float T2 = __shfl(Te, 2), T3 = __shfl(Te, 3);
                if (lane < 4) {
                    float offE = R + ((lane > 0) ? T0 : 0.f)
                                   + ((lane > 1) ? T1 : 0.f)
                                   + ((lane > 2) ? T2 : 0.f);
                    f4v se;
                    se[0] = offE;
                    se[1] = offE + e[0];
                    se[2] = offE + e[0] + e[1];
                    se[3] = offE + e[0] + e[1] + e[2];
                    *(f4v*)&Sr[256 + 4 * lane] = se;
                }
                if (lane == 0) Sr[272] = R + T0 + T1 + T2 + T3;
            }
        }
        __syncthreads();

        // ---- phase B: det accumulation from prefix sums ----
        {
            int lo = (sy > cbeg) ? sy : cbeg;
            int hi = (ey < cbeg + CHUNK) ? ey : (cbeg + CHUNK);
            if (lo < hi) {
                int mid = (lo + hi + 1) >> 1;
                int y0 = half ? mid : lo;
                int y1 = half ? hi  : mid;
                for (int y = y0; y < y1; ++y) {
                    const float* Sr = S + (y - cbeg) * SROW;
                    float c0 = Sr[xe0] - Sr[sx];
                    float c1 = Sr[xe1] - Sr[xs1];
                    float c2 = Sr[ex]  - Sr[xs2];
                    float m0 = (y < ye0) ? 1.f : 0.f;
                    float m1 = (y >= ys1 && y < ye1) ? 1.f : 0.f;
                    float m2 = (y >= ys2) ? 1.f : 0.f;
                    acc[0] = fmaf(m0, c0, acc[0]); acc[1] = fmaf(m0, c1, acc[1]); acc[2] = fmaf(m0, c2, acc[2]);
                    acc[3] = fmaf(m1, c0, acc[3]); acc[4] = fmaf(m1, c1, acc[4]); acc[5] = fmaf(m1, c2, acc[5]);
                    acc[6] = fmaf(m2, c0, acc[6]); acc[7] = fmaf(m2, c1, acc[7]); acc[8] = fmaf(m2, c2, acc[8]);
                }
            }
        }
        __syncthreads();
    }

    // ---- combine halves, divide by area, write kout ----
    if (half) {
        #pragma unroll
        for (int j = 0; j < 9; ++j) scratch[d * 9 + j] = acc[j];
    }
    __syncthreads();
    if (!half) {
        const float w0 = (float)(xe0 - sx), w1 = (float)(xe1 - xs1), w2 = (float)(ex - xs2);
        const float h0 = (float)(ye0 - sy), h1r = (float)(ye1 - ys1), h2 = (float)(ey - ys2);
        float aj[9];
        #pragma unroll
        for (int j = 0; j < 9; ++j) aj[j] = acc[j] + scratch[d * 9 + j];
        float* kd = kout + (size_t)(b * NDET + d) * KSTRIDE + ch;
        kd[0*CH] = aj[0] / (h0  * w0);
        kd[1*CH] = aj[1] / (h0  * w1);
        kd[2*CH] = aj[2] / (h0  * w2);
        kd[3*CH] = aj[3] / (h1r * w0);
        kd[4*CH] = aj[4] / (h1r * w1);
        kd[5*CH] = aj[5] / (h1r * w2);
        kd[6*CH] = aj[6] / (h2  * w0);
        kd[7*CH] = aj[7] / (h2  * w1);
        kd[8*CH] = aj[8] / (h2  * w2);
    }
}

// ============================================================================
// K2: QKV projection GEMM. kv-role: 512 blocks x 2 dets (18 rows);
//     q-role: 64 blocks x 16 dets (gather + posemb + GEMV).
// ============================================================================
#define K2_KV 512
#define K2_Q  64
__global__ __launch_bounds__(256) void qkv_kernel(
    const float* __restrict__ x, const float* __restrict__ vis,
    const int* __restrict__ inds, const float* __restrict__ kout,
    const float* __restrict__ Wqkv, const float* __restrict__ bqkv,
    float* __restrict__ kvp, float* __restrict__ qpb, float* __restrict__ qvb)
{
    const int bid = blockIdx.x;
    const int t   = threadIdx.x;

    __shared__ float As[2304];   // kv: 18x128 rows; q: 16x128 rows

    if (bid < K2_KV) {
        const int d0 = bid * 2;
        const float4* src = (const float4*)(kout + (size_t)d0 * KSTRIDE);
        for (int i = t; i < 576; i += 256) ((float4*)As)[i] = src[i];
        __syncthreads();

        const int o = t & 127, which = t >> 7;
        const float4* wr = (const float4*)(Wqkv + (size_t)(CH + which * CH + o) * CH);
        float acc[18];
        #pragma unroll
        for (int r = 0; r < 18; ++r) acc[r] = 0.f;
        for (int i = 0; i < 32; ++i) {
            float4 w = wr[i];
            #pragma unroll
            for (int r = 0; r < 18; ++r) {
                float4 a = ((const float4*)(As + r * 128))[i];   // broadcast
                acc[r] = dot4(w, a, acc[r]);
            }
        }
        const float bias = bqkv[CH + which * CH + o];
        #pragma unroll
        for (int r = 0; r < 18; ++r) {
            int det = d0 + (r / 9), slot = r % 9;
            kvp[(((size_t)det * 2 + which) * 9 + slot) * CH + o] = acc[r] + bias;
        }
    } else {
        const int dg = (bid - K2_KV) * 16;
        const int o  = t & 127;
        const int rh = t >> 7;
        const float fr = powf(10000.0f, -(float)(o & 126) * (1.0f / 128.0f));
        for (int j = 0; j < 8; ++j) {
            int r = rh + 2 * j;
            int det = dg + r;
            int b = det >> 7, n = det & 127;
            int p = inds[b * NDET + n];
            float qval = x[((size_t)b * CH + o) * HWSZ + p];
            float vv   = vis[(size_t)b * HWSZ + p];
            int vidx   = (int)(vv * 10.0f);
            float ang  = 0.1f * (float)vidx * fr;
            float pe   = (o & 1) ? cosf(ang) : sinf(ang);
            float q = qval + pe;
            As[r * 128 + o] = q;
            qvb[(size_t)det * CH + o] = q;
        }
        __syncthreads();
        const float4* wr = (const float4*)(Wqkv + (size_t)o * CH);   // Wq row o
        float acc[8] = {0.f,0.f,0.f,0.f,0.f,0.f,0.f,0.f};
        for (int i = 0; i < 32; ++i) {
            float4 w = wr[i];
            #pragma unroll
            for (int j = 0; j < 8; ++j) {
                float4 a = ((const float4*)(As + (rh + 2 * j) * 128))[i];
                acc[j] = dot4(w, a, acc[j]);
            }
        }
        const float bias = bqkv[o];
        #pragma unroll
        for (int j = 0; j < 8; ++j)
            qpb[(size_t)(dg + rh + 2 * j) * CH + o] = acc[j] + bias;
    }
}

// ============================================================================
// K3: attention per det (64 threads, no weights)
// ============================================================================
__global__ __launch_bounds__(64) void attn_kernel(
    const float* __restrict__ kvp, const float* __restrict__ qpb,
    float* __restrict__ aovb)
{
    const int bid = blockIdx.x;
    const int t   = threadIdx.x;

    __shared__ float qpl[CH];
    __shared__ float kpl[9][CH];
    __shared__ float vpl[9][CH];
    __shared__ float attl[NHEAD][9];

    const int det = bid;
    const float4* kph = (const float4*)(kvp + (size_t)det * 2 * 9 * CH);
    for (int i = t; i < 288; i += 64) ((float4*)kpl)[i] = kph[i];
    for (int i = t; i < 288; i += 64) ((float4*)vpl)[i] = kph[288 + i];
    for (int i = t; i < 32;  i += 64) ((float4*)qpl)[i] = ((const float4*)(qpb + (size_t)det * CH))[i];
    __syncthreads();

    for (int pr = t; pr < NHEAD * 9; pr += 64) {
        int h = pr / 9, s = pr - h * 9;
        const float* qh = qpl + h * HDIM;
        const float* kh = &kpl[s][h * HDIM];
        float a = 0.f;
        #pragma unroll
        for (int e = 0; e < HDIM; ++e) a = fmaf(qh[e], kh[e], a);
        attl[h][s] = a * 0.25f;
    }
    __syncthreads();

    if (t < NHEAD) {
        float m = attl[t][0];
        #pragma unroll
        for (int s = 1; s < 9; ++s) m = fmaxf(m, attl[t][s]);
        float e[9]; float sum = 0.f;
        #pragma unroll
        for (int s = 0; s < 9; ++s) { e[s] = expf(attl[t][s] - m); sum += e[s]; }
        float inv = 1.0f / sum;
        #pragma unroll
        for (int s = 0; s < 9; ++s) attl[t][s] = e[s] * inv;
    }
    __syncthreads();

    for (int o = t; o < CH; o += 64) {
        int h = o >> 4;
        float a = 0.f;
        #pragma unroll
        for (int s = 0; s < 9; ++s) a = fmaf(attl[h][s], vpl[s][o], a);
        aovb[(size_t)det * CH + o] = a;
    }
}

// ============================================================================
// K4: ao@Wo^T + bo + qv resid + LN1 -> tv, then FFN1 -> h1 (fused; 64 blocks)
// ============================================================================
__global__ __launch_bounds__(256) void wo_ln1_ffn1_kernel(
    const float* __restrict__ aovb, const float* __restrict__ qvb,
    const float* __restrict__ Wo, const float* __restrict__ bo,
    const float* __restrict__ g2, const float* __restrict__ be2,
    const float* __restrict__ W1, const float* __restrict__ b1,
    float* __restrict__ tvb, float* __restrict__ h1b)
{
    const int bid = blockIdx.x;
    const int t   = threadIdx.x;

    __shared__ float A[16 * CH];     // ao
    __shared__ float Q[16 * CH];     // qv, then tv (reused)
    __shared__ float T[16][CH];      // pre-LN
    __shared__ float stats[16][2];

    const int dg = bid * 16;
    {
        const float4* sa = (const float4*)(aovb + (size_t)dg * CH);
        const float4* sq = (const float4*)(qvb  + (size_t)dg * CH);
        for (int i = t; i < 512; i += 256) { ((float4*)A)[i] = sa[i]; ((float4*)Q)[i] = sq[i]; }
    }
    __syncthreads();

    const int o = t & 127, rh = t >> 7;
    {
        const float4* wr = (const float4*)(Wo + (size_t)o * CH);
        float acc[8] = {0.f,0.f,0.f,0.f,0.f,0.f,0.f,0.f};
        for (int i = 0; i < 32; ++i) {
            float4 w = wr[i];
            #pragma unroll
            for (int j = 0; j < 8; ++j) {
                float4 a = ((const float4*)(A + (rh + 2 * j) * CH))[i];
                acc[j] = dot4(w, a, acc[j]);
            }
        }
        const float bb = bo[o];
        #pragma unroll
        for (int j = 0; j < 8; ++j) {
            int r = rh + 2 * j;
            T[r][o] = Q[r * CH + o] + acc[j] + bb;
        }
    }
    __syncthreads();

    {
        const int row = t >> 4, l = t & 15;
        float s1 = 0.f, s2 = 0.f;
        #pragma unroll
        for (int m = 0; m < 8; ++m) {
            float v = T[row][l + 16 * m];
            s1 += v; s2 += v * v;
        }
        #pragma unroll
        for (int off = 8; off >= 1; off >>= 1) {
            s1 += __shfl_xor(s1, off);
            s2 += __shfl_xor(s2, off);
        }
        if (l == 0) { stats[row][0] = s1; stats[row][1] = s2; }
    }
    __syncthreads();

    const float gg = g2[o], bb2 = be2[o];
    #pragma unroll
    for (int j = 0; j < 8; ++j) {
        int r = rh + 2 * j;
        float m   = stats[r][0] * (1.0f / 128.0f);
        float var = stats[r][1] * (1.0f / 128.0f) - m * m;
        float tv  = (T[r][o] - m) * rsqrtf(var + 1e-5f) * gg + bb2;
        Q[r * CH + o] = tv;                               // tv into LDS
        tvb[(size_t)(dg + r) * CH + o] = tv;              // K5 needs it (resid)
    }
    __syncthreads();

    // ---- FFN1: h1 = relu(tv @ W1^T + b1) for 16 dets, 512 outs (2 reps) ----
    #pragma unroll
    for (int rep = 0; rep < 2; ++rep) {
        const int oo = t + rep * 256;
        const float4* wr = (const float4*)(W1 + (size_t)oo * CH);
        float acc[16];
        #pragma unroll
        for (int r = 0; r < 16; ++r) acc[r] = 0.f;
        for (int i = 0; i < 32; ++i) {
            float4 w = wr[i];
            #pragma unroll
            for (int r = 0; r < 16; ++r) {
                float4 a = ((const float4*)(Q + r * CH))[i];
                acc[r] = dot4(w, a, acc[r]);
            }
        }
        const float bb = b1[oo];
        #pragma unroll
        for (int r = 0; r < 16; ++r)
            h1b[(size_t)(dg + r) * DFF + oo] = fmaxf(acc[r] + bb, 0.f);
    }
}

// ============================================================================
// K5: FFN2 (h1@W2^T+b2) + tv resid + LN2 -> scattered write to out (128 blocks)
// ============================================================================
__global__ __launch_bounds__(256) void ffn2_ln2_scatter_kernel(
    const float* __restrict__ h1b, const float* __restrict__ tvb,
    const float* __restrict__ W2, const float* __restrict__ b2,
    const float* __restrict__ g3, const float* __restrict__ be3,
    const int* __restrict__ inds, float* __restrict__ out)
{
    const int bid = blockIdx.x;
    const int t   = threadIdx.x;

    __shared__ float A[8 * DFF];
    __shared__ float Tv[8 * CH];
    __shared__ float T[8][CH];
    __shared__ float stats[8][2];

    const int dg = bid * 8;
    {
        const float4* sa = (const float4*)(h1b + (size_t)dg * DFF);
        for (int i = t; i < 1024; i += 256) ((float4*)A)[i] = sa[i];
        const float4* st = (const float4*)(tvb + (size_t)dg * CH);
        for (int i = t; i < 256; i += 256) ((float4*)Tv)[i] = st[i];
    }
    __syncthreads();

    const int o = t & 127, rh = t >> 7;
    {
        const float4* wr = (const float4*)(W2 + (size_t)o * DFF);
        float acc[4] = {0.f,0.f,0.f,0.f};
        #pragma unroll 4
        for (int i = 0; i < 128; ++i) {
            float4 w = wr[i];
            #pragma unroll
            for (int j = 0; j < 4; ++j) {
                float4 a = ((const float4*)(A + (rh + 2 * j) * DFF))[i];
                acc[j] = dot4(w, a, acc[j]);
            }
        }
        const float bb = b2[o];
        #pragma unroll
        for (int j = 0; j < 4; ++j) {
            int r = rh + 2 * j;
            T[r][o] = Tv[r * CH + o] + acc[j] + bb;
        }
    }
    __syncthreads();

    {
        const int row = t >> 5, l = t & 31;
        float s1 = 0.f, s2 = 0.f;
        #pragma unroll
        for (int m = 0; m < 4; ++m) {
            float v = T[row][l + 32 * m];
            s1 += v; s2 += v * v;
        }
        #pragma unroll
        for (int off = 16; off >= 1; off >>= 1) {
            s1 += __shfl_xor(s1, off);
            s2 += __shfl_xor(s2, off);
        }
        if (l == 0) { stats[row][0] = s1; stats[row][1] = s2; }
    }
    __syncthreads();

    const float gg = g3[o], bb3 = be3[o];
    #pragma unroll
    for (int j = 0; j < 4; ++j) {
        int r = rh + 2 * j;
        int det = dg + r;
        int b = det >> 7, n = det & 127;
        int p = inds[b * NDET + n];
        float m   = stats[r][0] * (1.0f / 128.0f);
        float var = stats[r][1] * (1.0f / 128.0f) - m * m;
        float ov  = (T[r][o] - m) * rsqrtf(var + 1e-5f) * gg + bb3;
        out[((size_t)b * CH + o) * HWSZ + p] = ov;        // scattered final write
    }
}

// ============================================================================
// Fallback path (ws too small): copy, then fully-fused det kernel
// ============================================================================
__global__ __launch_bounds__(256) void copy_x(const f4v* __restrict__ src,
                                              f4v* __restrict__ dst, size_t n4) {
    size_t i = (size_t)blockIdx.x * 256 + threadIdx.x;
    const size_t stride = (size_t)gridDim.x * 256;
    for (; i < n4; i += stride) {
        f4v v = src[i];
        __builtin_nontemporal_store(v, &dst[i]);
    }
}

__device__ __forceinline__ float block_layernorm(float v, int t,
        const float* __restrict__ gamma, const float* __restrict__ beta,
        float* redA, float* redB) {
    float s1 = v, s2 = v * v;
    #pragma unroll
    for (int off = 32; off >= 1; off >>= 1) {
        s1 += __shfl_xor(s1, off);
        s2 += __shfl_xor(s2, off);
    }
    if ((t & 63) == 0) { redA[t >> 6] = s1; redB[t >> 6] = s2; }
    __syncthreads();
    float sum = redA[0] + redA[1] + redA[2] + redA[3];
    float sq  = redB[0] + redB[1] + redB[2] + redB[3];
    __syncthreads();
    float m   = sum * (1.0f / 128.0f);
    float var = sq  * (1.0f / 128.0f) - m * m;
    float r = 0.f;
    if (t < CH) r = (v - m) * rsqrtf(var + 1e-5f) * gamma[t] + beta[t];
    return r;
}

__global__ __launch_bounds__(256) void er_fused_fb(
    const float* __restrict__ x, const float* __restrict__ vis,
    const int* __restrict__ dets, const int* __restrict__ inds,
    const float* __restrict__ Wqkv, const float* __restrict__ bqkv,
    const float* __restrict__ Wo,   const float* __restrict__ bo,
    const float* __restrict__ W1,   const float* __restrict__ b1,
    const float* __restrict__ W2,   const float* __restrict__ b2,
    const float* __restrict__ g2,   const float* __restrict__ be2,
    const float* __restrict__ g3,   const float* __restrict__ be3,
    float* __restrict__ out)
{
    const int bid = blockIdx.x;
    const int t   = threadIdx.x;

    __shared__ float kbuf[9][CH];
    __shared__ float qv[CH];
    __shared__ float qp[CH];
    __shared__ float kp[9][CH];
    __shared__ float vp[9][CH];
    __shared__ float att[NHEAD][9];
    __shared__ float aov[CH];
    __shared__ float tv[CH];
    __shared__ float h1[DFF];
    __shared__ float part[256];
    __shared__ float redA[4], redB[4];
    __shared__ float msk[48][4];

    const int b = bid >> 7;
    const int n = bid & (NDET - 1);

    const int4 dv = *((const int4*)(dets + (size_t)(b * NDET + n) * 4));
    const int sx = dv.x, sy = dv.y, ex = dv.z, ey = dv.w;
    const int Lx = ex - sx, Ly = ey - sy;
    const int xs1 = sx + Lx / 3,        xs2 = sx + 2 * Lx / 3;
    const int xe0 = sx + (Lx + 2) / 3,  xe1 = sx + (2 * Lx + 2) / 3;
    const int ys1 = sy + Ly / 3,        ys2 = sy + 2 * Ly / 3;
    const int ye0 = sy + (Ly + 2) / 3,  ye1 = sy + (2 * Ly + 2) / 3;

    const int p = inds[b * NDET + n];

    if (t < 48) {
        int y = sy + t;
        bool inb = (y < ey);
        msk[t][0] = (inb && y < ye0)              ? 1.f : 0.f;
        msk[t][1] = (inb && y >= ys1 && y < ye1)  ? 1.f : 0.f;
        msk[t][2] = (inb && y >= ys2)             ? 1.f : 0.f;
        msk[t][3] = 0.f;
    }
    if (t < CH) {
        float qval = x[((size_t)b * CH + t) * HWSZ + p];
        float vv   = vis[(size_t)b * HWSZ + p];
        int vidx   = (int)(vv * 10.0f);
        float fr   = powf(10000.0f, -(float)(t & 126) * (1.0f / 128.0f));
        float ang  = 0.1f * (float)vidx * fr;
        float pe   = (t & 1) ? cosf(ang) : sinf(ang);
        qv[t] = qval + pe;
    }
    __syncthreads();

    {
        const int g   = t >> 4;
        const int lx  = t & 15;
        const int sx4 = sx & ~3;
        const int xb  = sx4 + lx * 4;
        const int lxmax = ((ex - 1) - sx4) >> 2;
        const int xba = sx4 + ((lx < lxmax) ? lx : lxmax) * 4;

        float4 mx0, mx1, mx2;
        {
            float m0[4], m1[4], m2[4];
            #pragma unroll
            for (int e = 0; e < 4; ++e) {
                int xx = xb + e;
                m0[e] = (xx >= sx  && xx < xe0) ? 1.f : 0.f;
                m1[e] = (xx >= xs1 && xx < xe1) ? 1.f : 0.f;
                m2[e] = (xx >= xs2 && xx < ex ) ? 1.f : 0.f;
            }
            mx0 = make_float4(m0[0], m0[1], m0[2], m0[3]);
            mx1 = make_float4(m1[0], m1[1], m1[2], m1[3]);
            mx2 = make_float4(m2[0], m2[1], m2[2], m2[3]);
        }

        const int rows_n = ey - sy;
        const int nch    = (rows_n + 7) >> 3;

        for (int c = 0; c < 8; ++c) {
            const int dd = g + c * 16;
            const float* base = x + ((size_t)b * CH + dd) * HWSZ + xba;
            float4 ac0 = make_float4(0.f,0.f,0.f,0.f);
            float4 ac1 = make_float4(0.f,0.f,0.f,0.f);
            float4 ac2 = make_float4(0.f,0.f,0.f,0.f);
            for (int ck = 0; ck < nch; ++ck) {
                const int y0 = sy + (ck << 3);
                float4 v[8];
                #pragma unroll
                for (int k = 0; k < 8; ++k) {
                    int y = y0 + k;
                    y = (y < ey) ? y : (ey - 1);
                    v[k] = *(const float4*)(base + (size_t)y * WWID);
                }
                #pragma unroll
                for (int k = 0; k < 8; ++k) {
                    const float4 m = *(const float4*)&msk[(y0 - sy) + k][0];
                    ac0.x = fmaf(m.x, v[k].x, ac0.x); ac0.y = fmaf(m.x, v[k].y, ac0.y);
                    ac0.z = fmaf(m.x, v[k].z, ac0.z); ac0.w = fmaf(m.x, v[k].w, ac0.w);
                    ac1.x = fmaf(m.y, v[k].x, ac1.x); ac1.y = fmaf(m.y, v[k].y, ac1.y);
                    ac1.z = fmaf(m.y, v[k].z, ac1.z); ac1.w = fmaf(m.y, v[k].w, ac1.w);
                    ac2.x = fmaf(m.z, v[k].x, ac2.x); ac2.y = fmaf(m.z, v[k].y, ac2.y);
                    ac2.z = fmaf(m.z, v[k].z, ac2.z); ac2.w = fmaf(m.z, v[k].w, ac2.w);
                }
            }
            float a[9];
            a[0] = dot4(mx0, ac0, 0.f); a[1] = dot4(mx1, ac0, 0.f); a[2] = dot4(mx2, ac0, 0.f);
            a[3] = dot4(mx0, ac1, 0.f); a[4] = dot4(mx1, ac1, 0.f); a[5] = dot4(mx2, ac1, 0.f);
            a[6] = dot4(mx0, ac2, 0.f); a[7] = dot4(mx1, ac2, 0.f); a[8] = dot4(mx2, ac2, 0.f);
            #pragma unroll
            for (int jj = 0; jj < 9; ++jj) {
                a[jj] += __shfl_xor(a[jj], 8);
                a[jj] += __shfl_xor(a[jj], 4);
                a[jj] += __shfl_xor(a[jj], 2);
                a[jj] += __shfl_xor(a[jj], 1);
            }
            if (lx == 0) {
                int w0 = xe0 - sx, w1 = xe1 - xs1, w2 = ex - xs2;
                int h0 = ye0 - sy, h1r = ye1 - ys1, h2 = ey - ys2;
                kbuf[0][dd] = a[0] / (float)(h0 * w0);
                kbuf[1][dd] = a[1] / (float)(h0 * w1);
                kbuf[2][dd] = a[2] / (float)(h0 * w2);
                kbuf[3][dd] = a[3] / (float)(h1r * w0);
                kbuf[4][dd] = a[4] / (float)(h1r * w1);
                kbuf[5][dd] = a[5] / (float)(h1r * w2);
                kbuf[6][dd] = a[6] / (float)(h2 * w0);
                kbuf[7][dd] = a[7] / (float)(h2 * w1);
                kbuf[8][dd] = a[8] / (float)(h2 * w2);
            }
        }
    }
    __syncthreads();

    if (t < CH) {
        const float4* wr = (const float4*)(Wqkv + (size_t)t * CH);
        const float4* qq = (const float4*)qv;
        float s = 0.f;
        #pragma unroll 8
        for (int i = 0; i < CH / 4; ++i) s = dot4(wr[i], qq[i], s);
        qp[t] = s + bqkv[t];
    }
    {
        const int o = t & (CH - 1);
        const int which = t >> 7;
        const float4* wr = (const float4*)(Wqkv + (size_t)(CH + which * CH + o) * CH);
        float acc[9] = {0.f,0.f,0.f,0.f,0.f,0.f,0.f,0.f,0.f};
        #pragma unroll 4
        for (int i = 0; i < CH / 4; ++i) {
            float4 w = wr[i];
            #pragma unroll
            for (int s = 0; s < 9; ++s) {
                float4 kk = ((const float4*)(&kbuf[s][0]))[i];
                acc[s] = dot4(w, kk, acc[s]);
            }
        }
        float bias = bqkv[CH + which * CH + o];
        if (which == 0) {
            #pragma unroll
            for (int s = 0; s < 9; ++s) kp[s][o] = acc[s] + bias;
        } else {
            #pragma unroll
            for (int s = 0; s < 9; ++s) vp[s][o] = acc[s] + bias;
        }
    }
    __syncthreads();

    if (t < NHEAD * 9) {
        int h = t / 9, s = t - h * 9;
        const float* qh = qp + h * HDIM;
        const float* kh = &kp[s][h * HDIM];
        float a = 0.f;
        #pragma unroll
        for (int e = 0; e < HDIM; ++e) a = fmaf(qh[e], kh[e], a);
        att[h][s] = a * 0.25f;
    }
    __syncthreads();

    if (t < NHEAD) {
        float m = att[t][0];
        #pragma unroll
        for (int s = 1; s < 9; ++s) m = fmaxf(m, att[t][s]);
        float e[9]; float sum = 0.f;
        #pragma unroll
        for (int s = 0; s < 9; ++s) { e[s] = expf(att[t][s] - m); sum += e[s]; }
        float inv = 1.0f / sum;
        #pragma unroll
        for (int s = 0; s < 9; ++s) att[t][s] = e[s] * inv;
    }
    __syncthreads();

    if (t < CH) {
        int h = t >> 4;
        float a = 0.f;
        #pragma unroll
        for (int s = 0; s < 9; ++s) a = fmaf(att[h][s], vp[s][t], a);
        aov[t] = a;
    }
    __syncthreads();

    float v1 = 0.f;
    if (t < CH) {
        const float4* wr = (const float4*)(Wo + (size_t)t * CH);
        const float4* u4 = (const float4*)aov;
        float s = 0.f;
        #pragma unroll 8
        for (int i = 0; i < CH / 4; ++i) s = dot4(wr[i], u4[i], s);
        v1 = qv[t] + s + bo[t];
    }
    float t1 = block_layernorm(v1, t, g2, be2, redA, redB);
    if (t < CH) tv[t] = t1;
    __syncthreads();

    #pragma unroll
    for (int rep = 0; rep < 2; ++rep) {
        int o = t + rep * 256;
        const float4* wr = (const float4*)(W1 + (size_t)o * CH);
        const float4* u4 = (const float4*)tv;
        float s = 0.f;
        #pragma unroll 8
        for (int i = 0; i < CH / 4; ++i) s = dot4(wr[i], u4[i], s);
        h1[o] = fmaxf(s + b1[o], 0.f);
    }
    __syncthreads();

    {
        int o = t & (CH - 1), hf = t >> 7;
        const float4* wr = (const float4*)(W2 + (size_t)o * DFF + hf * (DFF / 2));
        const float4* u4 = (const float4*)(h1 + hf * (DFF / 2));
        float s = 0.f;
        #pragma unroll 8
        for (int i = 0; i < DFF / 8; ++i) s = dot4(wr[i], u4[i], s);
        part[t] = s;
    }
    __syncthreads();

    float v2 = 0.f;
    if (t < CH) {
        float t2 = part[t] + part[t + 128] + b2[t];
        v2 = tv[t] + t2;
    }
    float outv = block_layernorm(v2, t, g3, be3, redA, redB);
    if (t < CH) out[((size_t)b * CH + t) * HWSZ + p] = outv;
}

extern "C" void kernel_launch(void* const* d_in, const int* in_sizes, int n_in,
                              void* d_out, int out_size, void* d_ws, size_t ws_size,
                              hipStream_t stream) {
    const float* x    = (const float*)d_in[0];
    const float* vis  = (const float*)d_in[1];
    const int*   dets = (const int*)d_in[2];
    const int*   inds = (const int*)d_in[3];
    const float* Wqkv = (const float*)d_in[4];
    const float* bqkv = (const float*)d_in[5];
    const float* Wo   = (const float*)d_in[6];
    const float* bo   = (const float*)d_in[7];
    const float* W1   = (const float*)d_in[8];
    const float* b1   = (const float*)d_in[9];
    const float* W2   = (const float*)d_in[10];
    const float* b2   = (const float*)d_in[11];
    const float* g2   = (const float*)d_in[12];
    const float* be2  = (const float*)d_in[13];
    const float* g3   = (const float*)d_in[14];
    const float* be3  = (const float*)d_in[15];
    float* out = (float*)d_out;

    // workspace layout (floats)
    const size_t SZ_KOUT = (size_t)NDB * KSTRIDE;
    const size_t SZ_128  = (size_t)NDB * CH;
    const size_t SZ_KVP  = (size_t)NDB * 2 * 9 * CH;
    const size_t SZ_H1   = (size_t)NDB * DFF;
    const size_t need = (SZ_KOUT + 4 * SZ_128 + SZ_KVP + SZ_H1) * sizeof(float);

    const size_t N4 = (size_t)BB * CH * HWSZ / 4;
    if (ws_size >= need) {
        float* kout = (float*)d_ws;
        float* qvb  = kout + SZ_KOUT;
        float* qpb  = qvb  + SZ_128;
        float* kvp  = qpb  + SZ_128;
        float* aovb = kvp  + SZ_KVP;
        float* tvb  = aovb + SZ_128;
        float* h1b  = tvb  + SZ_128;

        pool_stream<<<dim3(NPLANE), dim3(256), 0, stream>>>(x, dets, kout, out);
        qkv_kernel<<<dim3(K2_KV + K2_Q), dim3(256), 0, stream>>>(
            x, vis, inds, kout, Wqkv, bqkv, kvp, qpb, qvb);
        attn_kernel<<<dim3(NDB), dim3(64), 0, stream>>>(kvp, qpb, aovb);
        wo_ln1_ffn1_kernel<<<dim3(64), dim3(256), 0, stream>>>(
            aovb, qvb, Wo, bo, g2, be2, W1, b1, tvb, h1b);
        ffn2_ln2_scatter_kernel<<<dim3(128), dim3(256), 0, stream>>>(
            h1b, tvb, W2, b2, g3, be3, inds, out);
    } else {
        copy_x<<<dim3(2048), dim3(256), 0, stream>>>(
            (const f4v*)x, (f4v*)out, N4);
        er_fused_fb<<<dim3(NDB), dim3(256), 0, stream>>>(
            x, vis, dets, inds, Wqkv, bqkv, Wo, bo, W1, b1, W2, b2,
            g2, be2, g3, be3, out);
    }
}

// Round 10
// 147.960 us; speedup vs baseline: 1.4053x; 1.0460x over previous
//
#include <hip/hip_runtime.h>
#include <math.h>

#define BB 8
#define CH 128
#define HH 152
#define WWID 272
#define HWSZ (HH*WWID)
#define NDET 128
#define NHEAD 8
#define HDIM 16
#define DFF 512
#define NDB (BB*NDET)      // 1024 dets
#define KSTRIDE 1152       // 9*CH floats of pooled k per det
#define CHUNK 19           // rows per LDS prefix-sum slab
#define RHALF 76           // rows per half-plane block (152 = 2*76, 76 = 4*19)
#define SROW 276           // S row stride in floats (273 used, %4==0)

typedef float f4v __attribute__((ext_vector_type(4)));

__device__ __forceinline__ float dot4(float4 w, float4 u, float s) {
    s = fmaf(w.x, u.x, s);
    s = fmaf(w.y, u.y, s);
    s = fmaf(w.z, u.z, s);
    s = fmaf(w.w, u.w, s);
    return s;
}

// ============================================================================
// K1: fused copy + pooling partials. One block per (plane, row-half):
// 2048 blocks. Waves stream rows (read -> NT store = the copy) and build an
// exclusive prefix-sum per row in LDS; det-threads accumulate PARTIAL box
// cell sums over this half's rows -> kpart[rhalf]. Tail combines + divides.
// LDS = S only (20.5KB, combine scratch folded into S) -> 7 blocks/CU.
// ============================================================================
__global__ __launch_bounds__(256) void pool_stream(
    const float* __restrict__ x, const int* __restrict__ dets,
    float* __restrict__ kpart, float* __restrict__ out)
{
    const int bid   = blockIdx.x;          // plane*2 + rhalf
    const int t     = threadIdx.x;
    const int plane = bid >> 1, rhalf = bid & 1;
    const int b     = plane >> 7, ch = plane & 127;
    const int lane  = t & 63,  w  = t >> 6;
    const int rbeg  = rhalf * RHALF;

    __shared__ float S[CHUNK * SROW];      // prefix sums; reused as scratch

    const float* xp = x + ((size_t)b * CH + ch) * HWSZ;
    f4v* o4 = (f4v*)(out + ((size_t)b * CH + ch) * HWSZ);

    // ---- det-thread setup: thread d & d+128 both own det d ----
    const int d = t & 127, half = t >> 7;
    const int4 dv = *((const int4*)(dets + (size_t)(b * NDET + d) * 4));
    const int sx = dv.x, sy = dv.y, ex = dv.z, ey = dv.w;
    const int Lx = ex - sx, Ly = ey - sy;
    // cell edges (cells OVERLAP due to floor/ceil in reference)
    const int xs1 = sx + Lx / 3,        xs2 = sx + 2 * Lx / 3;
    const int xe0 = sx + (Lx + 2) / 3,  xe1 = sx + (2 * Lx + 2) / 3;
    const int ys1 = sy + Ly / 3,        ys2 = sy + 2 * Ly / 3;
    const int ye0 = sy + (Ly + 2) / 3,  ye1 = sy + (2 * Ly + 2) / 3;

    float acc[9] = {0.f,0.f,0.f,0.f,0.f,0.f,0.f,0.f,0.f};

    #pragma unroll 1
    for (int c = 0; c < RHALF / CHUNK; ++c) {
        const int cbeg = rbeg + c * CHUNK;

        // ---- phase A: stream + scan rows (wave-parallel, prefetched) ----
        {
            int rl = w;                       // wave w does rows w, w+4, ...
            f4v vm = (f4v)(0.f), ve = (f4v)(0.f);
            bool have = (rl < CHUNK);
            if (have) {
                const f4v* rowp = (const f4v*)(xp + (size_t)(cbeg + rl) * WWID);
                vm = rowp[lane];
                if (lane < 4) ve = rowp[64 + lane];
            }
            while (have) {
                const int rc = rl;
                f4v v = vm, e = ve;
                rl += 4;
                have = (rl < CHUNK);
                if (have) {                   // prefetch next row
                    const f4v* rowp = (const f4v*)(xp + (size_t)(cbeg + rl) * WWID);
                    vm = rowp[lane];
                    if (lane < 4) ve = rowp[64 + lane];
                }
                // copy current row to out (NT: don't evict x from L3)
                __builtin_nontemporal_store(v, &o4[(size_t)(cbeg + rc) * 68 + lane]);
                if (lane < 4)
                    __builtin_nontemporal_store(e, &o4[(size_t)(cbeg + rc) * 68 + 64 + lane]);
                // exclusive prefix: S[c] = sum of cols [0, c)
                float T = v[0] + v[1] + v[2] + v[3];
                float s = T;
                #pragma unroll
                for (int o = 1; o < 64; o <<= 1) {
                    float u = __shfl_up(s, o);
                    if (lane >= o) s += u;
                }
                float off0 = s - T;
                float* Sr = S + rc * SROW;
                f4v sm;
                sm[0] = off0;
                sm[1] = off0 + v[0];
                sm[2] = off0 + v[0] + v[1];
                sm[3] = off0 + v[0] + v[1] + v[2];
                *(f4v*)&Sr[4 * lane] = sm;
                float R  = __shfl(s, 63);                       // total cols 0..255
                float Te = (lane < 4) ? (e[0]+e[1]+e[2]+e[3]) : 0.f;
                float T0 = __shfl(Te, 0), T1 = __shfl(Te, 1);
                float T2 = __shfl(Te, 2), T3 = __shfl(Te, 3);
                if (lane < 4) {
                    float offE = R + ((lane > 0) ? T0 : 0.f)
                                   + ((lane > 1) ? T1 : 0.f)
                                   + ((lane > 2) ? T2 : 0.f);
                    f4v se;
                    se[0] = offE;
                    se[1] = offE + e[0];
                    se[2] = offE + e[0] + e[1];
                    se[3] = offE + e[0] + e[1] + e[2];
                    *(f4v*)&Sr[256 + 4 * lane] = se;
                }
                if (lane == 0) Sr[272] = R + T0 + T1 + T2 + T3;
            }
        }
        __syncthreads();

        // ---- phase B: det partial accumulation from prefix sums ----
        {
            int lo = (sy > cbeg) ? sy : cbeg;
            int hi = (ey < cbeg + CHUNK) ? ey : (cbeg + CHUNK);
            if (lo < hi) {
                int mid = (lo + hi + 1) >> 1;
                int y0 = half ? mid : lo;
                int y1 = half ? hi  : mid;
                for (int y = y0; y < y1; ++y) {
                    const float* Sr = S + (y - cbeg) * SROW;
                    float c0 = Sr[xe0] - Sr[sx];
                    float c1 = Sr[xe1] - Sr[xs1];
                    float c2 = Sr[ex]  - Sr[xs2];
                    float m0 = (y < ye0) ? 1.f : 0.f;
                    float m1 = (y >= ys1 && y < ye1) ? 1.f : 0.f;
                    float m2 = (y >= ys2) ? 1.f : 0.f;
                    acc[0] = fmaf(m0, c0, acc[0]); acc[1] = fmaf(m0, c1, acc[1]); acc[2] = fmaf(m0, c2, acc[2]);
                    acc[3] = fmaf(m1, c0, acc[3]); acc[4] = fmaf(m1, c1, acc[4]); acc[5] = fmaf(m1, c2, acc[5]);
                    acc[6] = fmaf(m2, c0, acc[6]); acc[7] = fmaf(m2, c1, acc[7]); acc[8] = fmaf(m2, c2, acc[8]);
                }
            }
        }
        __syncthreads();
    }

    // ---- combine thread-halves via S (reused as scratch), write partials ----
    if (half) {
        #pragma unroll
        for (int j = 0; j < 9; ++j) S[d * 9 + j] = acc[j];
    }
    __syncthreads();
    if (!half) {
        float* kd = kpart + ((size_t)rhalf * NDB + (size_t)(b * NDET + d)) * KSTRIDE + ch;
        #pragma unroll
        for (int j = 0; j < 9; ++j)
            kd[j * CH] = acc[j] + S[d * 9 + j];    // NO area divide (tail does it)
    }
}

// ============================================================================
// K2: fully-fused transformer tail. 512 blocks x 2 dets x 256 threads.
// k-combine -> QKV -> attention -> Wo+LN1 -> FFN1 -> FFN2+LN2 -> scatter.
// All intermediates in LDS; weights stream from L2 (amortized over 2 dets).
// ============================================================================
__global__ __launch_bounds__(256) void tail_kernel(
    const float* __restrict__ x, const float* __restrict__ vis,
    const int* __restrict__ dets, const int* __restrict__ inds,
    const float* __restrict__ kpA, const float* __restrict__ kpB,
    const float* __restrict__ Wqkv, const float* __restrict__ bqkv,
    const float* __restrict__ Wo,   const float* __restrict__ bo,
    const float* __restrict__ W1,   const float* __restrict__ b1,
    const float* __restrict__ W2,   const float* __restrict__ b2,
    const float* __restrict__ g2,   const float* __restrict__ be2,
    const float* __restrict__ g3,   const float* __restrict__ be3,
    float* __restrict__ out)
{
    const int bid = blockIdx.x;
    const int t   = threadIdx.x;
    const int d0  = bid * 2;           // 2 dets per block, never straddles images
    const int b   = d0 >> 7;
    const int o   = t & 127, dl = t >> 7;

    __shared__ float kbuf[2 * 9 * CH];   // pooled k (area-divided)
    __shared__ float kp[2 * 9 * CH];
    __shared__ float vp[2 * 9 * CH];
    __shared__ float invA[2][9];
    __shared__ float qv[2][CH];
    __shared__ float qp[2][CH];
    __shared__ float attl[2][NHEAD][9];
    __shared__ float aov[2][CH];
    __shared__ float Tv[2][CH];
    __shared__ float h1[2][DFF];
    __shared__ float part2[2][2][CH];    // [half][det][o]
    __shared__ float wst[4][2];

    // ---- inverse cell areas (18 threads) ----
    if (t < 18) {
        int dd = t / 9, slot = t - dd * 9;
        const int4 dv = *((const int4*)(dets + (size_t)(b * NDET + ((d0 + dd) & 127)) * 4));
        int sx = dv.x, sy = dv.y, ex = dv.z, ey = dv.w;
        int Lx = ex - sx, Ly = ey - sy;
        int xs1 = sx + Lx / 3,       xs2 = sx + 2 * Lx / 3;
        int xe0 = sx + (Lx + 2) / 3, xe1 = sx + (2 * Lx + 2) / 3;
        int ys1 = sy + Ly / 3,       ys2 = sy + 2 * Ly / 3;
        int ye0 = sy + (Ly + 2) / 3, ye1 = sy + (2 * Ly + 2) / 3;
        int xi = slot % 3, yi = slot / 3;
        int wdt = (xi == 0) ? (xe0 - sx) : (xi == 1) ? (xe1 - xs1) : (ex - xs2);
        int hgt = (yi == 0) ? (ye0 - sy) : (yi == 1) ? (ye1 - ys1) : (ey - ys2);
        invA[dd][slot] = 1.0f / (float)(hgt * wdt);
    }
    // ---- q gather + positional embedding ----
    {
        int p = inds[b * NDET + ((d0 + dl) & 127)];
        float qval = x[((size_t)b * CH + o) * HWSZ + p];
        float vv   = vis[(size_t)b * HWSZ + p];
        int vidx   = (int)(vv * 10.0f);
        float fr   = powf(10000.0f, -(float)(o & 126) * (1.0f / 128.0f));
        float ang  = 0.1f * (float)vidx * fr;
        qv[dl][o]  = qval + ((o & 1) ? cosf(ang) : sinf(ang));
    }
    __syncthreads();

    // ---- combine pooling partials + area divide ----
    for (int i = t; i < 2 * KSTRIDE; i += 256) {
        int dd = (i >= KSTRIDE);
        int r  = i - dd * KSTRIDE;
        int slot = r >> 7;
        float vA = kpA[(size_t)(d0 + dd) * KSTRIDE + r];
        float vB = kpB[(size_t)(d0 + dd) * KSTRIDE + r];
        kbuf[dd * KSTRIDE + r] = (vA + vB) * invA[dd][slot];
    }
    __syncthreads();

    // ---- qp = Wq @ qv ----
    {
        const float4* wr = (const float4*)(Wqkv + (size_t)o * CH);
        const float4* qq = (const float4*)&qv[dl][0];
        float s = 0.f;
        #pragma unroll 8
        for (int i = 0; i < 32; ++i) s = dot4(wr[i], qq[i], s);
        qp[dl][o] = s + bqkv[o];
    }
    // ---- kp/vp: 18 rows x 128 outs, which = k or v ----
    {
        const int which = t >> 7;
        const float4* wr = (const float4*)(Wqkv + (size_t)(CH + which * CH + o) * CH);
        float acc[18];
        #pragma unroll
        for (int r = 0; r < 18; ++r) acc[r] = 0.f;
        for (int i = 0; i < 32; ++i) {
            float4 w = wr[i];
            #pragma unroll
            for (int r = 0; r < 18; ++r) {
                float4 a = ((const float4*)kbuf)[r * 32 + i];
                acc[r] = dot4(w, a, acc[r]);
            }
        }
        const float bias = bqkv[CH + which * CH + o];
        float* dst = which ? vp : kp;
        #pragma unroll
        for (int r = 0; r < 18; ++r) dst[r * CH + o] = acc[r] + bias;
    }
    __syncthreads();

    // ---- attention scores ----
    if (o < 72) {
        int h = o / 9, s = o - h * 9;
        const float* qh = &qp[dl][h * HDIM];
        const float* kh = &kp[dl * KSTRIDE + s * CH + h * HDIM];
        float a = 0.f;
        #pragma unroll
        for (int e = 0; e < HDIM; ++e) a = fmaf(qh[e], kh[e], a);
        attl[dl][h][s] = a * 0.25f;
    }
    __syncthreads();
    // ---- softmax per (det, head) ----
    if (o < 8) {
        float m = attl[dl][o][0];
        #pragma unroll
        for (int s = 1; s < 9; ++s) m = fmaxf(m, attl[dl][o][s]);
        float e[9]; float sum = 0.f;
        #pragma unroll
        for (int s = 0; s < 9; ++s) { e[s] = expf(attl[dl][o][s] - m); sum += e[s]; }
        float inv = 1.0f / sum;
        #pragma unroll
        for (int s = 0; s < 9; ++s) attl[dl][o][s] = e[s] * inv;
    }
    __syncthreads();
    // ---- ao = att @ vp ----
    {
        int h = o >> 4;
        float a = 0.f;
        #pragma unroll
        for (int s = 0; s < 9; ++s) a = fmaf(attl[dl][h][s], vp[dl * KSTRIDE + s * CH + o], a);
        aov[dl][o] = a;
    }
    __syncthreads();

    // ---- Wo + resid ----
    float v1;
    {
        const float4* wr = (const float4*)(Wo + (size_t)o * CH);
        const float4* u4 = (const float4*)&aov[dl][0];
        float s = 0.f;
        #pragma unroll 8
        for (int i = 0; i < 32; ++i) s = dot4(wr[i], u4[i], s);
        v1 = qv[dl][o] + s + bo[o];
    }
    // ---- LN1 (det dl spans waves 2dl, 2dl+1) ----
    {
        float s1 = v1, s2 = v1 * v1;
        #pragma unroll
        for (int off = 32; off >= 1; off >>= 1) {
            s1 += __shfl_xor(s1, off);
            s2 += __shfl_xor(s2, off);
        }
        if ((t & 63) == 0) { wst[t >> 6][0] = s1; wst[t >> 6][1] = s2; }
    }
    __syncthreads();
    {
        float sum = wst[2 * dl][0] + wst[2 * dl + 1][0];
        float sq  = wst[2 * dl][1] + wst[2 * dl + 1][1];
        float m   = sum * (1.0f / 128.0f);
        float var = sq  * (1.0f / 128.0f) - m * m;
        Tv[dl][o] = (v1 - m) * rsqrtf(var + 1e-5f) * g2[o] + be2[o];
    }
    __syncthreads();

    // ---- FFN1: 512 outs x 2 dets ----
    #pragma unroll
    for (int rep = 0; rep < 2; ++rep) {
        int oo = t + rep * 256;
        const float4* wr = (const float4*)(W1 + (size_t)oo * CH);
        float a0 = 0.f, a1 = 0.f;
        for (int i = 0; i < 32; ++i) {
            float4 w = wr[i];
            a0 = dot4(w, ((const float4*)&Tv[0][0])[i], a0);
            a1 = dot4(w, ((const float4*)&Tv[1][0])[i], a1);
        }
        float bb = b1[oo];
        h1[0][oo] = fmaxf(a0 + bb, 0.f);
        h1[1][oo] = fmaxf(a1 + bb, 0.f);
    }
    __syncthreads();

    // ---- FFN2 partials: thread (o, hf) does half the 512-dot for both dets ----
    {
        const int hf = t >> 7;
        const float4* wr = (const float4*)(W2 + (size_t)o * DFF + hf * (DFF / 2));
        float a0 = 0.f, a1 = 0.f;
        #pragma unroll 4
        for (int i = 0; i < 64; ++i) {
            float4 w = wr[i];
            a0 = dot4(w, ((const float4*)&h1[0][hf * 256])[i], a0);
            a1 = dot4(w, ((const float4*)&h1[1][hf * 256])[i], a1);
        }
        part2[hf][0][o] = a0;
        part2[hf][1][o] = a1;
    }
    __syncthreads();
    float v2 = part2[0][dl][o] + part2[1][dl][o] + b2[o] + Tv[dl][o];
    // ---- LN2 ----
    {
        float s1 = v2, s2 = v2 * v2;
        #pragma unroll
        for (int off = 32; off >= 1; off >>= 1) {
            s1 += __shfl_xor(s1, off);
            s2 += __shfl_xor(s2, off);
        }
        if ((t & 63) == 0) { wst[t >> 6][0] = s1; wst[t >> 6][1] = s2; }
    }
    __syncthreads();
    {
        float sum = wst[2 * dl][0] + wst[2 * dl + 1][0];
        float sq  = wst[2 * dl][1] + wst[2 * dl + 1][1];
        float m   = sum * (1.0f / 128.0f);
        float var = sq  * (1.0f / 128.0f) - m * m;
        float ov  = (v2 - m) * rsqrtf(var + 1e-5f) * g3[o] + be3[o];
        int p = inds[b * NDET + ((d0 + dl) & 127)];
        out[((size_t)b * CH + o) * HWSZ + p] = ov;       // scattered final write
    }
}

// ============================================================================
// Fallback path (ws too small): copy, then fully-fused det kernel
// ============================================================================
__global__ __launch_bounds__(256) void copy_x(const f4v* __restrict__ src,
                                              f4v* __restrict__ dst, size_t n4) {
    size_t i = (size_t)blockIdx.x * 256 + threadIdx.x;
    const size_t stride = (size_t)gridDim.x * 256;
    for (; i < n4; i += stride) {
        f4v v = src[i];
        __builtin_nontemporal_store(v, &dst[i]);
    }
}

__device__ __forceinline__ float block_layernorm(float v, int t,
        const float* __restrict__ gamma, const float* __restrict__ beta,
        float* redA, float* redB) {
    float s1 = v, s2 = v * v;
    #pragma unroll
    for (int off = 32; off >= 1; off >>= 1) {
        s1 += __shfl_xor(s1, off);
        s2 += __shfl_xor(s2, off);
    }
    if ((t & 63) == 0) { redA[t >> 6] = s1; redB[t >> 6] = s2; }
    __syncthreads();
    float sum = redA[0] + redA[1] + redA[2] + redA[3];
    float sq  = redB[0] + redB[1] + redB[2] + redB[3];
    __syncthreads();
    float m   = sum * (1.0f / 128.0f);
    float var = sq  * (1.0f / 128.0f) - m * m;
    float r = 0.f;
    if (t < CH) r = (v - m) * rsqrtf(var + 1e-5f) * gamma[t] + beta[t];
    return r;
}

__global__ __launch_bounds__(256) void er_fused_fb(
    const float* __restrict__ x, const float* __restrict__ vis,
    const int* __restrict__ dets, const int* __restrict__ inds,
    const float* __restrict__ Wqkv, const float* __restrict__ bqkv,
    const float* __restrict__ Wo,   const float* __restrict__ bo,
    const float* __restrict__ W1,   const float* __restrict__ b1,
    const float* __restrict__ W2,   const float* __restrict__ b2,
    const float* __restrict__ g2,   const float* __restrict__ be2,
    const float* __restrict__ g3,   const float* __restrict__ be3,
    float* __restrict__ out)
{
    const int bid = blockIdx.x;
    const int t   = threadIdx.x;

    __shared__ float kbuf[9][CH];
    __shared__ float qv[CH];
    __shared__ float qp[CH];
    __shared__ float kp[9][CH];
    __shared__ float vp[9][CH];
    __shared__ float att[NHEAD][9];
    __shared__ float aov[CH];
    __shared__ float tv[CH];
    __shared__ float h1[DFF];
    __shared__ float part[256];
    __shared__ float redA[4], redB[4];
    __shared__ float msk[48][4];

    const int b = bid >> 7;
    const int n = bid & (NDET - 1);

    const int4 dv = *((const int4*)(dets + (size_t)(b * NDET + n) * 4));
    const int sx = dv.x, sy = dv.y, ex = dv.z, ey = dv.w;
    const int Lx = ex - sx, Ly = ey - sy;
    const int xs1 = sx + Lx / 3,        xs2 = sx + 2 * Lx / 3;
    const int xe0 = sx + (Lx + 2) / 3,  xe1 = sx + (2 * Lx + 2) / 3;
    const int ys1 = sy + Ly / 3,        ys2 = sy + 2 * Ly / 3;
    const int ye0 = sy + (Ly + 2) / 3,  ye1 = sy + (2 * Ly + 2) / 3;

    const int p = inds[b * NDET + n];

    if (t < 48) {
        int y = sy + t;
        bool inb = (y < ey);
        msk[t][0] = (inb && y < ye0)              ? 1.f : 0.f;
        msk[t][1] = (inb && y >= ys1 && y < ye1)  ? 1.f : 0.f;
        msk[t][2] = (inb && y >= ys2)             ? 1.f : 0.f;
        msk[t][3] = 0.f;
    }
    if (t < CH) {
        float qval = x[((size_t)b * CH + t) * HWSZ + p];
        float vv   = vis[(size_t)b * HWSZ + p];
        int vidx   = (int)(vv * 10.0f);
        float fr   = powf(10000.0f, -(float)(t & 126) * (1.0f / 128.0f));
        float ang  = 0.1f * (float)vidx * fr;
        float pe   = (t & 1) ? cosf(ang) : sinf(ang);
        qv[t] = qval + pe;
    }
    __syncthreads();

    {
        const int g   = t >> 4;
        const int lx  = t & 15;
        const int sx4 = sx & ~3;
        const int xb  = sx4 + lx * 4;
        const int lxmax = ((ex - 1) - sx4) >> 2;
        const int xba = sx4 + ((lx < lxmax) ? lx : lxmax) * 4;

        float4 mx0, mx1, mx2;
        {
            float m0[4], m1[4], m2[4];
            #pragma unroll
            for (int e = 0; e < 4; ++e) {
                int xx = xb + e;
                m0[e] = (xx >= sx  && xx < xe0) ? 1.f : 0.f;
                m1[e] = (xx >= xs1 && xx < xe1) ? 1.f : 0.f;
                m2[e] = (xx >= xs2 && xx < ex ) ? 1.f : 0.f;
            }
            mx0 = make_float4(m0[0], m0[1], m0[2], m0[3]);
            mx1 = make_float4(m1[0], m1[1], m1[2], m1[3]);
            mx2 = make_float4(m2[0], m2[1], m2[2], m2[3]);
        }

        const int rows_n = ey - sy;
        const int nch    = (rows_n + 7) >> 3;

        for (int c = 0; c < 8; ++c) {
            const int dd = g + c * 16;
            const float* base = x + ((size_t)b * CH + dd) * HWSZ + xba;
            float4 ac0 = make_float4(0.f,0.f,0.f,0.f);
            float4 ac1 = make_float4(0.f,0.f,0.f,0.f);
            float4 ac2 = make_float4(0.f,0.f,0.f,0.f);
            for (int ck = 0; ck < nch; ++ck) {
                const int y0 = sy + (ck << 3);
                float4 v[8];
                #pragma unroll
                for (int k = 0; k < 8; ++k) {
                    int y = y0 + k;
                    y = (y < ey) ? y : (ey - 1);
                    v[k] = *(const float4*)(base + (size_t)y * WWID);
                }
                #pragma unroll
                for (int k = 0; k < 8; ++k) {
                    const float4 m = *(const float4*)&msk[(y0 - sy) + k][0];
                    ac0.x = fmaf(m.x, v[k].x, ac0.x); ac0.y = fmaf(m.x, v[k].y, ac0.y);
                    ac0.z = fmaf(m.x, v[k].z, ac0.z); ac0.w = fmaf(m.x, v[k].w, ac0.w);
                    ac1.x = fmaf(m.y, v[k].x, ac1.x); ac1.y = fmaf(m.y, v[k].y, ac1.y);
                    ac1.z = fmaf(m.y, v[k].z, ac1.z); ac1.w = fmaf(m.y, v[k].w, ac1.w);
                    ac2.x = fmaf(m.z, v[k].x, ac2.x); ac2.y = fmaf(m.z, v[k].y, ac2.y);
                    ac2.z = fmaf(m.z, v[k].z, ac2.z); ac2.w = fmaf(m.z, v[k].w, ac2.w);
                }
            }
            float a[9];
            a[0] = dot4(mx0, ac0, 0.f); a[1] = dot4(mx1, ac0, 0.f); a[2] = dot4(mx2, ac0, 0.f);
            a[3] = dot4(mx0, ac1, 0.f); a[4] = dot4(mx1, ac1, 0.f); a[5] = dot4(mx2, ac1, 0.f);
            a[6] = dot4(mx0, ac2, 0.f); a[7] = dot4(mx1, ac2, 0.f); a[8] = dot4(mx2, ac2, 0.f);
            #pragma unroll
            for (int jj = 0; jj < 9; ++jj) {
                a[jj] += __shfl_xor(a[jj], 8);
                a[jj] += __shfl_xor(a[jj], 4);
                a[jj] += __shfl_xor(a[jj], 2);
                a[jj] += __shfl_xor(a[jj], 1);
            }
            if (lx == 0) {
                int w0 = xe0 - sx, w1 = xe1 - xs1, w2 = ex - xs2;
                int h0 = ye0 - sy, h1r = ye1 - ys1, h2 = ey - ys2;
                kbuf[0][dd] = a[0] / (float)(h0 * w0);
                kbuf[1][dd] = a[1] / (float)(h0 * w1);
                kbuf[2][dd] = a[2] / (float)(h0 * w2);
                kbuf[3][dd] = a[3] / (float)(h1r * w0);
                kbuf[4][dd] = a[4] / (float)(h1r * w1);
                kbuf[5][dd] = a[5] / (float)(h1r * w2);
                kbuf[6][dd] = a[6] / (float)(h2 * w0);
                kbuf[7][dd] = a[7] / (float)(h2 * w1);
                kbuf[8][dd] = a[8] / (float)(h2 * w2);
            }
        }
    }
    __syncthreads();

    if (t < CH) {
        const float4* wr = (const float4*)(Wqkv + (size_t)t * CH);
        const float4* qq = (const float4*)qv;
        float s = 0.f;
        #pragma unroll 8
        for (int i = 0; i < CH / 4; ++i) s = dot4(wr[i], qq[i], s);
        qp[t] = s + bqkv[t];
    }
    {
        const int o = t & (CH - 1);
        const int which = t >> 7;
        const float4* wr = (const float4*)(Wqkv + (size_t)(CH + which * CH + o) * CH);
        float acc[9] = {0.f,0.f,0.f,0.f,0.f,0.f,0.f,0.f,0.f};
        #pragma unroll 4
        for (int i = 0; i < CH / 4; ++i) {
            float4 w = wr[i];
            #pragma unroll
            for (int s = 0; s < 9; ++s) {
                float4 kk = ((const float4*)(&kbuf[s][0]))[i];
                acc[s] = dot4(w, kk, acc[s]);
            }
        }
        float bias = bqkv[CH + which * CH + o];
        if (which == 0) {
            #pragma unroll
            for (int s = 0; s < 9; ++s) kp[s][o] = acc[s] + bias;
        } else {
            #pragma unroll
            for (int s = 0; s < 9; ++s) vp[s][o] = acc[s] + bias;
        }
    }
    __syncthreads();

    if (t < NHEAD * 9) {
        int h = t / 9, s = t - h * 9;
        const float* qh = qp + h * HDIM;
        const float* kh = &kp[s][h * HDIM];
        float a = 0.f;
        #pragma unroll
        for (int e = 0; e < HDIM; ++e) a = fmaf(qh[e], kh[e], a);
        att[h][s] = a * 0.25f;
    }
    __syncthreads();

    if (t < NHEAD) {
        float m = att[t][0];
        #pragma unroll
        for (int s = 1; s < 9; ++s) m = fmaxf(m, att[t][s]);
        float e[9]; float sum = 0.f;
        #pragma unroll
        for (int s = 0; s < 9; ++s) { e[s] = expf(att[t][s] - m); sum += e[s]; }
        float inv = 1.0f / sum;
        #pragma unroll
        for (int s = 0; s < 9; ++s) att[t][s] = e[s] * inv;
    }
    __syncthreads();

    if (t < CH) {
        int h = t >> 4;
        float a = 0.f;
        #pragma unroll
        for (int s = 0; s < 9; ++s) a = fmaf(att[h][s], vp[s][t], a);
        aov[t] = a;
    }
    __syncthreads();

    float v1 = 0.f;
    if (t < CH) {
        const float4* wr = (const float4*)(Wo + (size_t)t * CH);
        const float4* u4 = (const float4*)aov;
        float s = 0.f;
        #pragma unroll 8
        for (int i = 0; i < CH / 4; ++i) s = dot4(wr[i], u4[i], s);
        v1 = qv[t] + s + bo[t];
    }
    float t1 = block_layernorm(v1, t, g2, be2, redA, redB);
    if (t < CH) tv[t] = t1;
    __syncthreads();

    #pragma unroll
    for (int rep = 0; rep < 2; ++rep) {
        int o = t + rep * 256;
        const float4* wr = (const float4*)(W1 + (size_t)o * CH);
        const float4* u4 = (const float4*)tv;
        float s = 0.f;
        #pragma unroll 8
        for (int i = 0; i < CH / 4; ++i) s = dot4(wr[i], u4[i], s);
        h1[o] = fmaxf(s + b1[o], 0.f);
    }
    __syncthreads();

    {
        int o = t & (CH - 1), hf = t >> 7;
        const float4* wr = (const float4*)(W2 + (size_t)o * DFF + hf * (DFF / 2));
        const float4* u4 = (const float4*)(h1 + hf * (DFF / 2));
        float s = 0.f;
        #pragma unroll 8
        for (int i = 0; i < DFF / 8; ++i) s = dot4(wr[i], u4[i], s);
        part[t] = s;
    }
    __syncthreads();

    float v2 = 0.f;
    if (t < CH) {
        float t2 = part[t] + part[t + 128] + b2[t];
        v2 = tv[t] + t2;
    }
    float outv = block_layernorm(v2, t, g3, be3, redA, redB);
    if (t < CH) out[((size_t)b * CH + t) * HWSZ + p] = outv;
}

extern "C" void kernel_launch(void* const* d_in, const int* in_sizes, int n_in,
                              void* d_out, int out_size, void* d_ws, size_t ws_size,
                              hipStream_t stream) {
    const float* x    = (const float*)d_in[0];
    const float* vis  = (const float*)d_in[1];
    const int*   dets = (const int*)d_in[2];
    const int*   inds = (const int*)d_in[3];
    const float* Wqkv = (const float*)d_in[4];
    const float* bqkv = (const float*)d_in[5];
    const float* Wo   = (const float*)d_in[6];
    const float* bo   = (const float*)d_in[7];
    const float* W1   = (const float*)d_in[8];
    const float* b1   = (const float*)d_in[9];
    const float* W2   = (const float*)d_in[10];
    const float* b2   = (const float*)d_in[11];
    const float* g2   = (const float*)d_in[12];
    const float* be2  = (const float*)d_in[13];
    const float* g3   = (const float*)d_in[14];
    const float* be3  = (const float*)d_in[15];
    float* out = (float*)d_out;

    const size_t SZ_KP = (size_t)NDB * KSTRIDE;          // one partial buffer
    const size_t need  = 2 * SZ_KP * sizeof(float);

    const size_t N4 = (size_t)BB * CH * HWSZ / 4;
    if (ws_size >= need) {
        float* kpA = (float*)d_ws;
        float* kpB = kpA + SZ_KP;

        pool_stream<<<dim3(2048), dim3(256), 0, stream>>>(x, dets, kpA, out);
        tail_kernel<<<dim3(512), dim3(256), 0, stream>>>(
            x, vis, dets, inds, kpA, kpB, Wqkv, bqkv, Wo, bo,
            W1, b1, W2, b2, g2, be2, g3, be3, out);
    } else {
        copy_x<<<dim3(2048), dim3(256), 0, stream>>>(
            (const f4v*)x, (f4v*)out, N4);
        er_fused_fb<<<dim3(NDB), dim3(256), 0, stream>>>(
            x, vis, dets, inds, Wqkv, bqkv, Wo, bo, W1, b1, W2, b2,
            g2, be2, g3, be3, out);
    }
}

// Round 11
// 145.909 us; speedup vs baseline: 1.4250x; 1.0141x over previous
//
#include <hip/hip_runtime.h>
#include <math.h>

#define BB 8
#define CH 128
#define HH 152
#define WWID 272
#define HWSZ (HH*WWID)
#define NDET 128
#define NHEAD 8
#define HDIM 16
#define DFF 512
#define NDB (BB*NDET)      // 1024 dets
#define KSTRIDE 1152       // 9*CH floats of pooled k per det
#define CHUNK 16           // rows per LDS slab: 16*276*4 = 17664B -> 8 blocks/CU
#define RHALF 76           // rows per half-plane block (152 = 2*76; chunks 16,16,16,16,12)
#define SROW 276           // S row stride in floats (273 used, %4==0)

typedef float f4v __attribute__((ext_vector_type(4)));

__device__ __forceinline__ float dot4(float4 w, float4 u, float s) {
    s = fmaf(w.x, u.x, s);
    s = fmaf(w.y, u.y, s);
    s = fmaf(w.z, u.z, s);
    s = fmaf(w.w, u.w, s);
    return s;
}

// ============================================================================
// K1: fused copy + pooling partials. One block per (plane, row-half):
// 2048 blocks. Waves stream rows (read -> NT store = the copy) and build an
// exclusive prefix-sum per row in LDS; det-threads accumulate PARTIAL box
// cell sums over this half's rows -> kpart[rhalf]. Tail combines + divides.
// LDS 17.7KB -> 8 blocks/CU (thread cap) -> ALL 2048 blocks co-resident.
// ============================================================================
__global__ __launch_bounds__(256) void pool_stream(
    const float* __restrict__ x, const int* __restrict__ dets,
    float* __restrict__ kpart, float* __restrict__ out)
{
    const int bid   = blockIdx.x;          // plane*2 + rhalf
    const int t     = threadIdx.x;
    const int plane = bid >> 1, rhalf = bid & 1;
    const int b     = plane >> 7, ch = plane & 127;
    const int lane  = t & 63,  w  = t >> 6;
    const int rbeg  = rhalf * RHALF;

    __shared__ float S[CHUNK * SROW];      // prefix sums; reused as scratch

    const float* xp = x + ((size_t)b * CH + ch) * HWSZ;
    f4v* o4 = (f4v*)(out + ((size_t)b * CH + ch) * HWSZ);

    // ---- det-thread setup: thread d & d+128 both own det d ----
    const int d = t & 127, half = t >> 7;
    const int4 dv = *((const int4*)(dets + (size_t)(b * NDET + d) * 4));
    const int sx = dv.x, sy = dv.y, ex = dv.z, ey = dv.w;
    const int Lx = ex - sx, Ly = ey - sy;
    // cell edges (cells OVERLAP due to floor/ceil in reference)
    const int xs1 = sx + Lx / 3,        xs2 = sx + 2 * Lx / 3;
    const int xe0 = sx + (Lx + 2) / 3,  xe1 = sx + (2 * Lx + 2) / 3;
    const int ys1 = sy + Ly / 3,        ys2 = sy + 2 * Ly / 3;
    const int ye0 = sy + (Ly + 2) / 3,  ye1 = sy + (2 * Ly + 2) / 3;

    float acc[9] = {0.f,0.f,0.f,0.f,0.f,0.f,0.f,0.f,0.f};

    #pragma unroll 1
    for (int cbeg = rbeg; cbeg < rbeg + RHALF; cbeg += CHUNK) {
        const int csize = (rbeg + RHALF - cbeg < CHUNK) ? (rbeg + RHALF - cbeg) : CHUNK;

        // ---- phase A: stream + scan rows (wave-parallel, prefetched) ----
        {
            int rl = w;                       // wave w does rows w, w+4, ...
            f4v vm = (f4v)(0.f), ve = (f4v)(0.f);
            bool have = (rl < csize);
            if (have) {
                const f4v* rowp = (const f4v*)(xp + (size_t)(cbeg + rl) * WWID);
                vm = rowp[lane];
                if (lane < 4) ve = rowp[64 + lane];
            }
            while (have) {
                const int rc = rl;
                f4v v = vm, e = ve;
                rl += 4;
                have = (rl < csize);
                if (have) {                   // prefetch next row
                    const f4v* rowp = (const f4v*)(xp + (size_t)(cbeg + rl) * WWID);
                    vm = rowp[lane];
                    if (lane < 4) ve = rowp[64 + lane];
                }
                // copy current row to out (NT: don't evict x from L3)
                __builtin_nontemporal_store(v, &o4[(size_t)(cbeg + rc) * 68 + lane]);
                if (lane < 4)
                    __builtin_nontemporal_store(e, &o4[(size_t)(cbeg + rc) * 68 + 64 + lane]);
                // exclusive prefix: S[c] = sum of cols [0, c)
                float T = v[0] + v[1] + v[2] + v[3];
                float s = T;
                #pragma unroll
                for (int o = 1; o < 64; o <<= 1) {
                    float u = __shfl_up(s, o);
                    if (lane >= o) s += u;
                }
                float off0 = s - T;
                float* Sr = S + rc * SROW;
                f4v sm;
                sm[0] = off0;
                sm[1] = off0 + v[0];
                sm[2] = off0 + v[0] + v[1];
                sm[3] = off0 + v[0] + v[1] + v[2];
                *(f4v*)&Sr[4 * lane] = sm;
                float R  = __shfl(s, 63);                       // total cols 0..255
                float Te = (lane < 4) ? (e[0]+e[1]+e[2]+e[3]) : 0.f;
                float T0 = __shfl(Te, 0), T1 = __shfl(Te, 1);
                float T2 = __shfl(Te, 2), T3 = __shfl(Te, 3);
                if (lane < 4) {
                    float offE = R + ((lane > 0) ? T0 : 0.f)
                                   + ((lane > 1) ? T1 : 0.f)
                                   + ((lane > 2) ? T2 : 0.f);
                    f4v se;
                    se[0] = offE;
                    se[1] = offE + e[0];
                    se[2] = offE + e[0] + e[1];
                    se[3] = offE + e[0] + e[1] + e[2];
                    *(f4v*)&Sr[256 + 4 * lane] = se;
                }
                if (lane == 0) Sr[272] = R + T0 + T1 + T2 + T3;
            }
        }
        __syncthreads();

        // ---- phase B: det partial accumulation from prefix sums ----
        {
            int lo = (sy > cbeg) ? sy : cbeg;
            int hi = (ey < cbeg + csize) ? ey : (cbeg + csize);
            if (lo < hi) {
                int mid = (lo + hi + 1) >> 1;
                int y0 = half ? mid : lo;
                int y1 = half ? hi  : mid;
                for (int y = y0; y < y1; ++y) {
                    const float* Sr = S + (y - cbeg) * SROW;
                    float c0 = Sr[xe0] - Sr[sx];
                    float c1 = Sr[xe1] - Sr[xs1];
                    float c2 = Sr[ex]  - Sr[xs2];
                    float m0 = (y < ye0) ? 1.f : 0.f;
                    float m1 = (y >= ys1 && y < ye1) ? 1.f : 0.f;
                    float m2 = (y >= ys2) ? 1.f : 0.f;
                    acc[0] = fmaf(m0, c0, acc[0]); acc[1] = fmaf(m0, c1, acc[1]); acc[2] = fmaf(m0, c2, acc[2]);
                    acc[3] = fmaf(m1, c0, acc[3]); acc[4] = fmaf(m1, c1, acc[4]); acc[5] = fmaf(m1, c2, acc[5]);
                    acc[6] = fmaf(m2, c0, acc[6]); acc[7] = fmaf(m2, c1, acc[7]); acc[8] = fmaf(m2, c2, acc[8]);
                }
            }
        }
        __syncthreads();
    }

    // ---- combine thread-halves via S (reused as scratch), write partials ----
    if (half) {
        #pragma unroll
        for (int j = 0; j < 9; ++j) S[d * 9 + j] = acc[j];
    }
    __syncthreads();
    if (!half) {
        float* kd = kpart + ((size_t)rhalf * NDB + (size_t)(b * NDET + d)) * KSTRIDE + ch;
        #pragma unroll
        for (int j = 0; j < 9; ++j)
            kd[j * CH] = acc[j] + S[d * 9 + j];    // NO area divide (tail does it)
    }
}

// ============================================================================
// K2: fully-fused transformer tail. 512 blocks x 2 dets x 256 threads.
// k-combine -> QKV -> attention -> Wo+LN1 -> FFN1 -> FFN2+LN2 -> scatter.
// ============================================================================
__global__ __launch_bounds__(256) void tail_kernel(
    const float* __restrict__ x, const float* __restrict__ vis,
    const int* __restrict__ dets, const int* __restrict__ inds,
    const float* __restrict__ kpA, const float* __restrict__ kpB,
    const float* __restrict__ Wqkv, const float* __restrict__ bqkv,
    const float* __restrict__ Wo,   const float* __restrict__ bo,
    const float* __restrict__ W1,   const float* __restrict__ b1,
    const float* __restrict__ W2,   const float* __restrict__ b2,
    const float* __restrict__ g2,   const float* __restrict__ be2,
    const float* __restrict__ g3,   const float* __restrict__ be3,
    float* __restrict__ out)
{
    const int bid = blockIdx.x;
    const int t   = threadIdx.x;
    const int d0  = bid * 2;           // 2 dets per block, never straddles images
    const int b   = d0 >> 7;
    const int o   = t & 127, dl = t >> 7;

    __shared__ float kbuf[2 * 9 * CH];   // pooled k (area-divided)
    __shared__ float kp[2 * 9 * CH];
    __shared__ float vp[2 * 9 * CH];
    __shared__ float invA[2][9];
    __shared__ float qv[2][CH];
    __shared__ float qp[2][CH];
    __shared__ float attl[2][NHEAD][9];
    __shared__ float aov[2][CH];
    __shared__ float Tv[2][CH];
    __shared__ float h1[2][DFF];
    __shared__ float part2[2][2][CH];    // [half][det][o]
    __shared__ float wst[4][2];

    // ---- inverse cell areas (18 threads) ----
    if (t < 18) {
        int dd = t / 9, slot = t - dd * 9;
        const int4 dv = *((const int4*)(dets + (size_t)(b * NDET + ((d0 + dd) & 127)) * 4));
        int sx = dv.x, sy = dv.y, ex = dv.z, ey = dv.w;
        int Lx = ex - sx, Ly = ey - sy;
        int xs1 = sx + Lx / 3,       xs2 = sx + 2 * Lx / 3;
        int xe0 = sx + (Lx + 2) / 3, xe1 = sx + (2 * Lx + 2) / 3;
        int ys1 = sy + Ly / 3,       ys2 = sy + 2 * Ly / 3;
        int ye0 = sy + (Ly + 2) / 3, ye1 = sy + (2 * Ly + 2) / 3;
        int xi = slot % 3, yi = slot / 3;
        int wdt = (xi == 0) ? (xe0 - sx) : (xi == 1) ? (xe1 - xs1) : (ex - xs2);
        int hgt = (yi == 0) ? (ye0 - sy) : (yi == 1) ? (ye1 - ys1) : (ey - ys2);
        invA[dd][slot] = 1.0f / (float)(hgt * wdt);
    }
    // ---- q gather + positional embedding ----
    {
        int p = inds[b * NDET + ((d0 + dl) & 127)];
        float qval = x[((size_t)b * CH + o) * HWSZ + p];
        float vv   = vis[(size_t)b * HWSZ + p];
        int vidx   = (int)(vv * 10.0f);
        float fr   = powf(10000.0f, -(float)(o & 126) * (1.0f / 128.0f));
        float ang  = 0.1f * (float)vidx * fr;
        qv[dl][o]  = qval + ((o & 1) ? cosf(ang) : sinf(ang));
    }
    __syncthreads();

    // ---- combine pooling partials + area divide ----
    for (int i = t; i < 2 * KSTRIDE; i += 256) {
        int dd = (i >= KSTRIDE);
        int r  = i - dd * KSTRIDE;
        int slot = r >> 7;
        float vA = kpA[(size_t)(d0 + dd) * KSTRIDE + r];
        float vB = kpB[(size_t)(d0 + dd) * KSTRIDE + r];
        kbuf[dd * KSTRIDE + r] = (vA + vB) * invA[dd][slot];
    }
    __syncthreads();

    // ---- qp = Wq @ qv ----
    {
        const float4* wr = (const float4*)(Wqkv + (size_t)o * CH);
        const float4* qq = (const float4*)&qv[dl][0];
        float s = 0.f;
        #pragma unroll 8
        for (int i = 0; i < 32; ++i) s = dot4(wr[i], qq[i], s);
        qp[dl][o] = s + bqkv[o];
    }
    // ---- kp/vp: 18 rows x 128 outs, which = k or v ----
    {
        const int which = t >> 7;
        const float4* wr = (const float4*)(Wqkv + (size_t)(CH + which * CH + o) * CH);
        float acc[18];
        #pragma unroll
        for (int r = 0; r < 18; ++r) acc[r] = 0.f;
        for (int i = 0; i < 32; ++i) {
            float4 w = wr[i];
            #pragma unroll
            for (int r = 0; r < 18; ++r) {
                float4 a = ((const float4*)kbuf)[r * 32 + i];
                acc[r] = dot4(w, a, acc[r]);
            }
        }
        const float bias = bqkv[CH + which * CH + o];
        float* dst = which ? vp : kp;
        #pragma unroll
        for (int r = 0; r < 18; ++r) dst[r * CH + o] = acc[r] + bias;
    }
    __syncthreads();

    // ---- attention scores ----
    if (o < 72) {
        int h = o / 9, s = o - h * 9;
        const float* qh = &qp[dl][h * HDIM];
        const float* kh = &kp[dl * KSTRIDE + s * CH + h * HDIM];
        float a = 0.f;
        #pragma unroll
        for (int e = 0; e < HDIM; ++e) a = fmaf(qh[e], kh[e], a);
        attl[dl][h][s] = a * 0.25f;
    }
    __syncthreads();
    // ---- softmax per (det, head) ----
    if (o < 8) {
        float m = attl[dl][o][0];
        #pragma unroll
        for (int s = 1; s < 9; ++s) m = fmaxf(m, attl[dl][o][s]);
        float e[9]; float sum = 0.f;
        #pragma unroll
        for (int s = 0; s < 9; ++s) { e[s] = expf(attl[dl][o][s] - m); sum += e[s]; }
        float inv = 1.0f / sum;
        #pragma unroll
        for (int s = 0; s < 9; ++s) attl[dl][o][s] = e[s] * inv;
    }
    __syncthreads();
    // ---- ao = att @ vp ----
    {
        int h = o >> 4;
        float a = 0.f;
        #pragma unroll
        for (int s = 0; s < 9; ++s) a = fmaf(attl[dl][h][s], vp[dl * KSTRIDE + s * CH + o], a);
        aov[dl][o] = a;
    }
    __syncthreads();

    // ---- Wo + resid ----
    float v1;
    {
        const float4* wr = (const float4*)(Wo + (size_t)o * CH);
        const float4* u4 = (const float4*)&aov[dl][0];
        float s = 0.f;
        #pragma unroll 8
        for (int i = 0; i < 32; ++i) s = dot4(wr[i], u4[i], s);
        v1 = qv[dl][o] + s + bo[o];
    }
    // ---- LN1 (det dl spans waves 2dl, 2dl+1) ----
    {
        float s1 = v1, s2 = v1 * v1;
        #pragma unroll
        for (int off = 32; off >= 1; off >>= 1) {
            s1 += __shfl_xor(s1, off);
            s2 += __shfl_xor(s2, off);
        }
        if ((t & 63) == 0) { wst[t >> 6][0] = s1; wst[t >> 6][1] = s2; }
    }
    __syncthreads();
    {
        float sum = wst[2 * dl][0] + wst[2 * dl + 1][0];
        float sq  = wst[2 * dl][1] + wst[2 * dl + 1][1];
        float m   = sum * (1.0f / 128.0f);
        float var = sq  * (1.0f / 128.0f) - m * m;
        Tv[dl][o] = (v1 - m) * rsqrtf(var + 1e-5f) * g2[o] + be2[o];
    }
    __syncthreads();

    // ---- FFN1: 512 outs x 2 dets ----
    #pragma unroll
    for (int rep = 0; rep < 2; ++rep) {
        int oo = t + rep * 256;
        const float4* wr = (const float4*)(W1 + (size_t)oo * CH);
        float a0 = 0.f, a1 = 0.f;
        for (int i = 0; i < 32; ++i) {
            float4 w = wr[i];
            a0 = dot4(w, ((const float4*)&Tv[0][0])[i], a0);
            a1 = dot4(w, ((const float4*)&Tv[1][0])[i], a1);
        }
        float bb = b1[oo];
        h1[0][oo] = fmaxf(a0 + bb, 0.f);
        h1[1][oo] = fmaxf(a1 + bb, 0.f);
    }
    __syncthreads();

    // ---- FFN2 partials: thread (o, hf) does half the 512-dot for both dets ----
    {
        const int hf = t >> 7;
        const float4* wr = (const float4*)(W2 + (size_t)o * DFF + hf * (DFF / 2));
        float a0 = 0.f, a1 = 0.f;
        #pragma unroll 4
        for (int i = 0; i < 64; ++i) {
            float4 w = wr[i];
            a0 = dot4(w, ((const float4*)&h1[0][hf * 256])[i], a0);
            a1 = dot4(w, ((const float4*)&h1[1][hf * 256])[i], a1);
        }
        part2[hf][0][o] = a0;
        part2[hf][1][o] = a1;
    }
    __syncthreads();
    float v2 = part2[0][dl][o] + part2[1][dl][o] + b2[o] + Tv[dl][o];
    // ---- LN2 ----
    {
        float s1 = v2, s2 = v2 * v2;
        #pragma unroll
        for (int off = 32; off >= 1; off >>= 1) {
            s1 += __shfl_xor(s1, off);
            s2 += __shfl_xor(s2, off);
        }
        if ((t & 63) == 0) { wst[t >> 6][0] = s1; wst[t >> 6][1] = s2; }
    }
    __syncthreads();
    {
        float sum = wst[2 * dl][0] + wst[2 * dl + 1][0];
        float sq  = wst[2 * dl][1] + wst[2 * dl + 1][1];
        float m   = sum * (1.0f / 128.0f);
        float var = sq  * (1.0f / 128.0f) - m * m;
        float ov  = (v2 - m) * rsqrtf(var + 1e-5f) * g3[o] + be3[o];
        int p = inds[b * NDET + ((d0 + dl) & 127)];
        out[((size_t)b * CH + o) * HWSZ + p] = ov;       // scattered final write
    }
}

// ============================================================================
// Fallback path (ws too small): copy, then fully-fused det kernel
// ============================================================================
__global__ __launch_bounds__(256) void copy_x(const f4v* __restrict__ src,
                                              f4v* __restrict__ dst, size_t n4) {
    size_t i = (size_t)blockIdx.x * 256 + threadIdx.x;
    const size_t stride = (size_t)gridDim.x * 256;
    for (; i < n4; i += stride) {
        f4v v = src[i];
        __builtin_nontemporal_store(v, &dst[i]);
    }
}

__device__ __forceinline__ float block_layernorm(float v, int t,
        const float* __restrict__ gamma, const float* __restrict__ beta,
        float* redA, float* redB) {
    float s1 = v, s2 = v * v;
    #pragma unroll
    for (int off = 32; off >= 1; off >>= 1) {
        s1 += __shfl_xor(s1, off);
        s2 += __shfl_xor(s2, off);
    }
    if ((t & 63) == 0) { redA[t >> 6] = s1; redB[t >> 6] = s2; }
    __syncthreads();
    float sum = redA[0] + redA[1] + redA[2] + redA[3];
    float sq  = redB[0] + redB[1] + redB[2] + redB[3];
    __syncthreads();
    float m   = sum * (1.0f / 128.0f);
    float var = sq  * (1.0f / 128.0f) - m * m;
    float r = 0.f;
    if (t < CH) r = (v - m) * rsqrtf(var + 1e-5f) * gamma[t] + beta[t];
    return r;
}

__global__ __launch_bounds__(256) void er_fused_fb(
    const float* __restrict__ x, const float* __restrict__ vis,
    const int* __restrict__ dets, const int* __restrict__ inds,
    const float* __restrict__ Wqkv, const float* __restrict__ bqkv,
    const float* __restrict__ Wo,   const float* __restrict__ bo,
    const float* __restrict__ W1,   const float* __restrict__ b1,
    const float* __restrict__ W2,   const float* __restrict__ b2,
    const float* __restrict__ g2,   const float* __restrict__ be2,
    const float* __restrict__ g3,   const float* __restrict__ be3,
    float* __restrict__ out)
{
    const int bid = blockIdx.x;
    const int t   = threadIdx.x;

    __shared__ float kbuf[9][CH];
    __shared__ float qv[CH];
    __shared__ float qp[CH];
    __shared__ float kp[9][CH];
    __shared__ float vp[9][CH];
    __shared__ float att[NHEAD][9];
    __shared__ float aov[CH];
    __shared__ float tv[CH];
    __shared__ float h1[DFF];
    __shared__ float part[256];
    __shared__ float redA[4], redB[4];
    __shared__ float msk[48][4];

    const int b = bid >> 7;
    const int n = bid & (NDET - 1);

    const int4 dv = *((const int4*)(dets + (size_t)(b * NDET + n) * 4));
    const int sx = dv.x, sy = dv.y, ex = dv.z, ey = dv.w;
    const int Lx = ex - sx, Ly = ey - sy;
    const int xs1 = sx + Lx / 3,        xs2 = sx + 2 * Lx / 3;
    const int xe0 = sx + (Lx + 2) / 3,  xe1 = sx + (2 * Lx + 2) / 3;
    const int ys1 = sy + Ly / 3,        ys2 = sy + 2 * Ly / 3;
    const int ye0 = sy + (Ly + 2) / 3,  ye1 = sy + (2 * Ly + 2) / 3;

    const int p = inds[b * NDET + n];

    if (t < 48) {
        int y = sy + t;
        bool inb = (y < ey);
        msk[t][0] = (inb && y < ye0)              ? 1.f : 0.f;
        msk[t][1] = (inb && y >= ys1 && y < ye1)  ? 1.f : 0.f;
        msk[t][2] = (inb && y >= ys2)             ? 1.f : 0.f;
        msk[t][3] = 0.f;
    }
    if (t < CH) {
        float qval = x[((size_t)b * CH + t) * HWSZ + p];
        float vv   = vis[(size_t)b * HWSZ + p];
        int vidx   = (int)(vv * 10.0f);
        float fr   = powf(10000.0f, -(float)(t & 126) * (1.0f / 128.0f));
        float ang  = 0.1f * (float)vidx * fr;
        float pe   = (t & 1) ? cosf(ang) : sinf(ang);
        qv[t] = qval + pe;
    }
    __syncthreads();

    {
        const int g   = t >> 4;
        const int lx  = t & 15;
        const int sx4 = sx & ~3;
        const int xb  = sx4 + lx * 4;
        const int lxmax = ((ex - 1) - sx4) >> 2;
        const int xba = sx4 + ((lx < lxmax) ? lx : lxmax) * 4;

        float4 mx0, mx1, mx2;
        {
            float m0[4], m1[4], m2[4];
            #pragma unroll
            for (int e = 0; e < 4; ++e) {
                int xx = xb + e;
                m0[e] = (xx >= sx  && xx < xe0) ? 1.f : 0.f;
                m1[e] = (xx >= xs1 && xx < xe1) ? 1.f : 0.f;
                m2[e] = (xx >= xs2 && xx < ex ) ? 1.f : 0.f;
            }
            mx0 = make_float4(m0[0], m0[1], m0[2], m0[3]);
            mx1 = make_float4(m1[0], m1[1], m1[2], m1[3]);
            mx2 = make_float4(m2[0], m2[1], m2[2], m2[3]);
        }

        const int rows_n = ey - sy;
        const int nch    = (rows_n + 7) >> 3;

        for (int c = 0; c < 8; ++c) {
            const int dd = g + c * 16;
            const float* base = x + ((size_t)b * CH + dd) * HWSZ + xba;
            float4 ac0 = make_float4(0.f,0.f,0.f,0.f);
            float4 ac1 = make_float4(0.f,0.f,0.f,0.f);
            float4 ac2 = make_float4(0.f,0.f,0.f,0.f);
            for (int ck = 0; ck < nch; ++ck) {
                const int y0 = sy + (ck << 3);
                float4 v[8];
                #pragma unroll
                for (int k = 0; k < 8; ++k) {
                    int y = y0 + k;
                    y = (y < ey) ? y : (ey - 1);
                    v[k] = *(const float4*)(base + (size_t)y * WWID);
                }
                #pragma unroll
                for (int k = 0; k < 8; ++k) {
                    const float4 m = *(const float4*)&msk[(y0 - sy) + k][0];
                    ac0.x = fmaf(m.x, v[k].x, ac0.x); ac0.y = fmaf(m.x, v[k].y, ac0.y);
                    ac0.z = fmaf(m.x, v[k].z, ac0.z); ac0.w = fmaf(m.x, v[k].w, ac0.w);
                    ac1.x = fmaf(m.y, v[k].x, ac1.x); ac1.y = fmaf(m.y, v[k].y, ac1.y);
                    ac1.z = fmaf(m.y, v[k].z, ac1.z); ac1.w = fmaf(m.y, v[k].w, ac1.w);
                    ac2.x = fmaf(m.z, v[k].x, ac2.x); ac2.y = fmaf(m.z, v[k].y, ac2.y);
                    ac2.z = fmaf(m.z, v[k].z, ac2.z); ac2.w = fmaf(m.z, v[k].w, ac2.w);
                }
            }
            float a[9];
            a[0] = dot4(mx0, ac0, 0.f); a[1] = dot4(mx1, ac0, 0.f); a[2] = dot4(mx2, ac0, 0.f);
            a[3] = dot4(mx0, ac1, 0.f); a[4] = dot4(mx1, ac1, 0.f); a[5] = dot4(mx2, ac1, 0.f);
            a[6] = dot4(mx0, ac2, 0.f); a[7] = dot4(mx1, ac2, 0.f); a[8] = dot4(mx2, ac2, 0.f);
            #pragma unroll
            for (int jj = 0; jj < 9; ++jj) {
                a[jj] += __shfl_xor(a[jj], 8);
                a[jj] += __shfl_xor(a[jj], 4);
                a[jj] += __shfl_xor(a[jj], 2);
                a[jj] += __shfl_xor(a[jj], 1);
            }
            if (lx == 0) {
                int w0 = xe0 - sx, w1 = xe1 - xs1, w2 = ex - xs2;
                int h0 = ye0 - sy, h1r = ye1 - ys1, h2 = ey - ys2;
                kbuf[0][dd] = a[0] / (float)(h0 * w0);
                kbuf[1][dd] = a[1] / (float)(h0 * w1);
                kbuf[2][dd] = a[2] / (float)(h0 * w2);
                kbuf[3][dd] = a[3] / (float)(h1r * w0);
                kbuf[4][dd] = a[4] / (float)(h1r * w1);
                kbuf[5][dd] = a[5] / (float)(h1r * w2);
                kbuf[6][dd] = a[6] / (float)(h2 * w0);
                kbuf[7][dd] = a[7] / (float)(h2 * w1);
                kbuf[8][dd] = a[8] / (float)(h2 * w2);
            }
        }
    }
    __syncthreads();

    if (t < CH) {
        const float4* wr = (const float4*)(Wqkv + (size_t)t * CH);
        const float4* qq = (const float4*)qv;
        float s = 0.f;
        #pragma unroll 8
        for (int i = 0; i < CH / 4; ++i) s = dot4(wr[i], qq[i], s);
        qp[t] = s + bqkv[t];
    }
    {
        const int o = t & (CH - 1);
        const int which = t >> 7;
        const float4* wr = (const float4*)(Wqkv + (size_t)(CH + which * CH + o) * CH);
        float acc[9] = {0.f,0.f,0.f,0.f,0.f,0.f,0.f,0.f,0.f};
        #pragma unroll 4
        for (int i = 0; i < CH / 4; ++i) {
            float4 w = wr[i];
            #pragma unroll
            for (int s = 0; s < 9; ++s) {
                float4 kk = ((const float4*)(&kbuf[s][0]))[i];
                acc[s] = dot4(w, kk, acc[s]);
            }
        }
        float bias = bqkv[CH + which * CH + o];
        if (which == 0) {
            #pragma unroll
            for (int s = 0; s < 9; ++s) kp[s][o] = acc[s] + bias;
        } else {
            #pragma unroll
            for (int s = 0; s < 9; ++s) vp[s][o] = acc[s] + bias;
        }
    }
    __syncthreads();

    if (t < NHEAD * 9) {
        int h = t / 9, s = t - h * 9;
        const float* qh = qp + h * HDIM;
        const float* kh = &kp[s][h * HDIM];
        float a = 0.f;
        #pragma unroll
        for (int e = 0; e < HDIM; ++e) a = fmaf(qh[e], kh[e], a);
        att[h][s] = a * 0.25f;
    }
    __syncthreads();

    if (t < NHEAD) {
        float m = att[t][0];
        #pragma unroll
        for (int s = 1; s < 9; ++s) m = fmaxf(m, att[t][s]);
        float e[9]; float sum = 0.f;
        #pragma unroll
        for (int s = 0; s < 9; ++s) { e[s] = expf(att[t][s] - m); sum += e[s]; }
        float inv = 1.0f / sum;
        #pragma unroll
        for (int s = 0; s < 9; ++s) att[t][s] = e[s] * inv;
    }
    __syncthreads();

    if (t < CH) {
        int h = t >> 4;
        float a = 0.f;
        #pragma unroll
        for (int s = 0; s < 9; ++s) a = fmaf(att[h][s], vp[s][t], a);
        aov[t] = a;
    }
    __syncthreads();

    float v1 = 0.f;
    if (t < CH) {
        const float4* wr = (const float4*)(Wo + (size_t)t * CH);
        const float4* u4 = (const float4*)aov;
        float s = 0.f;
        #pragma unroll 8
        for (int i = 0; i < CH / 4; ++i) s = dot4(wr[i], u4[i], s);
        v1 = qv[t] + s + bo[t];
    }
    float t1 = block_layernorm(v1, t, g2, be2, redA, redB);
    if (t < CH) tv[t] = t1;
    __syncthreads();

    #pragma unroll
    for (int rep = 0; rep < 2; ++rep) {
        int o = t + rep * 256;
        const float4* wr = (const float4*)(W1 + (size_t)o * CH);
        const float4* u4 = (const float4*)tv;
        float s = 0.f;
        #pragma unroll 8
        for (int i = 0; i < CH / 4; ++i) s = dot4(wr[i], u4[i], s);
        h1[o] = fmaxf(s + b1[o], 0.f);
    }
    __syncthreads();

    {
        int o = t & (CH - 1), hf = t >> 7;
        const float4* wr = (const float4*)(W2 + (size_t)o * DFF + hf * (DFF / 2));
        const float4* u4 = (const float4*)(h1 + hf * (DFF / 2));
        float s = 0.f;
        #pragma unroll 8
        for (int i = 0; i < DFF / 8; ++i) s = dot4(wr[i], u4[i], s);
        part[t] = s;
    }
    __syncthreads();

    float v2 = 0.f;
    if (t < CH) {
        float t2 = part[t] + part[t + 128] + b2[t];
        v2 = tv[t] + t2;
    }
    float outv = block_layernorm(v2, t, g3, be3, redA, redB);
    if (t < CH) out[((size_t)b * CH + t) * HWSZ + p] = outv;
}

extern "C" void kernel_launch(void* const* d_in, const int* in_sizes, int n_in,
                              void* d_out, int out_size, void* d_ws, size_t ws_size,
                              hipStream_t stream) {
    const float* x    = (const float*)d_in[0];
    const float* vis  = (const float*)d_in[1];
    const int*   dets = (const int*)d_in[2];
    const int*   inds = (const int*)d_in[3];
    const float* Wqkv = (const float*)d_in[4];
    const float* bqkv = (const float*)d_in[5];
    const float* Wo   = (const float*)d_in[6];
    const float* bo   = (const float*)d_in[7];
    const float* W1   = (const float*)d_in[8];
    const float* b1   = (const float*)d_in[9];
    const float* W2   = (const float*)d_in[10];
    const float* b2   = (const float*)d_in[11];
    const float* g2   = (const float*)d_in[12];
    const float* be2  = (const float*)d_in[13];
    const float* g3   = (const float*)d_in[14];
    const float* be3  = (const float*)d_in[15];
    float* out = (float*)d_out;

    const size_t SZ_KP = (size_t)NDB * KSTRIDE;          // one partial buffer
    const size_t need  = 2 * SZ_KP * sizeof(float);

    const size_t N4 = (size_t)BB * CH * HWSZ / 4;
    if (ws_size >= need) {
        float* kpA = (float*)d_ws;
        float* kpB = kpA + SZ_KP;

        pool_stream<<<dim3(2048), dim3(256), 0, stream>>>(x, dets, kpA, out);
        tail_kernel<<<dim3(512), dim3(256), 0, stream>>>(
            x, vis, dets, inds, kpA, kpB, Wqkv, bqkv, Wo, bo,
            W1, b1, W2, b2, g2, be2, g3, be3, out);
    } else {
        copy_x<<<dim3(2048), dim3(256), 0, stream>>>(
            (const f4v*)x, (f4v*)out, N4);
        er_fused_fb<<<dim3(NDB), dim3(256), 0, stream>>>(
            x, vis, dets, inds, Wqkv, bqkv, Wo, bo, W1, b1, W2, b2,
            g2, be2, g3, be3, out);
    }
}